// Round 9
// baseline (788.248 us; speedup 1.0000x reference)
//
#include <hip/hip_runtime.h>
#include <math.h>

// ---------------------------------------------------------------------------
// NystromAttention round 16: R8 (784us) + attn1_conv rewritten in the
// attn3_flash barrier-free wave-private structure (block=64 rows, wave owns
// 16 rows end-to-end: QK(256 landmarks) -> in-register softmax -> wave-
// private P -> PV + banded conv; ZERO block barriers) + pinv final-iteration
// dead-output trim (fp32 zn / B-form unused after the loop).
// b=4 n=4096 dim=512 h=8 d=64 m=256, l=16, iters=6, conv k=33.
// MFMA 16x16x32_bf16 layouts (HW-verified per guide):
//   A: m=lane&15, k=(lane>>4)*8+j    B: n=lane&15, k=(lane>>4)*8+j
//   C/D: col=lane&15, row=(lane>>4)*4+reg
// ---------------------------------------------------------------------------

#define QKV_STRIDE 262144   // 4096*64 per (b,h)
#define LM_STRIDE 16384     // 256*64
#define MM_STRIDE 65536     // 256*256

typedef float f32x4 __attribute__((ext_vector_type(4)));
typedef short bf8 __attribute__((ext_vector_type(8)));   // 8 bf16 in 4 VGPRs
typedef short s4v __attribute__((ext_vector_type(4)));

__device__ __forceinline__ unsigned short f2bf_(float f) {
  unsigned u = __float_as_uint(f);
  u += 0x7FFFu + ((u >> 16) & 1u);   // RNE
  return (unsigned short)(u >> 16);
}
__device__ __forceinline__ float bf2f_(unsigned short h) {
  return __uint_as_float(((unsigned)h) << 16);
}

// async global->LDS, 16B per lane; LDS dest must be wave-uniform base.
__device__ __forceinline__ void gl16(const short* g, short* l) {
  __builtin_amdgcn_global_load_lds(
      (const __attribute__((address_space(1))) unsigned int*)g,
      (__attribute__((address_space(3))) unsigned int*)l, 16, 0, 0);
}

__global__ __launch_bounds__(256) void zero_scal(float* scal) {
  if (threadIdx.x < 2) scal[threadIdx.x] = 0.0f;
}

// ---------------- x (fp32) -> xb16 (bf16 row-major) -------------------------
__global__ __launch_bounds__(256) void x_to_bf16(const float* __restrict__ x,
                                                 short* __restrict__ xb) {
  const int g = blockIdx.x * 256 + threadIdx.x;   // 524288 threads
  const float4* xp = (const float4*)x;
#pragma unroll
  for (int u = 0; u < 4; ++u) {
    const size_t i4 = (size_t)u * 524288 + g;
    float4 v = xp[i4];
    s4v o;
    o[0] = (short)f2bf_(v.x); o[1] = (short)f2bf_(v.y);
    o[2] = (short)f2bf_(v.z); o[3] = (short)f2bf_(v.w);
    *(s4v*)&xb[i4 * 4] = o;
  }
}

// ------------- transpose + fp32->bf16: dst[C][R] = bf16(src[R][C]) ----------
__global__ __launch_bounds__(256) void transpose_bf16(const float* __restrict__ src,
                                                      short* __restrict__ dst,
                                                      int R, int C) {
  __shared__ float T[32][33];
  const int t = threadIdx.x;
  const int c0 = blockIdx.x * 32, r0 = blockIdx.y * 32;
  const int tr = t >> 3, tc = (t & 7) << 2;
  float4 vsrc = *(const float4*)&src[(size_t)(r0 + tr) * C + c0 + tc];
  T[tr][tc + 0] = vsrc.x; T[tr][tc + 1] = vsrc.y;
  T[tr][tc + 2] = vsrc.z; T[tr][tc + 3] = vsrc.w;
  __syncthreads();
  s4v o;
  o[0] = (short)f2bf_(T[tc + 0][tr]);
  o[1] = (short)f2bf_(T[tc + 1][tr]);
  o[2] = (short)f2bf_(T[tc + 2][tr]);
  o[3] = (short)f2bf_(T[tc + 3][tr]);
  *(s4v*)&dst[(size_t)(c0 + tr) * R + r0 + tc] = o;
}

// ---- qkv = xb16 @ w_qkv via MFMA -> qb16/kb16 row-major, vT16 transposed ---
// global_load_lds staging; XCD-swizzled 1-D grid (bijective, 1536 = 8*192).
__global__ __launch_bounds__(256) void gemm_qkv_mfma(const short* __restrict__ xb,
                                                     const short* __restrict__ wT,
                                                     short* __restrict__ qb16,
                                                     short* __restrict__ kb16,
                                                     short* __restrict__ vT16) {
  __shared__ short SMEM[17408];   // As[0..4095], Bs[4096..8191]; v: stage 128x136
  short* As = SMEM;
  short* Bs = SMEM + 4096;
  const int tid = threadIdx.x;
  const int lane = tid & 63, w = tid >> 6;
  const int wr = w >> 1, wc = w & 1;
  const int bid = (blockIdx.x & 7) * 192 + (blockIdx.x >> 3);  // 1536 = 8*192
  const int bn = bid % 12, bm = bid / 12;
  const int gm0 = bm * 128, gn0 = bn * 128;
  const int mA0 = (tid >> 6) * 16 + (tid & 15), kA0 = ((tid >> 4) & 3) * 8;
  const int s1 = tid + 256;
  const int mA1 = (s1 >> 6) * 16 + (s1 & 15), kA1 = ((s1 >> 4) & 3) * 8;
  const short* srcA0 = &xb[(size_t)(gm0 + mA0) * 512 + kA0];
  const short* srcA1 = &xb[(size_t)(gm0 + mA1) * 512 + kA1];
  const short* srcB0 = &wT[(size_t)(gn0 + mA0) * 512 + kA0];
  const short* srcB1 = &wT[(size_t)(gn0 + mA1) * 512 + kA1];
  short* dA0 = &As[w * 512];
  short* dA1 = &As[2048 + w * 512];
  short* dB0 = &Bs[w * 512];
  short* dB1 = &Bs[2048 + w * 512];
  f32x4 acc[4][4];
#pragma unroll
  for (int i = 0; i < 4; ++i)
#pragma unroll
    for (int j = 0; j < 4; ++j) acc[i][j] = (f32x4){0.f, 0.f, 0.f, 0.f};
  for (int kt = 0; kt < 16; ++kt) {
    const int k0 = kt * 32;
    __syncthreads();                 // prev-step LDS reads done before overwrite
    gl16(srcA0 + k0, dA0);
    gl16(srcA1 + k0, dA1);
    gl16(srcB0 + k0, dB0);
    gl16(srcB1 + k0, dB1);
    __syncthreads();                 // drains vmcnt -> tile resident
    bf8 af[4], bf[4];
#pragma unroll
    for (int i = 0; i < 4; ++i) {
      af[i] = *(const bf8*)&As[((wr * 4 + i) * 64 + lane) * 8];
      bf[i] = *(const bf8*)&Bs[((wc * 4 + i) * 64 + lane) * 8];
    }
#pragma unroll
    for (int i = 0; i < 4; ++i)
#pragma unroll
      for (int j = 0; j < 4; ++j)
        acc[i][j] = __builtin_amdgcn_mfma_f32_16x16x32_bf16(af[i], bf[j], acc[i][j], 0, 0, 0);
  }
  const int which = bn >> 2;  // 0:q 1:k 2:v
  const int qd = lane >> 4, c = lane & 15;
  if (which < 2) {
    short* dst = which == 0 ? qb16 : kb16;
    const float scale = which == 0 ? 0.125f : 1.0f;
#pragma unroll
    for (int i = 0; i < 4; ++i)
#pragma unroll
      for (int j = 0; j < 4; ++j) {
        const int col = gn0 + wc * 64 + j * 16 + c;
        const int head = (col >> 6) & 7, dd = col & 63;
#pragma unroll
        for (int r = 0; r < 4; ++r) {
          const int row = gm0 + wr * 64 + i * 16 + qd * 4 + r;
          const int b = row >> 12, seq = row & 4095;
          dst[(size_t)(b * 8 + head) * QKV_STRIDE + seq * 64 + dd] =
              (short)f2bf_(acc[i][j][r] * scale);
        }
      }
  } else {
    __syncthreads();
#pragma unroll
    for (int i = 0; i < 4; ++i)
#pragma unroll
    for (int j = 0; j < 4; ++j) {
        const int colL = wc * 64 + j * 16 + c;
#pragma unroll
        for (int r = 0; r < 4; ++r) {
          const int rowL = wr * 64 + i * 16 + qd * 4 + r;
          SMEM[colL * 136 + rowL] = (short)f2bf_(acc[i][j][r]);
        }
      }
    __syncthreads();
    const int b = gm0 >> 12, seq0 = gm0 & 4095;
    const int dcol = tid >> 1, half = tid & 1;
    const int col = gn0 + dcol;
    const int head = (col >> 6) & 7, d = col & 63;
    const short* src = &SMEM[dcol * 136 + half * 64];
    short* dstp = &vT16[(size_t)(b * 8 + head) * QKV_STRIDE + (size_t)d * 4096 +
                        seq0 + half * 64];
#pragma unroll
    for (int u = 0; u < 16; ++u) *(s4v*)&dstp[u * 4] = *(const s4v*)&src[u * 4];
  }
}

// ---------------- landmark means (bf16 in, fp32 + bf16-kl out) --------------
__global__ __launch_bounds__(256) void lmk_mean(const short* __restrict__ qb16,
                                                const short* __restrict__ kb16,
                                                float* __restrict__ ql,
                                                float* __restrict__ kl,
                                                short* __restrict__ klb16) {
  const int g = blockIdx.x * 256 + threadIdx.x;
  const int dd = g & 63, mi = (g >> 6) & 255, bh = g >> 14;
  const size_t base = (size_t)bh * QKV_STRIDE + mi * 1024 + dd;
  float sq = 0.f, sk = 0.f;
#pragma unroll
  for (int jj = 0; jj < 16; ++jj) {
    sq += bf2f_((unsigned short)qb16[base + jj * 64]);
    sk += bf2f_((unsigned short)kb16[base + jj * 64]);
  }
  const float qv = sq * 0.0625f, kv = sk * 0.0625f;
  ql[g] = qv;
  kl[g] = kv;
  klb16[g] = (short)f2bf_(kv);
}

// ---------------- sim2 = ql @ kl^T, softmax -> x2 hi/lo ---------------------
__global__ __launch_bounds__(256) void sim2_softmax(const float* __restrict__ ql,
                                                    const float* __restrict__ kl,
                                                    short* __restrict__ x2hi,
                                                    short* __restrict__ x2lo) {
  const int blk = blockIdx.x;
  const int bh = blk >> 4, rg = blk & 15;
  __shared__ float Qs[16][64];
  __shared__ float Ks[64][68];
  __shared__ float S[16][257];
  __shared__ float red[16][17];
  __shared__ float rowinv[16];
  const int tid = threadIdx.x;
  const int r = tid >> 4, jc = tid & 15;
#pragma unroll
  for (int u = 0; u < 4; ++u) {
    int t2 = tid + u * 256;
    Qs[t2 >> 6][t2 & 63] =
        ql[(size_t)bh * LM_STRIDE + (rg * 16 + (t2 >> 6)) * 64 + (t2 & 63)];
  }
  for (int c = 0; c < 4; ++c) {
    __syncthreads();
#pragma unroll
    for (int u = 0; u < 4; ++u) {
      int t4 = tid + u * 256;
      int row = t4 >> 4, c4 = (t4 & 15) << 2;
      *(float4*)&Ks[row][c4] =
          *(const float4*)&kl[(size_t)bh * LM_STRIDE + (c * 64 + row) * 64 + c4];
    }
    __syncthreads();
#pragma unroll
    for (int s = 0; s < 4; ++s) {
      const int jj = jc + (s << 4);
      float acc = 0.f;
#pragma unroll
      for (int k4 = 0; k4 < 16; ++k4) {
        const float4 a = *(const float4*)&Qs[r][k4 << 2];
        const float4 bb = *(const float4*)&Ks[jj][k4 << 2];
        acc += a.x * bb.x + a.y * bb.y + a.z * bb.z + a.w * bb.w;
      }
      S[r][(c << 6) + jj] = acc;
    }
  }
  __syncthreads();
  float pm = -3.0e38f;
#pragma unroll
  for (int u = 0; u < 16; ++u) pm = fmaxf(pm, S[r][jc + (u << 4)]);
  red[r][jc] = pm;
  __syncthreads();
  float m = red[r][0];
#pragma unroll
  for (int u = 1; u < 16; ++u) m = fmaxf(m, red[r][u]);
  __syncthreads();
  float ps = 0.f;
#pragma unroll
  for (int u = 0; u < 16; ++u) {
    const int j = jc + (u << 4);
    const float e = __expf(S[r][j] - m);
    S[r][j] = e;
    ps += e;
  }
  red[r][jc] = ps;
  __syncthreads();
  if (jc == 0) {
    float sum = 0.f;
#pragma unroll
    for (int u = 0; u < 16; ++u) sum += red[r][u];
    rowinv[r] = 1.0f / sum;
  }
  __syncthreads();
  for (int idx = tid; idx < 4096; idx += 256) {
    const int rr = idx >> 8, j = idx & 255;
    const float v = S[rr][j] * rowinv[rr];
    const unsigned short h = f2bf_(v);
    const size_t off = (size_t)bh * MM_STRIDE + (rg * 16 + rr) * 256 + j;
    x2hi[off] = (short)h;
    x2lo[off] = (short)f2bf_(v - bf2f_(h));
  }
}

// ---------------- global max of col/row abs-sums (hi/lo input) --------------
__global__ __launch_bounds__(256) void colrow_max(const short* __restrict__ x2hi,
                                                  const short* __restrict__ x2lo,
                                                  float* __restrict__ scal) {
  const int bh = blockIdx.x;
  const int tid = threadIdx.x;
  const size_t b0 = (size_t)bh * MM_STRIDE;
  float cs = 0.f, rs = 0.f;
  for (int j = 0; j < 256; ++j) {
    const size_t o = b0 + (size_t)tid * 256 + j;
    cs += fabsf(bf2f_((unsigned short)x2hi[o]) + bf2f_((unsigned short)x2lo[o]));
  }
  for (int i = 0; i < 256; ++i) {
    const size_t o = b0 + (size_t)i * 256 + tid;
    rs += fabsf(bf2f_((unsigned short)x2hi[o]) + bf2f_((unsigned short)x2lo[o]));
  }
  __shared__ float rc[256], rr[256];
  rc[tid] = cs; rr[tid] = rs;
  __syncthreads();
  for (int st = 128; st > 0; st >>= 1) {
    if (tid < st) {
      rc[tid] = fmaxf(rc[tid], rc[tid + st]);
      rr[tid] = fmaxf(rr[tid], rr[tid + st]);
    }
    __syncthreads();
  }
  if (tid == 0) {
    atomicMax((int*)&scal[0], __float_as_int(rc[0]));
    atomicMax((int*)&scal[1], __float_as_int(rr[0]));
  }
}

// --- z0 = x2^T/(cmax*rmax): A-form hi/lo + fp32, B-form (=x2/s) hi/lo -------
__global__ __launch_bounds__(256) void tscale2(const short* __restrict__ x2hi,
                                               const short* __restrict__ x2lo,
                                               const float* __restrict__ scal,
                                               short* __restrict__ zBhi,
                                               short* __restrict__ zBlo,
                                               short* __restrict__ zAhi,
                                               short* __restrict__ zAlo,
                                               float* __restrict__ zf) {
  const int g = blockIdx.x * 256 + threadIdx.x;
  const int j = g & 255, i = (g >> 8) & 255, bh = g >> 16;
  const float inv = 1.0f / (scal[0] * scal[1]);
  const float val = (bf2f_((unsigned short)x2hi[g]) +
                     bf2f_((unsigned short)x2lo[g])) * inv;
  const unsigned short h = f2bf_(val);
  const unsigned short lo = f2bf_(val - bf2f_(h));
  zBhi[g] = (short)h;
  zBlo[g] = (short)lo;
  const size_t tg = (size_t)bh * MM_STRIDE + (size_t)j * 256 + i;
  zAhi[tg] = (short)h;
  zAlo[tg] = (short)lo;
  zf[tg] = val;                     // fp32 A-form (exact E for step 4)
}

// --------- split-bf16 batched 256^3: C = alpha*Ef + beta*(A@B) --------------
// R4-verified (local optimum; do not restructure): 16x64 tiles, 512 blocks,
// staged gl16, 2 barriers/K-step; E read fp32 (exact).
__global__ __launch_bounds__(256) void pinv_mfma(const short* __restrict__ Ahi_g,
                                                 const short* __restrict__ Alo_g,
                                                 const short* __restrict__ Bhi_g,
                                                 const short* __restrict__ Blo_g,
                                                 const float* __restrict__ Ef,
                                                 float* __restrict__ Cf,
                                                 short* __restrict__ Chi,
                                                 short* __restrict__ Clo,
                                                 short* __restrict__ CThi,
                                                 short* __restrict__ CTlo,
                                                 float alpha, float beta,
                                                 int wantCf, int wantChl,
                                                 int wantT) {
  __shared__ short Ah[2048], Al[2048], Bh[2048], Bl[2048];
  __shared__ float Tbuf[64 * 68];
  const int tid = threadIdx.x;
  const int lane = tid & 63, w = tid >> 6;
  const int bid = blockIdx.x;
  const int xcd = bid & 7, y = bid >> 3;
  const int t16 = y & 15, bgrp = y >> 4;
  const int batch = bgrp * 8 + xcd;
  const int tm = t16 >> 2, tn = t16 & 3;
  const size_t bb = (size_t)batch * MM_STRIDE;
  const int ml = (tid >> 6) * 16 + (tid & 15), koff = ((tid >> 4) & 3) * 8;
  const short* sAh = Ahi_g + bb + (size_t)(tm * 64 + ml) * 256 + koff;
  const short* sAl = Alo_g + bb + (size_t)(tm * 64 + ml) * 256 + koff;
  const short* sBh = Bhi_g + bb + (size_t)(tn * 64 + ml) * 256 + koff;
  const short* sBl = Blo_g + bb + (size_t)(tn * 64 + ml) * 256 + koff;
  short* dAh = &Ah[w * 512];
  short* dAl = &Al[w * 512];
  short* dBh = &Bh[w * 512];
  short* dBl = &Bl[w * 512];
  f32x4 acc[4];
#pragma unroll
  for (int j = 0; j < 4; ++j) acc[j] = (f32x4){0.f, 0.f, 0.f, 0.f};
  for (int kt = 0; kt < 8; ++kt) {
    const int k0 = kt * 32;
    __syncthreads();
    gl16(sAh + k0, dAh);
    gl16(sAl + k0, dAl);
    gl16(sBh + k0, dBh);
    gl16(sBl + k0, dBl);
    __syncthreads();
    bf8 ah = *(const bf8*)&Ah[(w * 64 + lane) * 8];
    bf8 al = *(const bf8*)&Al[(w * 64 + lane) * 8];
#pragma unroll
    for (int j = 0; j < 4; ++j) {
      bf8 bh = *(const bf8*)&Bh[(j * 64 + lane) * 8];
      bf8 bl = *(const bf8*)&Bl[(j * 64 + lane) * 8];
      acc[j] = __builtin_amdgcn_mfma_f32_16x16x32_bf16(ah, bh, acc[j], 0, 0, 0);
      acc[j] = __builtin_amdgcn_mfma_f32_16x16x32_bf16(ah, bl, acc[j], 0, 0, 0);
      acc[j] = __builtin_amdgcn_mfma_f32_16x16x32_bf16(al, bh, acc[j], 0, 0, 0);
    }
  }
  const int qd = lane >> 4, c = lane & 15;
  float vals[4][4];
#pragma unroll
  for (int j = 0; j < 4; ++j) {
    const int col = tn * 64 + j * 16 + c;
#pragma unroll
    for (int r = 0; r < 4; ++r) {
      const int row = tm * 64 + w * 16 + qd * 4 + r;
      const size_t off = bb + (size_t)row * 256 + col;
      float e = 0.f;
      if (alpha != 0.0f) e = alpha * Ef[off];
      const float vv = e + beta * acc[j][r];
      vals[j][r] = vv;
      if (wantCf) Cf[off] = vv;
      if (wantChl) {
        const unsigned short h = f2bf_(vv);
        Chi[off] = (short)h;
        Clo[off] = (short)f2bf_(vv - bf2f_(h));
      }
    }
  }
  if (wantT) {
    __syncthreads();
#pragma unroll
    for (int j = 0; j < 4; ++j)
#pragma unroll
      for (int r = 0; r < 4; ++r)
        Tbuf[(j * 16 + c) * 68 + w * 16 + qd * 4 + r] = vals[j][r];
    __syncthreads();
    const int ctr = tid >> 2, seg = (tid & 3) * 16;
#pragma unroll
    for (int u = 0; u < 4; ++u) {
      float4 o = *(const float4*)&Tbuf[ctr * 68 + seg + u * 4];
      s4v hi, lo;
      unsigned short h;
      h = f2bf_(o.x); hi[0] = (short)h; lo[0] = (short)f2bf_(o.x - bf2f_(h));
      h = f2bf_(o.y); hi[1] = (short)h; lo[1] = (short)f2bf_(o.y - bf2f_(h));
      h = f2bf_(o.z); hi[2] = (short)h; lo[2] = (short)f2bf_(o.z - bf2f_(h));
      h = f2bf_(o.w); hi[3] = (short)h; lo[3] = (short)f2bf_(o.w - bf2f_(h));
      const size_t off = bb + (size_t)(tn * 64 + ctr) * 256 + tm * 64 + seg + u * 4;
      *(s4v*)&CThi[off] = hi;
      *(s4v*)&CTlo[off] = lo;
    }
  }
}

// ---- attn3 flash, per-wave (barrier-free): each wave owns 16 ql rows -------
__global__ __launch_bounds__(256) void attn3_flash(const float* __restrict__ ql,
                                                   const short* __restrict__ kb16,
                                                   const short* __restrict__ vT16,
                                                   float* __restrict__ opart,
                                                   float* __restrict__ mpart,
                                                   float* __restrict__ lpart) {
  const int kc = blockIdx.x;   // key chunk 0..3 (1024 keys each)
  const int rt = blockIdx.y;   // row tile 0..3 (64 rows each)
  const int bh = blockIdx.z;   // 0..31
  __shared__ short Pa[4][4096];  // per-wave 16 rows x 256 keys, A-frag order
  const int tid = threadIdx.x, lane = tid & 63, w = tid >> 6;
  const int qd = lane >> 4, c = lane & 15;
  const int rw = rt * 64 + w * 16;               // wave's first global row
  const float* qlp = ql + (size_t)bh * LM_STRIDE;
  const short* kp = kb16 + (size_t)bh * QKV_STRIDE;
  const short* vp = vT16 + (size_t)bh * QKV_STRIDE;
  short* Pw = &Pa[w][0];
  bf8 af[2];
#pragma unroll
  for (int st = 0; st < 2; ++st) {
    float4 x0 = *(const float4*)&qlp[(size_t)(rw + c) * 64 + st * 32 + qd * 8];
    float4 x1 = *(const float4*)&qlp[(size_t)(rw + c) * 64 + st * 32 + qd * 8 + 4];
    bf8 r;
    r[0] = (short)f2bf_(x0.x); r[1] = (short)f2bf_(x0.y);
    r[2] = (short)f2bf_(x0.z); r[3] = (short)f2bf_(x0.w);
    r[4] = (short)f2bf_(x1.x); r[5] = (short)f2bf_(x1.y);
    r[6] = (short)f2bf_(x1.z); r[7] = (short)f2bf_(x1.w);
    af[st] = r;
  }
  float m[4], l[4];
#pragma unroll
  for (int r = 0; r < 4; ++r) { m[r] = -3.0e38f; l[r] = 0.f; }
  f32x4 accO[4];
#pragma unroll
  for (int nb = 0; nb < 4; ++nb) accO[nb] = (f32x4){0.f, 0.f, 0.f, 0.f};
  for (int it = 0; it < 4; ++it) {
    const int kb0 = kc * 1024 + it * 256;
    f32x4 acc[16];
#pragma unroll
    for (int j = 0; j < 16; ++j) acc[j] = (f32x4){0.f, 0.f, 0.f, 0.f};
#pragma unroll
    for (int st = 0; st < 2; ++st)
#pragma unroll
      for (int j = 0; j < 16; ++j) {
        bf8 bfk = *(const bf8*)&kp[(size_t)(kb0 + j * 16 + c) * 64 + st * 32 + qd * 8];
        acc[j] = __builtin_amdgcn_mfma_f32_16x16x32_bf16(af[st], bfk, acc[j], 0, 0, 0);
      }
#pragma unroll
    for (int r = 0; r < 4; ++r) {
      float mx = acc[0][r];
#pragma unroll
      for (int j = 1; j < 16; ++j) mx = fmaxf(mx, acc[j][r]);
      mx = fmaxf(mx, __shfl_xor(mx, 1));
      mx = fmaxf(mx, __shfl_xor(mx, 2));
      mx = fmaxf(mx, __shfl_xor(mx, 4));
      mx = fmaxf(mx, __shfl_xor(mx, 8));
      const float mN = fmaxf(m[r], mx);
      const float a = __expf(m[r] - mN);
      m[r] = mN;
      l[r] *= a;
#pragma unroll
      for (int nb = 0; nb < 4; ++nb) accO[nb][r] *= a;
      float s = 0.f;
#pragma unroll
      for (int j = 0; j < 16; ++j) {
        const float e = __expf(acc[j][r] - mN);
        acc[j][r] = e;
        s += e;
      }
      s += __shfl_xor(s, 1);
      s += __shfl_xor(s, 2);
      s += __shfl_xor(s, 4);
      s += __shfl_xor(s, 8);
      l[r] += s;
    }
#pragma unroll
    for (int j = 0; j < 16; ++j) {
      const int kcol = j * 16 + c;
      const int kb8 = kcol >> 5;
      const int la_base = 16 * ((kcol >> 3) & 3);
      const int j8 = kcol & 7;
#pragma unroll
      for (int r = 0; r < 4; ++r) {
        const int rl = qd * 4 + r;
        Pw[(kb8 * 64 + la_base + rl) * 8 + j8] = (short)f2bf_(acc[j][r]);
      }
    }
#pragma unroll
    for (int kbk = 0; kbk < 8; ++kbk) {
      bf8 ap = *(const bf8*)&Pw[(kbk * 64 + lane) * 8];
#pragma unroll
      for (int nb = 0; nb < 4; ++nb) {
        bf8 bv = *(const bf8*)&vp[(size_t)(nb * 16 + c) * 4096 + kb0 + kbk * 32 + qd * 8];
        accO[nb] = __builtin_amdgcn_mfma_f32_16x16x32_bf16(ap, bv, accO[nb], 0, 0, 0);
      }
    }
  }
  const size_t ob = ((size_t)kc * 32 + bh) * 256 + rt * 64;
#pragma unroll
  for (int nb = 0; nb < 4; ++nb)
#pragma unroll
    for (int r = 0; r < 4; ++r)
      opart[(ob + w * 16 + qd * 4 + r) * 64 + nb * 16 + c] = accO[nb][r];
  if (c == 0) {
#pragma unroll
    for (int r = 0; r < 4; ++r) {
      mpart[ob + w * 16 + qd * 4 + r] = m[r];
      lpart[ob + w * 16 + qd * 4 + r] = l[r];
    }
  }
}

// ------- merge the 4 key-chunk partials -> avT hi/lo bf16 [bh][d][row] ------
__global__ __launch_bounds__(256) void attn3_merge(const float* __restrict__ opart,
                                                   const float* __restrict__ mpart,
                                                   const float* __restrict__ lpart,
                                                   short* __restrict__ avth,
                                                   short* __restrict__ avtl) {
  const int g = blockIdx.x * 256 + threadIdx.x;   // 524288 = 32*256*64
  const int d = g & 63;
  const int idx = g >> 6;                          // bh*256+row
  const int bh = idx >> 8, row = idx & 255;
  const float m0 = mpart[idx], m1 = mpart[8192 + idx],
              m2 = mpart[16384 + idx], m3 = mpart[24576 + idx];
  const float mx = fmaxf(fmaxf(m0, m1), fmaxf(m2, m3));
  const float w0 = __expf(m0 - mx), w1 = __expf(m1 - mx),
              w2 = __expf(m2 - mx), w3 = __expf(m3 - mx);
  const float l = lpart[idx] * w0 + lpart[8192 + idx] * w1 +
                  lpart[16384 + idx] * w2 + lpart[24576 + idx] * w3;
  const float o = opart[(size_t)idx * 64 + d] * w0 +
                  opart[524288 + (size_t)idx * 64 + d] * w1 +
                  opart[1048576 + (size_t)idx * 64 + d] * w2 +
                  opart[1572864 + (size_t)idx * 64 + d] * w3;
  const float val = o / l;
  const unsigned short h = f2bf_(val);
  const size_t o2 = ((size_t)bh * 64 + d) * 256 + row;
  avth[o2] = (short)h;
  avtl[o2] = (short)f2bf_(val - bf2f_(h));
}

// ------- w2^T = (z_final @ av)^T via split-bf16 MFMA ------------------------
__global__ __launch_bounds__(256) void zav_mfma(const short* __restrict__ zAhi,
                                                const short* __restrict__ zAlo,
                                                const short* __restrict__ avth,
                                                const short* __restrict__ avtl,
                                                short* __restrict__ w2tb16) {
  __shared__ short Tb[64 * 68];
  const int rt = blockIdx.x;      // 0..3
  const int bh = blockIdx.y;      // 0..31
  const int tid = threadIdx.x, lane = tid & 63, w = tid >> 6;
  const int qd = lane >> 4, c = lane & 15;
  const size_t zoff = (size_t)bh * MM_STRIDE + (size_t)(rt * 64 + w * 16 + c) * 256;
  const short* zh = zAhi + zoff;
  const short* zl = zAlo + zoff;
  const short* ahp = avth + (size_t)bh * LM_STRIDE;
  const short* alp = avtl + (size_t)bh * LM_STRIDE;
  f32x4 acc[4];
#pragma unroll
  for (int j = 0; j < 4; ++j) acc[j] = (f32x4){0.f, 0.f, 0.f, 0.f};
  for (int kt = 0; kt < 8; ++kt) {
    const int k0 = kt * 32 + qd * 8;
    bf8 ah = *(const bf8*)&zh[k0];
    bf8 al = *(const bf8*)&zl[k0];
#pragma unroll
    for (int j = 0; j < 4; ++j) {
      bf8 bhj = *(const bf8*)&ahp[(size_t)(j * 16 + c) * 256 + k0];
      bf8 blj = *(const bf8*)&alp[(size_t)(j * 16 + c) * 256 + k0];
      acc[j] = __builtin_amdgcn_mfma_f32_16x16x32_bf16(ah, bhj, acc[j], 0, 0, 0);
      acc[j] = __builtin_amdgcn_mfma_f32_16x16x32_bf16(ah, blj, acc[j], 0, 0, 0);
      acc[j] = __builtin_amdgcn_mfma_f32_16x16x32_bf16(al, bhj, acc[j], 0, 0, 0);
    }
  }
#pragma unroll
  for (int j = 0; j < 4; ++j)
#pragma unroll
    for (int r = 0; r < 4; ++r)
      Tb[(j * 16 + c) * 68 + w * 16 + qd * 4 + r] = (short)f2bf_(acc[j][r]);
  __syncthreads();
  const int col = tid >> 2, rs = (tid & 3) * 16;
  short* dst = &w2tb16[(size_t)bh * LM_STRIDE + (size_t)col * 256 + rt * 64 + rs];
  const short* srcp = &Tb[col * 68 + rs];
#pragma unroll
  for (int u = 0; u < 4; ++u) *(s4v*)&dst[u * 4] = *(const s4v*)&srcp[u * 4];
}

// -- attn1+conv: BARRIER-FREE wave-private (attn3 structure) -----------------
// Block = 64 rows (grid 2048, XCD remap: 4 bh/XCD); wave w owns 16 rows:
// QK over 256 landmarks -> in-register softmax -> wave-private P -> PV(w2)
// + banded conv MFMA. Zero __syncthreads.
__global__ __launch_bounds__(256) void attn1_conv_mfma(const short* __restrict__ qb16,
                                                       const short* __restrict__ klb16,
                                                       const short* __restrict__ w2tb16,
                                                       const short* __restrict__ vT16,
                                                       const float* __restrict__ cw,
                                                       short* __restrict__ ohb16) {
  __shared__ short Pa[4][4096];   // per-wave 16 rows x 256 landmarks, A-frag order
  __shared__ float cwS[33];
  const int tid = threadIdx.x, lane = tid & 63, w = tid >> 6;
  const int qd = lane >> 4, c = lane & 15;
  const int lin = blockIdx.x;                 // 0..2047
  const int xcd = lin & 7;
  const int idx = lin >> 3;                   // 0..255
  const int bh = xcd * 4 + (idx >> 6);        // 4 bh per XCD
  const int r0 = (idx & 63) * 64;
  const int rw = r0 + w * 16;                 // wave's first global row
  const short* qp = qb16 + (size_t)bh * QKV_STRIDE;
  const short* klp = klb16 + (size_t)bh * LM_STRIDE;
  const short* w2p = w2tb16 + (size_t)bh * LM_STRIDE;
  const short* vp = vT16 + (size_t)bh * QKV_STRIDE;
  short* Pw = &Pa[w][0];
  // each wave writes cwS redundantly (same values -> benign race, no barrier)
  if (lane < 33) cwS[lane] = cw[(bh & 7) * 33 + lane];
  // q A-frags for the wave's 16 rows
  bf8 af[2];
#pragma unroll
  for (int st = 0; st < 2; ++st)
    af[st] = *(const bf8*)&qp[(size_t)(rw + c) * 64 + st * 32 + qd * 8];
  // QK^T over 256 landmarks (16 col-tiles)
  f32x4 acc[16];
#pragma unroll
  for (int j = 0; j < 16; ++j) acc[j] = (f32x4){0.f, 0.f, 0.f, 0.f};
#pragma unroll
  for (int st = 0; st < 2; ++st)
#pragma unroll
    for (int j = 0; j < 16; ++j) {
      bf8 bfk = *(const bf8*)&klp[(size_t)(j * 16 + c) * 64 + st * 32 + qd * 8];
      acc[j] = __builtin_amdgcn_mfma_f32_16x16x32_bf16(af[st], bfk, acc[j], 0, 0, 0);
    }
  // plain softmax per row (rows qd*4+r; reduce over the 16 c-lanes)
#pragma unroll
  for (int r = 0; r < 4; ++r) {
    float mx = acc[0][r];
#pragma unroll
    for (int j = 1; j < 16; ++j) mx = fmaxf(mx, acc[j][r]);
    mx = fmaxf(mx, __shfl_xor(mx, 1));
    mx = fmaxf(mx, __shfl_xor(mx, 2));
    mx = fmaxf(mx, __shfl_xor(mx, 4));
    mx = fmaxf(mx, __shfl_xor(mx, 8));
    float s = 0.f;
#pragma unroll
    for (int j = 0; j < 16; ++j) {
      const float e = __expf(acc[j][r] - mx);
      acc[j][r] = e;
      s += e;
    }
    s += __shfl_xor(s, 1);
    s += __shfl_xor(s, 2);
    s += __shfl_xor(s, 4);
    s += __shfl_xor(s, 8);
    const float inv = 1.0f / s;
#pragma unroll
    for (int j = 0; j < 16; ++j) acc[j][r] *= inv;
  }
  // P -> wave-private LDS in A-frag order (k = landmark)
#pragma unroll
  for (int j = 0; j < 16; ++j) {
    const int kcol = j * 16 + c;
    const int kb8 = kcol >> 5;
    const int la_base = 16 * ((kcol >> 3) & 3);
    const int j8 = kcol & 7;
#pragma unroll
    for (int r = 0; r < 4; ++r) {
      const int rl = qd * 4 + r;
      Pw[(kb8 * 64 + la_base + rl) * 8 + j8] = (short)f2bf_(acc[j][r]);
    }
  }
  // O = P @ w2 (no barrier: same-wave LDS dependency)
  f32x4 accO[4];
#pragma unroll
  for (int nb = 0; nb < 4; ++nb) accO[nb] = (f32x4){0.f, 0.f, 0.f, 0.f};
#pragma unroll
  for (int kbk = 0; kbk < 8; ++kbk) {
    bf8 ap = *(const bf8*)&Pw[(kbk * 64 + lane) * 8];
#pragma unroll
    for (int nb = 0; nb < 4; ++nb) {
      bf8 bv = *(const bf8*)&w2p[(size_t)(nb * 16 + c) * 256 + kbk * 32 + qd * 8];
      accO[nb] = __builtin_amdgcn_mfma_f32_16x16x32_bf16(ap, bv, accO[nb], 0, 0, 0);
    }
  }
  // conv residual via banded MFMA: out += Band[16x64] @ Vwin[64x64]
  {
    bf8 ba[2];
    const int rl = lane & 15;                 // A m-index = row within wave tile
#pragma unroll
    for (int kb = 0; kb < 2; ++kb) {
#pragma unroll
      for (int e = 0; e < 8; ++e) {
        const int kk = kb * 32 + qd * 8 + e;
        const int t = kk - rl;
        const int s = rw - 16 + kk;
        const float bv = (t >= 0 && t < 33 && s >= 0 && s < 4096) ? cwS[t] : 0.f;
        ba[kb][e] = (short)f2bf_(bv);
      }
    }
#pragma unroll
    for (int kb = 0; kb < 2; ++kb) {
      int s0 = rw - 16 + kb * 32 + qd * 8;
      s0 = s0 < 0 ? 0 : (s0 > 4088 ? 4088 : s0);
#pragma unroll
      for (int nb = 0; nb < 4; ++nb) {
        bf8 bv = *(const bf8*)&vp[(size_t)(nb * 16 + c) * 4096 + s0];
        accO[nb] = __builtin_amdgcn_mfma_f32_16x16x32_bf16(ba[kb], bv, accO[nb], 0, 0, 0);
      }
    }
  }
  short* ohp = (short*)ohb16 + (size_t)bh * QKV_STRIDE;
#pragma unroll
  for (int nb = 0; nb < 4; ++nb)
#pragma unroll
    for (int r = 0; r < 4; ++r) {
      const int row = rw + qd * 4 + r;
      ohp[(size_t)row * 64 + nb * 16 + c] = (short)f2bf_(accO[nb][r]);
    }
}

// ------- out = concat_heads(oh_bf16) @ w_out + b_out (MFMA) -----------------
// global_load_lds staging; XCD-swizzled 1-D grid (512 = 8*64).
__global__ __launch_bounds__(256) void gemm_out_mfma(const short* __restrict__ ohb16,
                                                     const short* __restrict__ wT,
                                                     const float* __restrict__ bias,
                                                     float* __restrict__ out) {
  __shared__ short As[4096];
  __shared__ short Bs[4096];
  const int tid = threadIdx.x;
  const int lane = tid & 63, w = tid >> 6;
  const int wr = w >> 1, wc = w & 1;
  const int bid = (blockIdx.x & 7) * 64 + (blockIdx.x >> 3);   // 512 = 8*64
  const int bn = bid & 3, bm = bid >> 2;
  const int gm0 = bm * 128, gn0 = bn * 128;
  const int mA0 = (tid >> 6) * 16 + (tid & 15), kA0 = ((tid >> 4) & 3) * 8;
  const int s1 = tid + 256;
  const int mA1 = (s1 >> 6) * 16 + (s1 & 15), kA1 = ((s1 >> 4) & 3) * 8;
  const int b0r = (gm0 + mA0) >> 12, seq0 = (gm0 + mA0) & 4095;
  const int b1r = (gm0 + mA1) >> 12, seq1 = (gm0 + mA1) & 4095;
  short* dA0 = &As[w * 512];
  short* dA1 = &As[2048 + w * 512];
  short* dB0 = &Bs[w * 512];
  short* dB1 = &Bs[2048 + w * 512];
  f32x4 acc[4][4];
#pragma unroll
  for (int i = 0; i < 4; ++i)
#pragma unroll
    for (int j = 0; j < 4; ++j) acc[i][j] = (f32x4){0.f, 0.f, 0.f, 0.f};
  for (int kt = 0; kt < 16; ++kt) {
    const int ka = kt * 32 + kA0, kb = kt * 32 + kA1;
    __syncthreads();
    gl16(&ohb16[(size_t)(b0r * 8 + (ka >> 6)) * QKV_STRIDE + (size_t)seq0 * 64 + (ka & 63)], dA0);
    gl16(&ohb16[(size_t)(b1r * 8 + (kb >> 6)) * QKV_STRIDE + (size_t)seq1 * 64 + (kb & 63)], dA1);
    gl16(&wT[(size_t)(gn0 + mA0) * 512 + ka], dB0);
    gl16(&wT[(size_t)(gn0 + mA1) * 512 + kb], dB1);
    __syncthreads();
    bf8 af[4], bfr[4];
#pragma unroll
    for (int i = 0; i < 4; ++i) {
      af[i] = *(const bf8*)&As[((wr * 4 + i) * 64 + lane) * 8];
      bfr[i] = *(const bf8*)&Bs[((wc * 4 + i) * 64 + lane) * 8];
    }
#pragma unroll
    for (int i = 0; i < 4; ++i)
#pragma unroll
      for (int j = 0; j < 4; ++j)
        acc[i][j] = __builtin_amdgcn_mfma_f32_16x16x32_bf16(af[i], bfr[j], acc[i][j], 0, 0, 0);
  }
  const int qd = lane >> 4, c = lane & 15;
#pragma unroll
  for (int i = 0; i < 4; ++i)
#pragma unroll
    for (int j = 0; j < 4; ++j) {
      const int col = gn0 + wc * 64 + j * 16 + c;
      const float bval = bias[col];
#pragma unroll
      for (int r = 0; r < 4; ++r) {
        const int row = gm0 + wr * 64 + i * 16 + qd * 4 + r;
        out[(size_t)row * 512 + col] = acc[i][j][r] + bval;
      }
    }
}

// ---------------------------------------------------------------------------
extern "C" void kernel_launch(void* const* d_in, const int* in_sizes, int n_in,
                              void* d_out, int out_size, void* d_ws, size_t ws_size,
                              hipStream_t stream) {
  const float* x    = (const float*)d_in[0];
  const float* wqkv = (const float*)d_in[1];
  const float* wout = (const float*)d_in[2];
  const float* bout = (const float*)d_in[3];
  const float* cw   = (const float*)d_in[4];
  float* out = (float*)d_out;

  float* w = (float*)d_ws;
  // ---- compact layout: 37,486,656 floats total (~150 MB) ----
  short* qb16   = (short*)(w);              // [32,4096,64] bf16   (4194304 fl)
  short* kb16   = (short*)(w + 4194304);
  short* vT16   = (short*)(w + 8388608);    // [32,64,4096] bf16
  // region 12582912..16777216 (4194304 fl), time-multiplexed:
  short* xb16   = (short*)(w + 12582912);   // phase 1: x bf16 (dead after qkv)
  float* z0f    = w + 12582912;             // phase 2: fp32 z ping (2097152)
  float* z1f    = w + 14680064;             // phase 2: fp32 z pong (2097152)
  float* opart  = w + 12582912;             // phase 3: [4,32,256,64] (2097152)
  short* ohb16  = (short*)(w + 12582912);   // phase 4: oh bf16 (4194304 fl)
  float* ql     = w + 16777216;             // [32,256,64] fp32 (524288)
  float* kl     = w + 17301504;
  short* klb16  = (short*)(w + 17825792);   // (262144 fl)
  short* x2hi   = (short*)(w + 18087936);   // hi/lo pairs: 1048576 fl each
  short* x2lo   = (short*)(w + 19136512);
  float* xzf    = w + 20185088;             // fp32 xz (E steps 2,3) (2097152)
  short* xzAhi  = (short*)(w + 22282240);
  short* xzAlo  = (short*)(w + 23330816);
  short* xzBhi  = (short*)(w + 24379392);   // also u2B (xzB dead after step 2)
  short* xzBlo  = (short*)(w + 25427968);
  short* u1Bhi  = (short*)(w + 26476544);
  short* u1Blo  = (short*)(w + 27525120);
  short* z0Ahi  = (short*)(w + 28573696);
  short* z0Alo  = (short*)(w + 29622272);
  short* z0Bhi  = (short*)(w + 30670848);
  short* z0Blo  = (short*)(w + 31719424);
  short* z1Ahi  = (short*)(w + 32768000);
  short* z1Alo  = (short*)(w + 33816576);
  short* z1Bhi  = (short*)(w + 34865152);
  short* z1Blo  = (short*)(w + 35913728);
  float* scal   = w + 36962304;             // [2]
  short* wqkvT  = (short*)(w + 36962368);   // [1536,512] bf16 (393216 fl)
  short* woutT  = (short*)(w + 37355584);   // [512,512] bf16 (131072 fl)
  // end: 37486656 floats (~150 MB)
  // post-pinv aliases (xzf/xzA/u1B dead after the loop):
  short* avth   = (short*)(w + 20185088);   // [32,64,256] bf16 (262144 fl)
  short* avtl   = (short*)(w + 20447232);
  short* w2tb16 = (short*)(w + 20709376);   // [32,256,64] bf16 (262144 fl)
  float* mpart  = w + 26476544;             // [4,32,256] (32768 fl, in u1Bhi)
  float* lpart  = w + 26509312;

  zero_scal<<<1, 64, 0, stream>>>(scal);
  transpose_bf16<<<dim3(48, 16), 256, 0, stream>>>(wqkv, wqkvT, 512, 1536);
  transpose_bf16<<<dim3(16, 16), 256, 0, stream>>>(wout, woutT, 512, 512);
  x_to_bf16<<<2048, 256, 0, stream>>>(x, xb16);
  gemm_qkv_mfma<<<1536, 256, 0, stream>>>(xb16, wqkvT, qb16, kb16, vT16);
  lmk_mean<<<2048, 256, 0, stream>>>(qb16, kb16, ql, kl, klb16);
  sim2_softmax<<<512, 256, 0, stream>>>(ql, kl, x2hi, x2lo);
  colrow_max<<<32, 256, 0, stream>>>(x2hi, x2lo, scal);
  // overwrites xb16 region with z0f -- xb16 dead after gemm_qkv.
  tscale2<<<8192, 256, 0, stream>>>(x2hi, x2lo, scal, z0Bhi, z0Blo, z0Ahi, z0Alo, z0f);

  float *zcf = z0f, *znf = z1f;
  short *zAh = z0Ahi, *zAl = z0Alo, *zBh = z0Bhi, *zBl = z0Blo;
  short *nAh = z1Ahi, *nAl = z1Alo, *nBh = z1Bhi, *nBl = z1Blo;
  for (int it = 0; it < 6; ++it) {
    const int nl = (it < 5) ? 1 : 0;   // final iter: fp32 zn + B-form unused
    // xz = x2 @ z         (need xz fp32 + A-form hi/lo + B-form hi/lo)
    pinv_mfma<<<512, 256, 0, stream>>>(x2hi, x2lo, zBh, zBl, xzf,
                                       xzf, xzAhi, xzAlo, xzBhi, xzBlo,
                                       0.f, 1.f, 1, 1, 1);
    // u1 = 7*xz - xz@xz   (only u1^T hi/lo needed)
    pinv_mfma<<<512, 256, 0, stream>>>(xzAhi, xzAlo, xzBhi, xzBlo, xzf,
                                       znf, u1Bhi, u1Blo, u1Bhi, u1Blo,
                                       7.f, -1.f, 0, 0, 1);
    // u2 = 15*xz - xz@u1  (only u2^T hi/lo needed; overwrites xzB slots)
    pinv_mfma<<<512, 256, 0, stream>>>(xzAhi, xzAlo, u1Bhi, u1Blo, xzf,
                                       znf, xzBhi, xzBlo, xzBhi, xzBlo,
                                       15.f, -1.f, 0, 0, 1);
    // zn = 3.25*z - 0.25*z@u2  (fp32 + A hi/lo + B hi/lo; trimmed on it=5)
    pinv_mfma<<<512, 256, 0, stream>>>(zAh, zAl, xzBhi, xzBlo, zcf,
                                       znf, nAh, nAl, nBh, nBl,
                                       3.25f, -0.25f, nl, 1, nl);
    float* tf = zcf; zcf = znf; znf = tf;
    short* t;
    t = zAh; zAh = nAh; nAh = t;  t = zAl; zAl = nAl; nAl = t;
    t = zBh; zBh = nBh; nBh = t;  t = zBl; zBl = nBl; nBl = t;
  }
  // zAh/zAl == z0A here (6 swaps). z0f/z1f/xzf/xzA/u1B dead -> aliases live.
  // opart overwrites z0f region (dead); read by merge before ohb16 is written.

  attn3_flash<<<dim3(4, 4, 32), 256, 0, stream>>>(ql, kb16, vT16, opart, mpart, lpart);
  attn3_merge<<<2048, 256, 0, stream>>>(opart, mpart, lpart, avth, avtl);
  zav_mfma<<<dim3(4, 32), 256, 0, stream>>>(zAh, zAl, avth, avtl, w2tb16);
  // attn1_conv writes ohb16 over the opart/z0f/z1f region (all dead now).
  attn1_conv_mfma<<<2048, 256, 0, stream>>>(qb16, klb16, w2tb16, vT16, cw, ohb16);
  gemm_out_mfma<<<512, 256, 0, stream>>>(ohb16, woutT, bout, out);
}

// Round 10
// 720.918 us; speedup vs baseline: 1.0934x; 1.0934x over previous
//
#include <hip/hip_runtime.h>
#include <math.h>

// ---------------------------------------------------------------------------
// NystromAttention round 17: R8 base (784us; attn1_conv reverted to the
// verified 32-row/38%-occupancy version) + precision-staged Newton-Schulz:
// pinv iterations 0-3 run hi-only bf16 (1 MFMA per j, stage 2 buffers),
// iterations 4-5 keep the full split-bf16 (3-MFMA) path. NS self-corrects:
// the last two precise 4th-order iterations contract bf16-grade residual to
// fp32-grade. All lo/fp32 side-buffers still written from exact fp32 vv, so
// the transition is seamless. Keeps R9's final-iter dead-output trim.
// b=4 n=4096 dim=512 h=8 d=64 m=256, l=16, iters=6, conv k=33.
// MFMA 16x16x32_bf16 layouts (HW-verified per guide):
//   A: m=lane&15, k=(lane>>4)*8+j    B: n=lane&15, k=(lane>>4)*8+j
//   C/D: col=lane&15, row=(lane>>4)*4+reg
// ---------------------------------------------------------------------------

#define QKV_STRIDE 262144   // 4096*64 per (b,h)
#define LM_STRIDE 16384     // 256*64
#define MM_STRIDE 65536     // 256*256

typedef float f32x4 __attribute__((ext_vector_type(4)));
typedef short bf8 __attribute__((ext_vector_type(8)));   // 8 bf16 in 4 VGPRs
typedef short s4v __attribute__((ext_vector_type(4)));

__device__ __forceinline__ unsigned short f2bf_(float f) {
  unsigned u = __float_as_uint(f);
  u += 0x7FFFu + ((u >> 16) & 1u);   // RNE
  return (unsigned short)(u >> 16);
}
__device__ __forceinline__ float bf2f_(unsigned short h) {
  return __uint_as_float(((unsigned)h) << 16);
}

// async global->LDS, 16B per lane; LDS dest must be wave-uniform base.
__device__ __forceinline__ void gl16(const short* g, short* l) {
  __builtin_amdgcn_global_load_lds(
      (const __attribute__((address_space(1))) unsigned int*)g,
      (__attribute__((address_space(3))) unsigned int*)l, 16, 0, 0);
}

__global__ __launch_bounds__(256) void zero_scal(float* scal) {
  if (threadIdx.x < 2) scal[threadIdx.x] = 0.0f;
}

// ---------------- x (fp32) -> xb16 (bf16 row-major) -------------------------
__global__ __launch_bounds__(256) void x_to_bf16(const float* __restrict__ x,
                                                 short* __restrict__ xb) {
  const int g = blockIdx.x * 256 + threadIdx.x;   // 524288 threads
  const float4* xp = (const float4*)x;
#pragma unroll
  for (int u = 0; u < 4; ++u) {
    const size_t i4 = (size_t)u * 524288 + g;
    float4 v = xp[i4];
    s4v o;
    o[0] = (short)f2bf_(v.x); o[1] = (short)f2bf_(v.y);
    o[2] = (short)f2bf_(v.z); o[3] = (short)f2bf_(v.w);
    *(s4v*)&xb[i4 * 4] = o;
  }
}

// ------------- transpose + fp32->bf16: dst[C][R] = bf16(src[R][C]) ----------
__global__ __launch_bounds__(256) void transpose_bf16(const float* __restrict__ src,
                                                      short* __restrict__ dst,
                                                      int R, int C) {
  __shared__ float T[32][33];
  const int t = threadIdx.x;
  const int c0 = blockIdx.x * 32, r0 = blockIdx.y * 32;
  const int tr = t >> 3, tc = (t & 7) << 2;
  float4 vsrc = *(const float4*)&src[(size_t)(r0 + tr) * C + c0 + tc];
  T[tr][tc + 0] = vsrc.x; T[tr][tc + 1] = vsrc.y;
  T[tr][tc + 2] = vsrc.z; T[tr][tc + 3] = vsrc.w;
  __syncthreads();
  s4v o;
  o[0] = (short)f2bf_(T[tc + 0][tr]);
  o[1] = (short)f2bf_(T[tc + 1][tr]);
  o[2] = (short)f2bf_(T[tc + 2][tr]);
  o[3] = (short)f2bf_(T[tc + 3][tr]);
  *(s4v*)&dst[(size_t)(c0 + tr) * R + r0 + tc] = o;
}

// ---- qkv = xb16 @ w_qkv via MFMA -> qb16/kb16 row-major, vT16 transposed ---
// global_load_lds staging; XCD-swizzled 1-D grid (bijective, 1536 = 8*192).
__global__ __launch_bounds__(256) void gemm_qkv_mfma(const short* __restrict__ xb,
                                                     const short* __restrict__ wT,
                                                     short* __restrict__ qb16,
                                                     short* __restrict__ kb16,
                                                     short* __restrict__ vT16) {
  __shared__ short SMEM[17408];   // As[0..4095], Bs[4096..8191]; v: stage 128x136
  short* As = SMEM;
  short* Bs = SMEM + 4096;
  const int tid = threadIdx.x;
  const int lane = tid & 63, w = tid >> 6;
  const int wr = w >> 1, wc = w & 1;
  const int bid = (blockIdx.x & 7) * 192 + (blockIdx.x >> 3);  // 1536 = 8*192
  const int bn = bid % 12, bm = bid / 12;
  const int gm0 = bm * 128, gn0 = bn * 128;
  const int mA0 = (tid >> 6) * 16 + (tid & 15), kA0 = ((tid >> 4) & 3) * 8;
  const int s1 = tid + 256;
  const int mA1 = (s1 >> 6) * 16 + (s1 & 15), kA1 = ((s1 >> 4) & 3) * 8;
  const short* srcA0 = &xb[(size_t)(gm0 + mA0) * 512 + kA0];
  const short* srcA1 = &xb[(size_t)(gm0 + mA1) * 512 + kA1];
  const short* srcB0 = &wT[(size_t)(gn0 + mA0) * 512 + kA0];
  const short* srcB1 = &wT[(size_t)(gn0 + mA1) * 512 + kA1];
  short* dA0 = &As[w * 512];
  short* dA1 = &As[2048 + w * 512];
  short* dB0 = &Bs[w * 512];
  short* dB1 = &Bs[2048 + w * 512];
  f32x4 acc[4][4];
#pragma unroll
  for (int i = 0; i < 4; ++i)
#pragma unroll
    for (int j = 0; j < 4; ++j) acc[i][j] = (f32x4){0.f, 0.f, 0.f, 0.f};
  for (int kt = 0; kt < 16; ++kt) {
    const int k0 = kt * 32;
    __syncthreads();                 // prev-step LDS reads done before overwrite
    gl16(srcA0 + k0, dA0);
    gl16(srcA1 + k0, dA1);
    gl16(srcB0 + k0, dB0);
    gl16(srcB1 + k0, dB1);
    __syncthreads();                 // drains vmcnt -> tile resident
    bf8 af[4], bf[4];
#pragma unroll
    for (int i = 0; i < 4; ++i) {
      af[i] = *(const bf8*)&As[((wr * 4 + i) * 64 + lane) * 8];
      bf[i] = *(const bf8*)&Bs[((wc * 4 + i) * 64 + lane) * 8];
    }
#pragma unroll
    for (int i = 0; i < 4; ++i)
#pragma unroll
      for (int j = 0; j < 4; ++j)
        acc[i][j] = __builtin_amdgcn_mfma_f32_16x16x32_bf16(af[i], bf[j], acc[i][j], 0, 0, 0);
  }
  const int which = bn >> 2;  // 0:q 1:k 2:v
  const int qd = lane >> 4, c = lane & 15;
  if (which < 2) {
    short* dst = which == 0 ? qb16 : kb16;
    const float scale = which == 0 ? 0.125f : 1.0f;
#pragma unroll
    for (int i = 0; i < 4; ++i)
#pragma unroll
      for (int j = 0; j < 4; ++j) {
        const int col = gn0 + wc * 64 + j * 16 + c;
        const int head = (col >> 6) & 7, dd = col & 63;
#pragma unroll
        for (int r = 0; r < 4; ++r) {
          const int row = gm0 + wr * 64 + i * 16 + qd * 4 + r;
          const int b = row >> 12, seq = row & 4095;
          dst[(size_t)(b * 8 + head) * QKV_STRIDE + seq * 64 + dd] =
              (short)f2bf_(acc[i][j][r] * scale);
        }
      }
  } else {
    __syncthreads();
#pragma unroll
    for (int i = 0; i < 4; ++i)
#pragma unroll
      for (int j = 0; j < 4; ++j) {
        const int colL = wc * 64 + j * 16 + c;
#pragma unroll
        for (int r = 0; r < 4; ++r) {
          const int rowL = wr * 64 + i * 16 + qd * 4 + r;
          SMEM[colL * 136 + rowL] = (short)f2bf_(acc[i][j][r]);
        }
      }
    __syncthreads();
    const int b = gm0 >> 12, seq0 = gm0 & 4095;
    const int dcol = tid >> 1, half = tid & 1;
    const int col = gn0 + dcol;
    const int head = (col >> 6) & 7, d = col & 63;
    const short* src = &SMEM[dcol * 136 + half * 64];
    short* dstp = &vT16[(size_t)(b * 8 + head) * QKV_STRIDE + (size_t)d * 4096 +
                        seq0 + half * 64];
#pragma unroll
    for (int u = 0; u < 16; ++u) *(s4v*)&dstp[u * 4] = *(const s4v*)&src[u * 4];
  }
}

// ---------------- landmark means (bf16 in, fp32 + bf16-kl out) --------------
__global__ __launch_bounds__(256) void lmk_mean(const short* __restrict__ qb16,
                                                const short* __restrict__ kb16,
                                                float* __restrict__ ql,
                                                float* __restrict__ kl,
                                                short* __restrict__ klb16) {
  const int g = blockIdx.x * 256 + threadIdx.x;
  const int dd = g & 63, mi = (g >> 6) & 255, bh = g >> 14;
  const size_t base = (size_t)bh * QKV_STRIDE + mi * 1024 + dd;
  float sq = 0.f, sk = 0.f;
#pragma unroll
  for (int jj = 0; jj < 16; ++jj) {
    sq += bf2f_((unsigned short)qb16[base + jj * 64]);
    sk += bf2f_((unsigned short)kb16[base + jj * 64]);
  }
  const float qv = sq * 0.0625f, kv = sk * 0.0625f;
  ql[g] = qv;
  kl[g] = kv;
  klb16[g] = (short)f2bf_(kv);
}

// ---------------- sim2 = ql @ kl^T, softmax -> x2 hi/lo ---------------------
__global__ __launch_bounds__(256) void sim2_softmax(const float* __restrict__ ql,
                                                    const float* __restrict__ kl,
                                                    short* __restrict__ x2hi,
                                                    short* __restrict__ x2lo) {
  const int blk = blockIdx.x;
  const int bh = blk >> 4, rg = blk & 15;
  __shared__ float Qs[16][64];
  __shared__ float Ks[64][68];
  __shared__ float S[16][257];
  __shared__ float red[16][17];
  __shared__ float rowinv[16];
  const int tid = threadIdx.x;
  const int r = tid >> 4, jc = tid & 15;
#pragma unroll
  for (int u = 0; u < 4; ++u) {
    int t2 = tid + u * 256;
    Qs[t2 >> 6][t2 & 63] =
        ql[(size_t)bh * LM_STRIDE + (rg * 16 + (t2 >> 6)) * 64 + (t2 & 63)];
  }
  for (int c = 0; c < 4; ++c) {
    __syncthreads();
#pragma unroll
    for (int u = 0; u < 4; ++u) {
      int t4 = tid + u * 256;
      int row = t4 >> 4, c4 = (t4 & 15) << 2;
      *(float4*)&Ks[row][c4] =
          *(const float4*)&kl[(size_t)bh * LM_STRIDE + (c * 64 + row) * 64 + c4];
    }
    __syncthreads();
#pragma unroll
    for (int s = 0; s < 4; ++s) {
      const int jj = jc + (s << 4);
      float acc = 0.f;
#pragma unroll
      for (int k4 = 0; k4 < 16; ++k4) {
        const float4 a = *(const float4*)&Qs[r][k4 << 2];
        const float4 bb = *(const float4*)&Ks[jj][k4 << 2];
        acc += a.x * bb.x + a.y * bb.y + a.z * bb.z + a.w * bb.w;
      }
      S[r][(c << 6) + jj] = acc;
    }
  }
  __syncthreads();
  float pm = -3.0e38f;
#pragma unroll
  for (int u = 0; u < 16; ++u) pm = fmaxf(pm, S[r][jc + (u << 4)]);
  red[r][jc] = pm;
  __syncthreads();
  float m = red[r][0];
#pragma unroll
  for (int u = 1; u < 16; ++u) m = fmaxf(m, red[r][u]);
  __syncthreads();
  float ps = 0.f;
#pragma unroll
  for (int u = 0; u < 16; ++u) {
    const int j = jc + (u << 4);
    const float e = __expf(S[r][j] - m);
    S[r][j] = e;
    ps += e;
  }
  red[r][jc] = ps;
  __syncthreads();
  if (jc == 0) {
    float sum = 0.f;
#pragma unroll
    for (int u = 0; u < 16; ++u) sum += red[r][u];
    rowinv[r] = 1.0f / sum;
  }
  __syncthreads();
  for (int idx = tid; idx < 4096; idx += 256) {
    const int rr = idx >> 8, j = idx & 255;
    const float v = S[rr][j] * rowinv[rr];
    const unsigned short h = f2bf_(v);
    const size_t off = (size_t)bh * MM_STRIDE + (rg * 16 + rr) * 256 + j;
    x2hi[off] = (short)h;
    x2lo[off] = (short)f2bf_(v - bf2f_(h));
  }
}

// ---------------- global max of col/row abs-sums (hi/lo input) --------------
__global__ __launch_bounds__(256) void colrow_max(const short* __restrict__ x2hi,
                                                  const short* __restrict__ x2lo,
                                                  float* __restrict__ scal) {
  const int bh = blockIdx.x;
  const int tid = threadIdx.x;
  const size_t b0 = (size_t)bh * MM_STRIDE;
  float cs = 0.f, rs = 0.f;
  for (int j = 0; j < 256; ++j) {
    const size_t o = b0 + (size_t)tid * 256 + j;
    cs += fabsf(bf2f_((unsigned short)x2hi[o]) + bf2f_((unsigned short)x2lo[o]));
  }
  for (int i = 0; i < 256; ++i) {
    const size_t o = b0 + (size_t)i * 256 + tid;
    rs += fabsf(bf2f_((unsigned short)x2hi[o]) + bf2f_((unsigned short)x2lo[o]));
  }
  __shared__ float rc[256], rr[256];
  rc[tid] = cs; rr[tid] = rs;
  __syncthreads();
  for (int st = 128; st > 0; st >>= 1) {
    if (tid < st) {
      rc[tid] = fmaxf(rc[tid], rc[tid + st]);
      rr[tid] = fmaxf(rr[tid], rr[tid + st]);
    }
    __syncthreads();
  }
  if (tid == 0) {
    atomicMax((int*)&scal[0], __float_as_int(rc[0]));
    atomicMax((int*)&scal[1], __float_as_int(rr[0]));
  }
}

// --- z0 = x2^T/(cmax*rmax): A-form hi/lo + fp32, B-form (=x2/s) hi/lo -------
__global__ __launch_bounds__(256) void tscale2(const short* __restrict__ x2hi,
                                               const short* __restrict__ x2lo,
                                               const float* __restrict__ scal,
                                               short* __restrict__ zBhi,
                                               short* __restrict__ zBlo,
                                               short* __restrict__ zAhi,
                                               short* __restrict__ zAlo,
                                               float* __restrict__ zf) {
  const int g = blockIdx.x * 256 + threadIdx.x;
  const int j = g & 255, i = (g >> 8) & 255, bh = g >> 16;
  const float inv = 1.0f / (scal[0] * scal[1]);
  const float val = (bf2f_((unsigned short)x2hi[g]) +
                     bf2f_((unsigned short)x2lo[g])) * inv;
  const unsigned short h = f2bf_(val);
  const unsigned short lo = f2bf_(val - bf2f_(h));
  zBhi[g] = (short)h;
  zBlo[g] = (short)lo;
  const size_t tg = (size_t)bh * MM_STRIDE + (size_t)j * 256 + i;
  zAhi[tg] = (short)h;
  zAlo[tg] = (short)lo;
  zf[tg] = val;                     // fp32 A-form (exact E for step 4)
}

// --------- split-bf16 batched 256^3: C = alpha*Ef + beta*(A@B) --------------
// R4-verified structure (16x64 tiles, 512 blocks, staged gl16). prec=1: full
// split-bf16 (3 MFMA, stage hi+lo). prec=0: hi-only (1 MFMA, stage 2 bufs) --
// used for NS iterations 0-3 (self-correcting). E read fp32 (exact). All
// lo/fp32 outputs still written from exact fp32 vv regardless of prec.
__global__ __launch_bounds__(256) void pinv_mfma(const short* __restrict__ Ahi_g,
                                                 const short* __restrict__ Alo_g,
                                                 const short* __restrict__ Bhi_g,
                                                 const short* __restrict__ Blo_g,
                                                 const float* __restrict__ Ef,
                                                 float* __restrict__ Cf,
                                                 short* __restrict__ Chi,
                                                 short* __restrict__ Clo,
                                                 short* __restrict__ CThi,
                                                 short* __restrict__ CTlo,
                                                 float alpha, float beta,
                                                 int wantCf, int wantChl,
                                                 int wantT, int prec) {
  __shared__ short Ah[2048], Al[2048], Bh[2048], Bl[2048];
  __shared__ float Tbuf[64 * 68];
  const int tid = threadIdx.x;
  const int lane = tid & 63, w = tid >> 6;
  const int bid = blockIdx.x;
  const int xcd = bid & 7, y = bid >> 3;
  const int t16 = y & 15, bgrp = y >> 4;
  const int batch = bgrp * 8 + xcd;
  const int tm = t16 >> 2, tn = t16 & 3;
  const size_t bb = (size_t)batch * MM_STRIDE;
  const int ml = (tid >> 6) * 16 + (tid & 15), koff = ((tid >> 4) & 3) * 8;
  const short* sAh = Ahi_g + bb + (size_t)(tm * 64 + ml) * 256 + koff;
  const short* sAl = Alo_g + bb + (size_t)(tm * 64 + ml) * 256 + koff;
  const short* sBh = Bhi_g + bb + (size_t)(tn * 64 + ml) * 256 + koff;
  const short* sBl = Blo_g + bb + (size_t)(tn * 64 + ml) * 256 + koff;
  short* dAh = &Ah[w * 512];
  short* dAl = &Al[w * 512];
  short* dBh = &Bh[w * 512];
  short* dBl = &Bl[w * 512];
  f32x4 acc[4];
#pragma unroll
  for (int j = 0; j < 4; ++j) acc[j] = (f32x4){0.f, 0.f, 0.f, 0.f};
  for (int kt = 0; kt < 8; ++kt) {
    const int k0 = kt * 32;
    __syncthreads();
    gl16(sAh + k0, dAh);
    gl16(sBh + k0, dBh);
    if (prec) {
      gl16(sAl + k0, dAl);
      gl16(sBl + k0, dBl);
    }
    __syncthreads();
    bf8 ah = *(const bf8*)&Ah[(w * 64 + lane) * 8];
    if (prec) {
      bf8 al = *(const bf8*)&Al[(w * 64 + lane) * 8];
#pragma unroll
      for (int j = 0; j < 4; ++j) {
        bf8 bh = *(const bf8*)&Bh[(j * 64 + lane) * 8];
        bf8 bl = *(const bf8*)&Bl[(j * 64 + lane) * 8];
        acc[j] = __builtin_amdgcn_mfma_f32_16x16x32_bf16(ah, bh, acc[j], 0, 0, 0);
        acc[j] = __builtin_amdgcn_mfma_f32_16x16x32_bf16(ah, bl, acc[j], 0, 0, 0);
        acc[j] = __builtin_amdgcn_mfma_f32_16x16x32_bf16(al, bh, acc[j], 0, 0, 0);
      }
    } else {
#pragma unroll
      for (int j = 0; j < 4; ++j) {
        bf8 bh = *(const bf8*)&Bh[(j * 64 + lane) * 8];
        acc[j] = __builtin_amdgcn_mfma_f32_16x16x32_bf16(ah, bh, acc[j], 0, 0, 0);
      }
    }
  }
  const int qd = lane >> 4, c = lane & 15;
  float vals[4][4];
#pragma unroll
  for (int j = 0; j < 4; ++j) {
    const int col = tn * 64 + j * 16 + c;
#pragma unroll
    for (int r = 0; r < 4; ++r) {
      const int row = tm * 64 + w * 16 + qd * 4 + r;
      const size_t off = bb + (size_t)row * 256 + col;
      float e = 0.f;
      if (alpha != 0.0f) e = alpha * Ef[off];
      const float vv = e + beta * acc[j][r];
      vals[j][r] = vv;
      if (wantCf) Cf[off] = vv;
      if (wantChl) {
        const unsigned short h = f2bf_(vv);
        Chi[off] = (short)h;
        Clo[off] = (short)f2bf_(vv - bf2f_(h));
      }
    }
  }
  if (wantT) {
    __syncthreads();
#pragma unroll
    for (int j = 0; j < 4; ++j)
#pragma unroll
      for (int r = 0; r < 4; ++r)
        Tbuf[(j * 16 + c) * 68 + w * 16 + qd * 4 + r] = vals[j][r];
    __syncthreads();
    const int ctr = tid >> 2, seg = (tid & 3) * 16;
#pragma unroll
    for (int u = 0; u < 4; ++u) {
      float4 o = *(const float4*)&Tbuf[ctr * 68 + seg + u * 4];
      s4v hi, lo;
      unsigned short h;
      h = f2bf_(o.x); hi[0] = (short)h; lo[0] = (short)f2bf_(o.x - bf2f_(h));
      h = f2bf_(o.y); hi[1] = (short)h; lo[1] = (short)f2bf_(o.y - bf2f_(h));
      h = f2bf_(o.z); hi[2] = (short)h; lo[2] = (short)f2bf_(o.z - bf2f_(h));
      h = f2bf_(o.w); hi[3] = (short)h; lo[3] = (short)f2bf_(o.w - bf2f_(h));
      const size_t off = bb + (size_t)(tn * 64 + ctr) * 256 + tm * 64 + seg + u * 4;
      *(s4v*)&CThi[off] = hi;
      *(s4v*)&CTlo[off] = lo;
    }
  }
}

// ---- attn3 flash, per-wave (barrier-free): each wave owns 16 ql rows -------
__global__ __launch_bounds__(256) void attn3_flash(const float* __restrict__ ql,
                                                   const short* __restrict__ kb16,
                                                   const short* __restrict__ vT16,
                                                   float* __restrict__ opart,
                                                   float* __restrict__ mpart,
                                                   float* __restrict__ lpart) {
  const int kc = blockIdx.x;   // key chunk 0..3 (1024 keys each)
  const int rt = blockIdx.y;   // row tile 0..3 (64 rows each)
  const int bh = blockIdx.z;   // 0..31
  __shared__ short Pa[4][4096];  // per-wave 16 rows x 256 keys, A-frag order
  const int tid = threadIdx.x, lane = tid & 63, w = tid >> 6;
  const int qd = lane >> 4, c = lane & 15;
  const int rw = rt * 64 + w * 16;               // wave's first global row
  const float* qlp = ql + (size_t)bh * LM_STRIDE;
  const short* kp = kb16 + (size_t)bh * QKV_STRIDE;
  const short* vp = vT16 + (size_t)bh * QKV_STRIDE;
  short* Pw = &Pa[w][0];
  bf8 af[2];
#pragma unroll
  for (int st = 0; st < 2; ++st) {
    float4 x0 = *(const float4*)&qlp[(size_t)(rw + c) * 64 + st * 32 + qd * 8];
    float4 x1 = *(const float4*)&qlp[(size_t)(rw + c) * 64 + st * 32 + qd * 8 + 4];
    bf8 r;
    r[0] = (short)f2bf_(x0.x); r[1] = (short)f2bf_(x0.y);
    r[2] = (short)f2bf_(x0.z); r[3] = (short)f2bf_(x0.w);
    r[4] = (short)f2bf_(x1.x); r[5] = (short)f2bf_(x1.y);
    r[6] = (short)f2bf_(x1.z); r[7] = (short)f2bf_(x1.w);
    af[st] = r;
  }
  float m[4], l[4];
#pragma unroll
  for (int r = 0; r < 4; ++r) { m[r] = -3.0e38f; l[r] = 0.f; }
  f32x4 accO[4];
#pragma unroll
  for (int nb = 0; nb < 4; ++nb) accO[nb] = (f32x4){0.f, 0.f, 0.f, 0.f};
  for (int it = 0; it < 4; ++it) {
    const int kb0 = kc * 1024 + it * 256;
    f32x4 acc[16];
#pragma unroll
    for (int j = 0; j < 16; ++j) acc[j] = (f32x4){0.f, 0.f, 0.f, 0.f};
#pragma unroll
    for (int st = 0; st < 2; ++st)
#pragma unroll
      for (int j = 0; j < 16; ++j) {
        bf8 bfk = *(const bf8*)&kp[(size_t)(kb0 + j * 16 + c) * 64 + st * 32 + qd * 8];
        acc[j] = __builtin_amdgcn_mfma_f32_16x16x32_bf16(af[st], bfk, acc[j], 0, 0, 0);
      }
#pragma unroll
    for (int r = 0; r < 4; ++r) {
      float mx = acc[0][r];
#pragma unroll
      for (int j = 1; j < 16; ++j) mx = fmaxf(mx, acc[j][r]);
      mx = fmaxf(mx, __shfl_xor(mx, 1));
      mx = fmaxf(mx, __shfl_xor(mx, 2));
      mx = fmaxf(mx, __shfl_xor(mx, 4));
      mx = fmaxf(mx, __shfl_xor(mx, 8));
      const float mN = fmaxf(m[r], mx);
      const float a = __expf(m[r] - mN);
      m[r] = mN;
      l[r] *= a;
#pragma unroll
      for (int nb = 0; nb < 4; ++nb) accO[nb][r] *= a;
      float s = 0.f;
#pragma unroll
      for (int j = 0; j < 16; ++j) {
        const float e = __expf(acc[j][r] - mN);
        acc[j][r] = e;
        s += e;
      }
      s += __shfl_xor(s, 1);
      s += __shfl_xor(s, 2);
      s += __shfl_xor(s, 4);
      s += __shfl_xor(s, 8);
      l[r] += s;
    }
#pragma unroll
    for (int j = 0; j < 16; ++j) {
      const int kcol = j * 16 + c;
      const int kb8 = kcol >> 5;
      const int la_base = 16 * ((kcol >> 3) & 3);
      const int j8 = kcol & 7;
#pragma unroll
      for (int r = 0; r < 4; ++r) {
        const int rl = qd * 4 + r;
        Pw[(kb8 * 64 + la_base + rl) * 8 + j8] = (short)f2bf_(acc[j][r]);
      }
    }
#pragma unroll
    for (int kbk = 0; kbk < 8; ++kbk) {
      bf8 ap = *(const bf8*)&Pw[(kbk * 64 + lane) * 8];
#pragma unroll
      for (int nb = 0; nb < 4; ++nb) {
        bf8 bv = *(const bf8*)&vp[(size_t)(nb * 16 + c) * 4096 + kb0 + kbk * 32 + qd * 8];
        accO[nb] = __builtin_amdgcn_mfma_f32_16x16x32_bf16(ap, bv, accO[nb], 0, 0, 0);
      }
    }
  }
  const size_t ob = ((size_t)kc * 32 + bh) * 256 + rt * 64;
#pragma unroll
  for (int nb = 0; nb < 4; ++nb)
#pragma unroll
    for (int r = 0; r < 4; ++r)
      opart[(ob + w * 16 + qd * 4 + r) * 64 + nb * 16 + c] = accO[nb][r];
  if (c == 0) {
#pragma unroll
    for (int r = 0; r < 4; ++r) {
      mpart[ob + w * 16 + qd * 4 + r] = m[r];
      lpart[ob + w * 16 + qd * 4 + r] = l[r];
    }
  }
}

// ------- merge the 4 key-chunk partials -> avT hi/lo bf16 [bh][d][row] ------
__global__ __launch_bounds__(256) void attn3_merge(const float* __restrict__ opart,
                                                   const float* __restrict__ mpart,
                                                   const float* __restrict__ lpart,
                                                   short* __restrict__ avth,
                                                   short* __restrict__ avtl) {
  const int g = blockIdx.x * 256 + threadIdx.x;   // 524288 = 32*256*64
  const int d = g & 63;
  const int idx = g >> 6;                          // bh*256+row
  const int bh = idx >> 8, row = idx & 255;
  const float m0 = mpart[idx], m1 = mpart[8192 + idx],
              m2 = mpart[16384 + idx], m3 = mpart[24576 + idx];
  const float mx = fmaxf(fmaxf(m0, m1), fmaxf(m2, m3));
  const float w0 = __expf(m0 - mx), w1 = __expf(m1 - mx),
              w2 = __expf(m2 - mx), w3 = __expf(m3 - mx);
  const float l = lpart[idx] * w0 + lpart[8192 + idx] * w1 +
                  lpart[16384 + idx] * w2 + lpart[24576 + idx] * w3;
  const float o = opart[(size_t)idx * 64 + d] * w0 +
                  opart[524288 + (size_t)idx * 64 + d] * w1 +
                  opart[1048576 + (size_t)idx * 64 + d] * w2 +
                  opart[1572864 + (size_t)idx * 64 + d] * w3;
  const float val = o / l;
  const unsigned short h = f2bf_(val);
  const size_t o2 = ((size_t)bh * 64 + d) * 256 + row;
  avth[o2] = (short)h;
  avtl[o2] = (short)f2bf_(val - bf2f_(h));
}

// ------- w2^T = (z_final @ av)^T via split-bf16 MFMA ------------------------
__global__ __launch_bounds__(256) void zav_mfma(const short* __restrict__ zAhi,
                                                const short* __restrict__ zAlo,
                                                const short* __restrict__ avth,
                                                const short* __restrict__ avtl,
                                                short* __restrict__ w2tb16) {
  __shared__ short Tb[64 * 68];
  const int rt = blockIdx.x;      // 0..3
  const int bh = blockIdx.y;      // 0..31
  const int tid = threadIdx.x, lane = tid & 63, w = tid >> 6;
  const int qd = lane >> 4, c = lane & 15;
  const size_t zoff = (size_t)bh * MM_STRIDE + (size_t)(rt * 64 + w * 16 + c) * 256;
  const short* zh = zAhi + zoff;
  const short* zl = zAlo + zoff;
  const short* ahp = avth + (size_t)bh * LM_STRIDE;
  const short* alp = avtl + (size_t)bh * LM_STRIDE;
  f32x4 acc[4];
#pragma unroll
  for (int j = 0; j < 4; ++j) acc[j] = (f32x4){0.f, 0.f, 0.f, 0.f};
  for (int kt = 0; kt < 8; ++kt) {
    const int k0 = kt * 32 + qd * 8;
    bf8 ah = *(const bf8*)&zh[k0];
    bf8 al = *(const bf8*)&zl[k0];
#pragma unroll
    for (int j = 0; j < 4; ++j) {
      bf8 bhj = *(const bf8*)&ahp[(size_t)(j * 16 + c) * 256 + k0];
      bf8 blj = *(const bf8*)&alp[(size_t)(j * 16 + c) * 256 + k0];
      acc[j] = __builtin_amdgcn_mfma_f32_16x16x32_bf16(ah, bhj, acc[j], 0, 0, 0);
      acc[j] = __builtin_amdgcn_mfma_f32_16x16x32_bf16(ah, blj, acc[j], 0, 0, 0);
      acc[j] = __builtin_amdgcn_mfma_f32_16x16x32_bf16(al, bhj, acc[j], 0, 0, 0);
    }
  }
#pragma unroll
  for (int j = 0; j < 4; ++j)
#pragma unroll
    for (int r = 0; r < 4; ++r)
      Tb[(j * 16 + c) * 68 + w * 16 + qd * 4 + r] = (short)f2bf_(acc[j][r]);
  __syncthreads();
  const int col = tid >> 2, rs = (tid & 3) * 16;
  short* dst = &w2tb16[(size_t)bh * LM_STRIDE + (size_t)col * 256 + rt * 64 + rs];
  const short* srcp = &Tb[col * 68 + rs];
#pragma unroll
  for (int u = 0; u < 4; ++u) *(s4v*)&dst[u * 4] = *(const s4v*)&srcp[u * 4];
}

// -- attn1+conv: oh = softmax(q@kl^T)@w2 + conv(v) [conv via banded MFMA] ----
// 32-row blocks (R8-verified best: grid 4096, Pa 16KB -> ~8 blocks/CU).
// Wave w: QK cols w*64..+63; PV/conv rows (w&1)*16, cols (w>>1)*32. XCD remap.
__global__ __launch_bounds__(256) void attn1_conv_mfma(const short* __restrict__ qb16,
                                                       const short* __restrict__ klb16,
                                                       const short* __restrict__ w2tb16,
                                                       const short* __restrict__ vT16,
                                                       const float* __restrict__ cw,
                                                       short* __restrict__ ohb16) {
  __shared__ short Pa[8192];                // 32x256 bf16 in A-frag order (16KB)
  __shared__ float redM[4][32], redS[4][32];
  __shared__ float rowM[32], rowI[32];
  __shared__ float cwS[33];
  const int tid = threadIdx.x;
  const int lane = tid & 63, w = tid >> 6;
  const int qd = lane >> 4, c = lane & 15;
  const int lin = blockIdx.y * 128 + blockIdx.x;   // grid (128,32) -> 0..4095
  const int xcd = lin & 7;
  const int idx = lin >> 3;                        // 0..511
  const int bh = xcd * 4 + (idx >> 7);             // 4 bh per XCD
  const int r0 = (idx & 127) * 32;                 // 32-row tile
  const short* qp = qb16 + (size_t)bh * QKV_STRIDE;
  const short* klp = klb16 + (size_t)bh * LM_STRIDE;
  const short* w2p = w2tb16 + (size_t)bh * LM_STRIDE;
  const short* vp = vT16 + (size_t)bh * QKV_STRIDE;

  if (tid < 33) cwS[tid] = cw[(bh & 7) * 33 + tid];

  // ---- QK^T: S[32][256], wave w owns cols w*64..+63 ----
  f32x4 acc[2][4];
#pragma unroll
  for (int i = 0; i < 2; ++i)
#pragma unroll
    for (int j = 0; j < 4; ++j) acc[i][j] = (f32x4){0.f, 0.f, 0.f, 0.f};
#pragma unroll
  for (int st = 0; st < 2; ++st) {
    const int k0 = st * 32 + qd * 8;
    bf8 af[2], bf[4];
#pragma unroll
    for (int i = 0; i < 2; ++i)
      af[i] = *(const bf8*)&qp[(size_t)(r0 + i * 16 + c) * 64 + k0];
#pragma unroll
    for (int j = 0; j < 4; ++j)
      bf[j] = *(const bf8*)&klp[(size_t)(w * 64 + j * 16 + c) * 64 + k0];
#pragma unroll
    for (int i = 0; i < 2; ++i)
#pragma unroll
      for (int j = 0; j < 4; ++j)
        acc[i][j] = __builtin_amdgcn_mfma_f32_16x16x32_bf16(af[i], bf[j], acc[i][j], 0, 0, 0);
  }
  // ---- row max (over 4 waves x 64 cols each) ----
#pragma unroll
  for (int i = 0; i < 2; ++i)
#pragma unroll
    for (int r = 0; r < 4; ++r) {
      float m0 = fmaxf(fmaxf(acc[i][0][r], acc[i][1][r]),
                       fmaxf(acc[i][2][r], acc[i][3][r]));
      m0 = fmaxf(m0, __shfl_xor(m0, 1));
      m0 = fmaxf(m0, __shfl_xor(m0, 2));
      m0 = fmaxf(m0, __shfl_xor(m0, 4));
      m0 = fmaxf(m0, __shfl_xor(m0, 8));
      if (c == 0) redM[w][i * 16 + qd * 4 + r] = m0;
    }
  __syncthreads();
  if (tid < 32)
    rowM[tid] = fmaxf(fmaxf(redM[0][tid], redM[1][tid]),
                      fmaxf(redM[2][tid], redM[3][tid]));
  __syncthreads();
  // ---- exp + row sum ----
#pragma unroll
  for (int i = 0; i < 2; ++i)
#pragma unroll
    for (int r = 0; r < 4; ++r) {
      const float mrow = rowM[i * 16 + qd * 4 + r];
      float s = 0.f;
#pragma unroll
      for (int j = 0; j < 4; ++j) {
        const float e = __expf(acc[i][j][r] - mrow);
        acc[i][j][r] = e;
        s += e;
      }
      s += __shfl_xor(s, 1);
      s += __shfl_xor(s, 2);
      s += __shfl_xor(s, 4);
      s += __shfl_xor(s, 8);
      if (c == 0) redS[w][i * 16 + qd * 4 + r] = s;
    }
  __syncthreads();
  if (tid < 32)
    rowI[tid] = 1.0f / (redS[0][tid] + redS[1][tid] + redS[2][tid] + redS[3][tid]);
  __syncthreads();
  // ---- P -> Pa (A-frag order: tile (kb,i), lane2, elem) ----
#pragma unroll
  for (int i = 0; i < 2; ++i)
#pragma unroll
    for (int r = 0; r < 4; ++r) {
      const int row = i * 16 + qd * 4 + r;
      const float inv = rowI[row];
#pragma unroll
      for (int j = 0; j < 4; ++j) {
        const int col = w * 64 + j * 16 + c;
        const short val = (short)f2bf_(acc[i][j][r] * inv);
        const int kb = col >> 5;
        const int lane2 = (row & 15) + 16 * ((col >> 3) & 3);
        Pa[((kb * 2 + i) * 64 + lane2) * 8 + (col & 7)] = val;
      }
    }
  __syncthreads();
  // ---- PV: wave w -> rows (w&1)*16, cols (w>>1)*32 ----
  const int iw = w & 1, ch = w >> 1;
  f32x4 accO[2];
#pragma unroll
  for (int nb = 0; nb < 2; ++nb) accO[nb] = (f32x4){0.f, 0.f, 0.f, 0.f};
  for (int kb = 0; kb < 8; ++kb) {
    bf8 ap = *(const bf8*)&Pa[((kb * 2 + iw) * 64 + lane) * 8];
#pragma unroll
    for (int nb = 0; nb < 2; ++nb) {
      bf8 bfr = *(const bf8*)&w2p[(size_t)(ch * 32 + nb * 16 + c) * 256 + kb * 32 + qd * 8];
      accO[nb] = __builtin_amdgcn_mfma_f32_16x16x32_bf16(ap, bfr, accO[nb], 0, 0, 0);
    }
  }
  // ---- conv residual: Band[16x64] @ Vwin[64x32] per wave ----
  {
    bf8 ba[2];
    const int rl = iw * 16 + (lane & 15);   // row within 32-row block
#pragma unroll
    for (int kb = 0; kb < 2; ++kb) {
#pragma unroll
      for (int e = 0; e < 8; ++e) {
        const int kk = kb * 32 + qd * 8 + e;
        const int t = kk - rl;
        const int s = r0 - 16 + kk;
        const float bv = (t >= 0 && t < 33 && s >= 0 && s < 4096) ? cwS[t] : 0.f;
        ba[kb][e] = (short)f2bf_(bv);
      }
    }
#pragma unroll
    for (int kb = 0; kb < 2; ++kb) {
      int s0 = r0 - 16 + kb * 32 + qd * 8;
      s0 = s0 < 0 ? 0 : (s0 > 4088 ? 4088 : s0);
#pragma unroll
      for (int nb = 0; nb < 2; ++nb) {
        bf8 bv = *(const bf8*)&vp[(size_t)(ch * 32 + nb * 16 + c) * 4096 + s0];
        accO[nb] = __builtin_amdgcn_mfma_f32_16x16x32_bf16(ba[kb], bv, accO[nb], 0, 0, 0);
      }
    }
  }
  short* ohp = (short*)ohb16 + (size_t)bh * QKV_STRIDE;
#pragma unroll
  for (int nb = 0; nb < 2; ++nb)
#pragma unroll
    for (int r = 0; r < 4; ++r) {
      const int row = r0 + iw * 16 + qd * 4 + r;
      ohp[(size_t)row * 64 + ch * 32 + nb * 16 + c] = (short)f2bf_(accO[nb][r]);
    }
}

// ------- out = concat_heads(oh_bf16) @ w_out + b_out (MFMA) -----------------
// global_load_lds staging; XCD-swizzled 1-D grid (512 = 8*64).
__global__ __launch_bounds__(256) void gemm_out_mfma(const short* __restrict__ ohb16,
                                                     const short* __restrict__ wT,
                                                     const float* __restrict__ bias,
                                                     float* __restrict__ out) {
  __shared__ short As[4096];
  __shared__ short Bs[4096];
  const int tid = threadIdx.x;
  const int lane = tid & 63, w = tid >> 6;
  const int wr = w >> 1, wc = w & 1;
  const int bid = (blockIdx.x & 7) * 64 + (blockIdx.x >> 3);   // 512 = 8*64
  const int bn = bid & 3, bm = bid >> 2;
  const int gm0 = bm * 128, gn0 = bn * 128;
  const int mA0 = (tid >> 6) * 16 + (tid & 15), kA0 = ((tid >> 4) & 3) * 8;
  const int s1 = tid + 256;
  const int mA1 = (s1 >> 6) * 16 + (s1 & 15), kA1 = ((s1 >> 4) & 3) * 8;
  const int b0r = (gm0 + mA0) >> 12, seq0 = (gm0 + mA0) & 4095;
  const int b1r = (gm0 + mA1) >> 12, seq1 = (gm0 + mA1) & 4095;
  short* dA0 = &As[w * 512];
  short* dA1 = &As[2048 + w * 512];
  short* dB0 = &Bs[w * 512];
  short* dB1 = &Bs[2048 + w * 512];
  f32x4 acc[4][4];
#pragma unroll
  for (int i = 0; i < 4; ++i)
#pragma unroll
    for (int j = 0; j < 4; ++j) acc[i][j] = (f32x4){0.f, 0.f, 0.f, 0.f};
  for (int kt = 0; kt < 16; ++kt) {
    const int ka = kt * 32 + kA0, kb = kt * 32 + kA1;
    __syncthreads();
    gl16(&ohb16[(size_t)(b0r * 8 + (ka >> 6)) * QKV_STRIDE + (size_t)seq0 * 64 + (ka & 63)], dA0);
    gl16(&ohb16[(size_t)(b1r * 8 + (kb >> 6)) * QKV_STRIDE + (size_t)seq1 * 64 + (kb & 63)], dA1);
    gl16(&wT[(size_t)(gn0 + mA0) * 512 + ka], dB0);
    gl16(&wT[(size_t)(gn0 + mA1) * 512 + kb], dB1);
    __syncthreads();
    bf8 af[4], bfr[4];
#pragma unroll
    for (int i = 0; i < 4; ++i) {
      af[i] = *(const bf8*)&As[((wr * 4 + i) * 64 + lane) * 8];
      bfr[i] = *(const bf8*)&Bs[((wc * 4 + i) * 64 + lane) * 8];
    }
#pragma unroll
    for (int i = 0; i < 4; ++i)
#pragma unroll
      for (int j = 0; j < 4; ++j)
        acc[i][j] = __builtin_amdgcn_mfma_f32_16x16x32_bf16(af[i], bfr[j], acc[i][j], 0, 0, 0);
  }
  const int qd = lane >> 4, c = lane & 15;
#pragma unroll
  for (int i = 0; i < 4; ++i)
#pragma unroll
    for (int j = 0; j < 4; ++j) {
      const int col = gn0 + wc * 64 + j * 16 + c;
      const float bval = bias[col];
#pragma unroll
      for (int r = 0; r < 4; ++r) {
        const int row = gm0 + wr * 64 + i * 16 + qd * 4 + r;
        out[(size_t)row * 512 + col] = acc[i][j][r] + bval;
      }
    }
}

// ---------------------------------------------------------------------------
extern "C" void kernel_launch(void* const* d_in, const int* in_sizes, int n_in,
                              void* d_out, int out_size, void* d_ws, size_t ws_size,
                              hipStream_t stream) {
  const float* x    = (const float*)d_in[0];
  const float* wqkv = (const float*)d_in[1];
  const float* wout = (const float*)d_in[2];
  const float* bout = (const float*)d_in[3];
  const float* cw   = (const float*)d_in[4];
  float* out = (float*)d_out;

  float* w = (float*)d_ws;
  // ---- compact layout: 37,486,656 floats total (~150 MB) ----
  short* qb16   = (short*)(w);              // [32,4096,64] bf16   (4194304 fl)
  short* kb16   = (short*)(w + 4194304);
  short* vT16   = (short*)(w + 8388608);    // [32,64,4096] bf16
  // region 12582912..16777216 (4194304 fl), time-multiplexed:
  short* xb16   = (short*)(w + 12582912);   // phase 1: x bf16 (dead after qkv)
  float* z0f    = w + 12582912;             // phase 2: fp32 z ping (2097152)
  float* z1f    = w + 14680064;             // phase 2: fp32 z pong (2097152)
  float* opart  = w + 12582912;             // phase 3: [4,32,256,64] (2097152)
  short* ohb16  = (short*)(w + 12582912);   // phase 4: oh bf16 (4194304 fl)
  float* ql     = w + 16777216;             // [32,256,64] fp32 (524288)
  float* kl     = w + 17301504;
  short* klb16  = (short*)(w + 17825792);   // (262144 fl)
  short* x2hi   = (short*)(w + 18087936);   // hi/lo pairs: 1048576 fl each
  short* x2lo   = (short*)(w + 19136512);
  float* xzf    = w + 20185088;             // fp32 xz (E steps 2,3) (2097152)
  short* xzAhi  = (short*)(w + 22282240);
  short* xzAlo  = (short*)(w + 23330816);
  short* xzBhi  = (short*)(w + 24379392);   // also u2B (xzB dead after step 2)
  short* xzBlo  = (short*)(w + 25427968);
  short* u1Bhi  = (short*)(w + 26476544);
  short* u1Blo  = (short*)(w + 27525120);
  short* z0Ahi  = (short*)(w + 28573696);
  short* z0Alo  = (short*)(w + 29622272);
  short* z0Bhi  = (short*)(w + 30670848);
  short* z0Blo  = (short*)(w + 31719424);
  short* z1Ahi  = (short*)(w + 32768000);
  short* z1Alo  = (short*)(w + 33816576);
  short* z1Bhi  = (short*)(w + 34865152);
  short* z1Blo  = (short*)(w + 35913728);
  float* scal   = w + 36962304;             // [2]
  short* wqkvT  = (short*)(w + 36962368);   // [1536,512] bf16 (393216 fl)
  short* woutT  = (short*)(w + 37355584);   // [512,512] bf16 (131072 fl)
  // end: 37486656 floats (~150 MB)
  // post-pinv aliases (xzf/xzA/u1B dead after the loop):
  short* avth   = (short*)(w + 20185088);   // [32,64,256] bf16 (262144 fl)
  short* avtl   = (short*)(w + 20447232);
  short* w2tb16 = (short*)(w + 20709376);   // [32,256,64] bf16 (262144 fl)
  float* mpart  = w + 26476544;             // [4,32,256] (32768 fl, in u1Bhi)
  float* lpart  = w + 26509312;

  zero_scal<<<1, 64, 0, stream>>>(scal);
  transpose_bf16<<<dim3(48, 16), 256, 0, stream>>>(wqkv, wqkvT, 512, 1536);
  transpose_bf16<<<dim3(16, 16), 256, 0, stream>>>(wout, woutT, 512, 512);
  x_to_bf16<<<2048, 256, 0, stream>>>(x, xb16);
  gemm_qkv_mfma<<<1536, 256, 0, stream>>>(xb16, wqkvT, qb16, kb16, vT16);
  lmk_mean<<<2048, 256, 0, stream>>>(qb16, kb16, ql, kl, klb16);
  sim2_softmax<<<512, 256, 0, stream>>>(ql, kl, x2hi, x2lo);
  colrow_max<<<32, 256, 0, stream>>>(x2hi, x2lo, scal);
  // overwrites xb16 region with z0f -- xb16 dead after gemm_qkv.
  tscale2<<<8192, 256, 0, stream>>>(x2hi, x2lo, scal, z0Bhi, z0Blo, z0Ahi, z0Alo, z0f);

  float *zcf = z0f, *znf = z1f;
  short *zAh = z0Ahi, *zAl = z0Alo, *zBh = z0Bhi, *zBl = z0Blo;
  short *nAh = z1Ahi, *nAl = z1Alo, *nBh = z1Bhi, *nBl = z1Blo;
  for (int it = 0; it < 6; ++it) {
    const int pr = (it >= 4) ? 1 : 0;  // iters 0-3 hi-only (NS self-corrects)
    const int nl = (it < 5) ? 1 : 0;   // final iter: fp32 zn + B-form unused
    // xz = x2 @ z         (need xz fp32 + A-form hi/lo + B-form hi/lo)
    pinv_mfma<<<512, 256, 0, stream>>>(x2hi, x2lo, zBh, zBl, xzf,
                                       xzf, xzAhi, xzAlo, xzBhi, xzBlo,
                                       0.f, 1.f, 1, 1, 1, pr);
    // u1 = 7*xz - xz@xz   (only u1^T hi/lo needed)
    pinv_mfma<<<512, 256, 0, stream>>>(xzAhi, xzAlo, xzBhi, xzBlo, xzf,
                                       znf, u1Bhi, u1Blo, u1Bhi, u1Blo,
                                       7.f, -1.f, 0, 0, 1, pr);
    // u2 = 15*xz - xz@u1  (only u2^T hi/lo needed; overwrites xzB slots)
    pinv_mfma<<<512, 256, 0, stream>>>(xzAhi, xzAlo, u1Bhi, u1Blo, xzf,
                                       znf, xzBhi, xzBlo, xzBhi, xzBlo,
                                       15.f, -1.f, 0, 0, 1, pr);
    // zn = 3.25*z - 0.25*z@u2  (fp32 + A hi/lo + B hi/lo; trimmed on it=5)
    pinv_mfma<<<512, 256, 0, stream>>>(zAh, zAl, xzBhi, xzBlo, zcf,
                                       znf, nAh, nAl, nBh, nBl,
                                       3.25f, -0.25f, nl, 1, nl, pr);
    float* tf = zcf; zcf = znf; znf = tf;
    short* t;
    t = zAh; zAh = nAh; nAh = t;  t = zAl; zAl = nAl; nAl = t;
    t = zBh; zBh = nBh; nBh = t;  t = zBl; zBl = nBl; nBl = t;
  }
  // zAh/zAl == z0A here (6 swaps). z0f/z1f/xzf/xzA/u1B dead -> aliases live.
  // opart overwrites z0f region (dead); read by merge before ohb16 is written.

  attn3_flash<<<dim3(4, 4, 32), 256, 0, stream>>>(ql, kb16, vT16, opart, mpart, lpart);
  attn3_merge<<<2048, 256, 0, stream>>>(opart, mpart, lpart, avth, avtl);
  zav_mfma<<<dim3(4, 32), 256, 0, stream>>>(zAh, zAl, avth, avtl, w2tb16);
  // attn1_conv writes ohb16 over the opart/z0f/z1f region (all dead now).
  attn1_conv_mfma<<<dim3(128, 32), 256, 0, stream>>>(qb16, klb16, w2tb16, vT16, cw, ohb16);
  gemm_out_mfma<<<512, 256, 0, stream>>>(ohb16, woutT, bout, out);
}

// Round 11
// 713.452 us; speedup vs baseline: 1.1048x; 1.0105x over previous
//
#include <hip/hip_runtime.h>
#include <math.h>

// ---------------------------------------------------------------------------
// NystromAttention round 18: R10 (721us) + (a) BK=64 K-loops in pinv/qkv/out
// (halves barrier-drain count; bytes, coalescing and MFMA k-order BIT-
// IDENTICAL - only step width changes); (b) dead lo-write elimination: with
// precision-staged NS, lo outputs of sloppy steps are provably dead (steps
// 1-3 lo needed iff same iter precise; step-4 lo iff next consumer precise).
// b=4 n=4096 dim=512 h=8 d=64 m=256, l=16, iters=6, conv k=33.
// MFMA 16x16x32_bf16 layouts (HW-verified per guide):
//   A: m=lane&15, k=(lane>>4)*8+j    B: n=lane&15, k=(lane>>4)*8+j
//   C/D: col=lane&15, row=(lane>>4)*4+reg
// ---------------------------------------------------------------------------

#define QKV_STRIDE 262144   // 4096*64 per (b,h)
#define LM_STRIDE 16384     // 256*64
#define MM_STRIDE 65536     // 256*256

typedef float f32x4 __attribute__((ext_vector_type(4)));
typedef short bf8 __attribute__((ext_vector_type(8)));   // 8 bf16 in 4 VGPRs
typedef short s4v __attribute__((ext_vector_type(4)));

__device__ __forceinline__ unsigned short f2bf_(float f) {
  unsigned u = __float_as_uint(f);
  u += 0x7FFFu + ((u >> 16) & 1u);   // RNE
  return (unsigned short)(u >> 16);
}
__device__ __forceinline__ float bf2f_(unsigned short h) {
  return __uint_as_float(((unsigned)h) << 16);
}

// async global->LDS, 16B per lane; LDS dest must be wave-uniform base.
__device__ __forceinline__ void gl16(const short* g, short* l) {
  __builtin_amdgcn_global_load_lds(
      (const __attribute__((address_space(1))) unsigned int*)g,
      (__attribute__((address_space(3))) unsigned int*)l, 16, 0, 0);
}

__global__ __launch_bounds__(256) void zero_scal(float* scal) {
  if (threadIdx.x < 2) scal[threadIdx.x] = 0.0f;
}

// ---------------- x (fp32) -> xb16 (bf16 row-major) -------------------------
__global__ __launch_bounds__(256) void x_to_bf16(const float* __restrict__ x,
                                                 short* __restrict__ xb) {
  const int g = blockIdx.x * 256 + threadIdx.x;   // 524288 threads
  const float4* xp = (const float4*)x;
#pragma unroll
  for (int u = 0; u < 4; ++u) {
    const size_t i4 = (size_t)u * 524288 + g;
    float4 v = xp[i4];
    s4v o;
    o[0] = (short)f2bf_(v.x); o[1] = (short)f2bf_(v.y);
    o[2] = (short)f2bf_(v.z); o[3] = (short)f2bf_(v.w);
    *(s4v*)&xb[i4 * 4] = o;
  }
}

// ------------- transpose + fp32->bf16: dst[C][R] = bf16(src[R][C]) ----------
__global__ __launch_bounds__(256) void transpose_bf16(const float* __restrict__ src,
                                                      short* __restrict__ dst,
                                                      int R, int C) {
  __shared__ float T[32][33];
  const int t = threadIdx.x;
  const int c0 = blockIdx.x * 32, r0 = blockIdx.y * 32;
  const int tr = t >> 3, tc = (t & 7) << 2;
  float4 vsrc = *(const float4*)&src[(size_t)(r0 + tr) * C + c0 + tc];
  T[tr][tc + 0] = vsrc.x; T[tr][tc + 1] = vsrc.y;
  T[tr][tc + 2] = vsrc.z; T[tr][tc + 3] = vsrc.w;
  __syncthreads();
  s4v o;
  o[0] = (short)f2bf_(T[tc + 0][tr]);
  o[1] = (short)f2bf_(T[tc + 1][tr]);
  o[2] = (short)f2bf_(T[tc + 2][tr]);
  o[3] = (short)f2bf_(T[tc + 3][tr]);
  *(s4v*)&dst[(size_t)(c0 + tr) * R + r0 + tc] = o;
}

// ---- qkv = xb16 @ w_qkv via MFMA -> qb16/kb16 row-major, vT16 transposed ---
// BK=64 staged global_load_lds (8 K-steps, 2 barriers each);
// XCD-swizzled 1-D grid (bijective, 1536 = 8*192).
__global__ __launch_bounds__(256) void gemm_qkv_mfma(const short* __restrict__ xb,
                                                     const short* __restrict__ wT,
                                                     short* __restrict__ qb16,
                                                     short* __restrict__ kb16,
                                                     short* __restrict__ vT16) {
  __shared__ short SMEM[17408];   // staging: As[2][4096] Bs[2][4096]; V: 128x136
  short* As = SMEM;               // halves at 0 / 4096
  short* Bs = SMEM + 8192;        // halves at 0 / 4096
  const int tid = threadIdx.x;
  const int lane = tid & 63, w = tid >> 6;
  const int wr = w >> 1, wc = w & 1;
  const int bid = (blockIdx.x & 7) * 192 + (blockIdx.x >> 3);  // 1536 = 8*192
  const int bn = bid % 12, bm = bid / 12;
  const int gm0 = bm * 128, gn0 = bn * 128;
  const int mA0 = (tid >> 6) * 16 + (tid & 15), kA0 = ((tid >> 4) & 3) * 8;
  const int s1 = tid + 256;
  const int mA1 = (s1 >> 6) * 16 + (s1 & 15), kA1 = ((s1 >> 4) & 3) * 8;
  const short* srcA0 = &xb[(size_t)(gm0 + mA0) * 512 + kA0];
  const short* srcA1 = &xb[(size_t)(gm0 + mA1) * 512 + kA1];
  const short* srcB0 = &wT[(size_t)(gn0 + mA0) * 512 + kA0];
  const short* srcB1 = &wT[(size_t)(gn0 + mA1) * 512 + kA1];
  f32x4 acc[4][4];
#pragma unroll
  for (int i = 0; i < 4; ++i)
#pragma unroll
    for (int j = 0; j < 4; ++j) acc[i][j] = (f32x4){0.f, 0.f, 0.f, 0.f};
  for (int kt = 0; kt < 8; ++kt) {
    const int k0 = kt * 64;
    __syncthreads();                 // prev-step LDS reads done before overwrite
    gl16(srcA0 + k0, &As[w * 512]);
    gl16(srcA1 + k0, &As[2048 + w * 512]);
    gl16(srcA0 + k0 + 32, &As[4096 + w * 512]);
    gl16(srcA1 + k0 + 32, &As[4096 + 2048 + w * 512]);
    gl16(srcB0 + k0, &Bs[w * 512]);
    gl16(srcB1 + k0, &Bs[2048 + w * 512]);
    gl16(srcB0 + k0 + 32, &Bs[4096 + w * 512]);
    gl16(srcB1 + k0 + 32, &Bs[4096 + 2048 + w * 512]);
    __syncthreads();                 // drains vmcnt -> tile resident
#pragma unroll
    for (int st = 0; st < 2; ++st) {
      bf8 af[4], bf[4];
#pragma unroll
      for (int i = 0; i < 4; ++i) {
        af[i] = *(const bf8*)&As[st * 4096 + ((wr * 4 + i) * 64 + lane) * 8];
        bf[i] = *(const bf8*)&Bs[st * 4096 + ((wc * 4 + i) * 64 + lane) * 8];
      }
#pragma unroll
      for (int i = 0; i < 4; ++i)
#pragma unroll
        for (int j = 0; j < 4; ++j)
          acc[i][j] = __builtin_amdgcn_mfma_f32_16x16x32_bf16(af[i], bf[j], acc[i][j], 0, 0, 0);
    }
  }
  const int which = bn >> 2;  // 0:q 1:k 2:v
  const int qd = lane >> 4, c = lane & 15;
  if (which < 2) {
    short* dst = which == 0 ? qb16 : kb16;
    const float scale = which == 0 ? 0.125f : 1.0f;
#pragma unroll
    for (int i = 0; i < 4; ++i)
#pragma unroll
      for (int j = 0; j < 4; ++j) {
        const int col = gn0 + wc * 64 + j * 16 + c;
        const int head = (col >> 6) & 7, dd = col & 63;
#pragma unroll
        for (int r = 0; r < 4; ++r) {
          const int row = gm0 + wr * 64 + i * 16 + qd * 4 + r;
          const int b = row >> 12, seq = row & 4095;
          dst[(size_t)(b * 8 + head) * QKV_STRIDE + seq * 64 + dd] =
              (short)f2bf_(acc[i][j][r] * scale);
        }
      }
  } else {
    __syncthreads();
#pragma unroll
    for (int i = 0; i < 4; ++i)
#pragma unroll
      for (int j = 0; j < 4; ++j) {
        const int colL = wc * 64 + j * 16 + c;
#pragma unroll
        for (int r = 0; r < 4; ++r) {
          const int rowL = wr * 64 + i * 16 + qd * 4 + r;
          SMEM[colL * 136 + rowL] = (short)f2bf_(acc[i][j][r]);
        }
      }
    __syncthreads();
    const int b = gm0 >> 12, seq0 = gm0 & 4095;
    const int dcol = tid >> 1, half = tid & 1;
    const int col = gn0 + dcol;
    const int head = (col >> 6) & 7, d = col & 63;
    const short* src = &SMEM[dcol * 136 + half * 64];
    short* dstp = &vT16[(size_t)(b * 8 + head) * QKV_STRIDE + (size_t)d * 4096 +
                        seq0 + half * 64];
#pragma unroll
    for (int u = 0; u < 16; ++u) *(s4v*)&dstp[u * 4] = *(const s4v*)&src[u * 4];
  }
}

// ---------------- landmark means (bf16 in, fp32 + bf16-kl out) --------------
__global__ __launch_bounds__(256) void lmk_mean(const short* __restrict__ qb16,
                                                const short* __restrict__ kb16,
                                                float* __restrict__ ql,
                                                float* __restrict__ kl,
                                                short* __restrict__ klb16) {
  const int g = blockIdx.x * 256 + threadIdx.x;
  const int dd = g & 63, mi = (g >> 6) & 255, bh = g >> 14;
  const size_t base = (size_t)bh * QKV_STRIDE + mi * 1024 + dd;
  float sq = 0.f, sk = 0.f;
#pragma unroll
  for (int jj = 0; jj < 16; ++jj) {
    sq += bf2f_((unsigned short)qb16[base + jj * 64]);
    sk += bf2f_((unsigned short)kb16[base + jj * 64]);
  }
  const float qv = sq * 0.0625f, kv = sk * 0.0625f;
  ql[g] = qv;
  kl[g] = kv;
  klb16[g] = (short)f2bf_(kv);
}

// ---------------- sim2 = ql @ kl^T, softmax -> x2 hi/lo ---------------------
__global__ __launch_bounds__(256) void sim2_softmax(const float* __restrict__ ql,
                                                    const float* __restrict__ kl,
                                                    short* __restrict__ x2hi,
                                                    short* __restrict__ x2lo) {
  const int blk = blockIdx.x;
  const int bh = blk >> 4, rg = blk & 15;
  __shared__ float Qs[16][64];
  __shared__ float Ks[64][68];
  __shared__ float S[16][257];
  __shared__ float red[16][17];
  __shared__ float rowinv[16];
  const int tid = threadIdx.x;
  const int r = tid >> 4, jc = tid & 15;
#pragma unroll
  for (int u = 0; u < 4; ++u) {
    int t2 = tid + u * 256;
    Qs[t2 >> 6][t2 & 63] =
        ql[(size_t)bh * LM_STRIDE + (rg * 16 + (t2 >> 6)) * 64 + (t2 & 63)];
  }
  for (int c = 0; c < 4; ++c) {
    __syncthreads();
#pragma unroll
    for (int u = 0; u < 4; ++u) {
      int t4 = tid + u * 256;
      int row = t4 >> 4, c4 = (t4 & 15) << 2;
      *(float4*)&Ks[row][c4] =
          *(const float4*)&kl[(size_t)bh * LM_STRIDE + (c * 64 + row) * 64 + c4];
    }
    __syncthreads();
#pragma unroll
    for (int s = 0; s < 4; ++s) {
      const int jj = jc + (s << 4);
      float acc = 0.f;
#pragma unroll
      for (int k4 = 0; k4 < 16; ++k4) {
        const float4 a = *(const float4*)&Qs[r][k4 << 2];
        const float4 bb = *(const float4*)&Ks[jj][k4 << 2];
        acc += a.x * bb.x + a.y * bb.y + a.z * bb.z + a.w * bb.w;
      }
      S[r][(c << 6) + jj] = acc;
    }
  }
  __syncthreads();
  float pm = -3.0e38f;
#pragma unroll
  for (int u = 0; u < 16; ++u) pm = fmaxf(pm, S[r][jc + (u << 4)]);
  red[r][jc] = pm;
  __syncthreads();
  float m = red[r][0];
#pragma unroll
  for (int u = 1; u < 16; ++u) m = fmaxf(m, red[r][u]);
  __syncthreads();
  float ps = 0.f;
#pragma unroll
  for (int u = 0; u < 16; ++u) {
    const int j = jc + (u << 4);
    const float e = __expf(S[r][j] - m);
    S[r][j] = e;
    ps += e;
  }
  red[r][jc] = ps;
  __syncthreads();
  if (jc == 0) {
    float sum = 0.f;
#pragma unroll
    for (int u = 0; u < 16; ++u) sum += red[r][u];
    rowinv[r] = 1.0f / sum;
  }
  __syncthreads();
  for (int idx = tid; idx < 4096; idx += 256) {
    const int rr = idx >> 8, j = idx & 255;
    const float v = S[rr][j] * rowinv[rr];
    const unsigned short h = f2bf_(v);
    const size_t off = (size_t)bh * MM_STRIDE + (rg * 16 + rr) * 256 + j;
    x2hi[off] = (short)h;
    x2lo[off] = (short)f2bf_(v - bf2f_(h));
  }
}

// ---------------- global max of col/row abs-sums (hi/lo input) --------------
__global__ __launch_bounds__(256) void colrow_max(const short* __restrict__ x2hi,
                                                  const short* __restrict__ x2lo,
                                                  float* __restrict__ scal) {
  const int bh = blockIdx.x;
  const int tid = threadIdx.x;
  const size_t b0 = (size_t)bh * MM_STRIDE;
  float cs = 0.f, rs = 0.f;
  for (int j = 0; j < 256; ++j) {
    const size_t o = b0 + (size_t)tid * 256 + j;
    cs += fabsf(bf2f_((unsigned short)x2hi[o]) + bf2f_((unsigned short)x2lo[o]));
  }
  for (int i = 0; i < 256; ++i) {
    const size_t o = b0 + (size_t)i * 256 + tid;
    rs += fabsf(bf2f_((unsigned short)x2hi[o]) + bf2f_((unsigned short)x2lo[o]));
  }
  __shared__ float rc[256], rr[256];
  rc[tid] = cs; rr[tid] = rs;
  __syncthreads();
  for (int st = 128; st > 0; st >>= 1) {
    if (tid < st) {
      rc[tid] = fmaxf(rc[tid], rc[tid + st]);
      rr[tid] = fmaxf(rr[tid], rr[tid + st]);
    }
    __syncthreads();
  }
  if (tid == 0) {
    atomicMax((int*)&scal[0], __float_as_int(rc[0]));
    atomicMax((int*)&scal[1], __float_as_int(rr[0]));
  }
}

// --- z0 = x2^T/(cmax*rmax): A-form hi/lo + fp32, B-form (=x2/s) hi/lo -------
__global__ __launch_bounds__(256) void tscale2(const short* __restrict__ x2hi,
                                               const short* __restrict__ x2lo,
                                               const float* __restrict__ scal,
                                               short* __restrict__ zBhi,
                                               short* __restrict__ zBlo,
                                               short* __restrict__ zAhi,
                                               short* __restrict__ zAlo,
                                               float* __restrict__ zf) {
  const int g = blockIdx.x * 256 + threadIdx.x;
  const int j = g & 255, i = (g >> 8) & 255, bh = g >> 16;
  const float inv = 1.0f / (scal[0] * scal[1]);
  const float val = (bf2f_((unsigned short)x2hi[g]) +
                     bf2f_((unsigned short)x2lo[g])) * inv;
  const unsigned short h = f2bf_(val);
  const unsigned short lo = f2bf_(val - bf2f_(h));
  zBhi[g] = (short)h;
  zBlo[g] = (short)lo;
  const size_t tg = (size_t)bh * MM_STRIDE + (size_t)j * 256 + i;
  zAhi[tg] = (short)h;
  zAlo[tg] = (short)lo;
  zf[tg] = val;                     // fp32 A-form (exact E for step 4)
}

// --------- split-bf16 batched 256^3: C = alpha*Ef + beta*(A@B) --------------
// R4 tile structure (16x64, 512 blocks), BK=64 staging (4 K-steps). prec=1:
// 3-MFMA split path; prec=0: hi-only. wantLo gates dead lo stores (precision
// staging makes sloppy-consumed lo provably dead). E read fp32 (exact).
__global__ __launch_bounds__(256) void pinv_mfma(const short* __restrict__ Ahi_g,
                                                 const short* __restrict__ Alo_g,
                                                 const short* __restrict__ Bhi_g,
                                                 const short* __restrict__ Blo_g,
                                                 const float* __restrict__ Ef,
                                                 float* __restrict__ Cf,
                                                 short* __restrict__ Chi,
                                                 short* __restrict__ Clo,
                                                 short* __restrict__ CThi,
                                                 short* __restrict__ CTlo,
                                                 float alpha, float beta,
                                                 int wantCf, int wantChl,
                                                 int wantT, int wantLo,
                                                 int prec) {
  __shared__ short Ah[4096], Al[4096], Bh[4096], Bl[4096];   // [2][2048] halves
  __shared__ float Tbuf[64 * 68];
  const int tid = threadIdx.x;
  const int lane = tid & 63, w = tid >> 6;
  const int bid = blockIdx.x;
  const int xcd = bid & 7, y = bid >> 3;
  const int t16 = y & 15, bgrp = y >> 4;
  const int batch = bgrp * 8 + xcd;
  const int tm = t16 >> 2, tn = t16 & 3;
  const size_t bb = (size_t)batch * MM_STRIDE;
  const int ml = (tid >> 6) * 16 + (tid & 15), koff = ((tid >> 4) & 3) * 8;
  const short* sAh = Ahi_g + bb + (size_t)(tm * 64 + ml) * 256 + koff;
  const short* sAl = Alo_g + bb + (size_t)(tm * 64 + ml) * 256 + koff;
  const short* sBh = Bhi_g + bb + (size_t)(tn * 64 + ml) * 256 + koff;
  const short* sBl = Blo_g + bb + (size_t)(tn * 64 + ml) * 256 + koff;
  f32x4 acc[4];
#pragma unroll
  for (int j = 0; j < 4; ++j) acc[j] = (f32x4){0.f, 0.f, 0.f, 0.f};
  for (int kt = 0; kt < 4; ++kt) {
    const int k0 = kt * 64;
    __syncthreads();
    gl16(sAh + k0, &Ah[w * 512]);
    gl16(sAh + k0 + 32, &Ah[2048 + w * 512]);
    gl16(sBh + k0, &Bh[w * 512]);
    gl16(sBh + k0 + 32, &Bh[2048 + w * 512]);
    if (prec) {
      gl16(sAl + k0, &Al[w * 512]);
      gl16(sAl + k0 + 32, &Al[2048 + w * 512]);
      gl16(sBl + k0, &Bl[w * 512]);
      gl16(sBl + k0 + 32, &Bl[2048 + w * 512]);
    }
    __syncthreads();
#pragma unroll
    for (int st = 0; st < 2; ++st) {
      bf8 ah = *(const bf8*)&Ah[st * 2048 + (w * 64 + lane) * 8];
      if (prec) {
        bf8 al = *(const bf8*)&Al[st * 2048 + (w * 64 + lane) * 8];
#pragma unroll
        for (int j = 0; j < 4; ++j) {
          bf8 bh = *(const bf8*)&Bh[st * 2048 + (j * 64 + lane) * 8];
          bf8 bl = *(const bf8*)&Bl[st * 2048 + (j * 64 + lane) * 8];
          acc[j] = __builtin_amdgcn_mfma_f32_16x16x32_bf16(ah, bh, acc[j], 0, 0, 0);
          acc[j] = __builtin_amdgcn_mfma_f32_16x16x32_bf16(ah, bl, acc[j], 0, 0, 0);
          acc[j] = __builtin_amdgcn_mfma_f32_16x16x32_bf16(al, bh, acc[j], 0, 0, 0);
        }
      } else {
#pragma unroll
        for (int j = 0; j < 4; ++j) {
          bf8 bh = *(const bf8*)&Bh[st * 2048 + (j * 64 + lane) * 8];
          acc[j] = __builtin_amdgcn_mfma_f32_16x16x32_bf16(ah, bh, acc[j], 0, 0, 0);
        }
      }
    }
  }
  const int qd = lane >> 4, c = lane & 15;
  float vals[4][4];
#pragma unroll
  for (int j = 0; j < 4; ++j) {
    const int col = tn * 64 + j * 16 + c;
#pragma unroll
    for (int r = 0; r < 4; ++r) {
      const int row = tm * 64 + w * 16 + qd * 4 + r;
      const size_t off = bb + (size_t)row * 256 + col;
      float e = 0.f;
      if (alpha != 0.0f) e = alpha * Ef[off];
      const float vv = e + beta * acc[j][r];
      vals[j][r] = vv;
      if (wantCf) Cf[off] = vv;
      if (wantChl) {
        const unsigned short h = f2bf_(vv);
        Chi[off] = (short)h;
        if (wantLo) Clo[off] = (short)f2bf_(vv - bf2f_(h));
      }
    }
  }
  if (wantT) {
    __syncthreads();
#pragma unroll
    for (int j = 0; j < 4; ++j)
#pragma unroll
      for (int r = 0; r < 4; ++r)
        Tbuf[(j * 16 + c) * 68 + w * 16 + qd * 4 + r] = vals[j][r];
    __syncthreads();
    const int ctr = tid >> 2, seg = (tid & 3) * 16;
#pragma unroll
    for (int u = 0; u < 4; ++u) {
      float4 o = *(const float4*)&Tbuf[ctr * 68 + seg + u * 4];
      s4v hi, lo;
      unsigned short h;
      h = f2bf_(o.x); hi[0] = (short)h; lo[0] = (short)f2bf_(o.x - bf2f_(h));
      h = f2bf_(o.y); hi[1] = (short)h; lo[1] = (short)f2bf_(o.y - bf2f_(h));
      h = f2bf_(o.z); hi[2] = (short)h; lo[2] = (short)f2bf_(o.z - bf2f_(h));
      h = f2bf_(o.w); hi[3] = (short)h; lo[3] = (short)f2bf_(o.w - bf2f_(h));
      const size_t off = bb + (size_t)(tn * 64 + ctr) * 256 + tm * 64 + seg + u * 4;
      *(s4v*)&CThi[off] = hi;
      if (wantLo) *(s4v*)&CTlo[off] = lo;
    }
  }
}

// ---- attn3 flash, per-wave (barrier-free): each wave owns 16 ql rows -------
__global__ __launch_bounds__(256) void attn3_flash(const float* __restrict__ ql,
                                                   const short* __restrict__ kb16,
                                                   const short* __restrict__ vT16,
                                                   float* __restrict__ opart,
                                                   float* __restrict__ mpart,
                                                   float* __restrict__ lpart) {
  const int kc = blockIdx.x;   // key chunk 0..3 (1024 keys each)
  const int rt = blockIdx.y;   // row tile 0..3 (64 rows each)
  const int bh = blockIdx.z;   // 0..31
  __shared__ short Pa[4][4096];  // per-wave 16 rows x 256 keys, A-frag order
  const int tid = threadIdx.x, lane = tid & 63, w = tid >> 6;
  const int qd = lane >> 4, c = lane & 15;
  const int rw = rt * 64 + w * 16;               // wave's first global row
  const float* qlp = ql + (size_t)bh * LM_STRIDE;
  const short* kp = kb16 + (size_t)bh * QKV_STRIDE;
  const short* vp = vT16 + (size_t)bh * QKV_STRIDE;
  short* Pw = &Pa[w][0];
  bf8 af[2];
#pragma unroll
  for (int st = 0; st < 2; ++st) {
    float4 x0 = *(const float4*)&qlp[(size_t)(rw + c) * 64 + st * 32 + qd * 8];
    float4 x1 = *(const float4*)&qlp[(size_t)(rw + c) * 64 + st * 32 + qd * 8 + 4];
    bf8 r;
    r[0] = (short)f2bf_(x0.x); r[1] = (short)f2bf_(x0.y);
    r[2] = (short)f2bf_(x0.z); r[3] = (short)f2bf_(x0.w);
    r[4] = (short)f2bf_(x1.x); r[5] = (short)f2bf_(x1.y);
    r[6] = (short)f2bf_(x1.z); r[7] = (short)f2bf_(x1.w);
    af[st] = r;
  }
  float m[4], l[4];
#pragma unroll
  for (int r = 0; r < 4; ++r) { m[r] = -3.0e38f; l[r] = 0.f; }
  f32x4 accO[4];
#pragma unroll
  for (int nb = 0; nb < 4; ++nb) accO[nb] = (f32x4){0.f, 0.f, 0.f, 0.f};
  for (int it = 0; it < 4; ++it) {
    const int kb0 = kc * 1024 + it * 256;
    f32x4 acc[16];
#pragma unroll
    for (int j = 0; j < 16; ++j) acc[j] = (f32x4){0.f, 0.f, 0.f, 0.f};
#pragma unroll
    for (int st = 0; st < 2; ++st)
#pragma unroll
      for (int j = 0; j < 16; ++j) {
        bf8 bfk = *(const bf8*)&kp[(size_t)(kb0 + j * 16 + c) * 64 + st * 32 + qd * 8];
        acc[j] = __builtin_amdgcn_mfma_f32_16x16x32_bf16(af[st], bfk, acc[j], 0, 0, 0);
      }
#pragma unroll
    for (int r = 0; r < 4; ++r) {
      float mx = acc[0][r];
#pragma unroll
      for (int j = 1; j < 16; ++j) mx = fmaxf(mx, acc[j][r]);
      mx = fmaxf(mx, __shfl_xor(mx, 1));
      mx = fmaxf(mx, __shfl_xor(mx, 2));
      mx = fmaxf(mx, __shfl_xor(mx, 4));
      mx = fmaxf(mx, __shfl_xor(mx, 8));
      const float mN = fmaxf(m[r], mx);
      const float a = __expf(m[r] - mN);
      m[r] = mN;
      l[r] *= a;
#pragma unroll
      for (int nb = 0; nb < 4; ++nb) accO[nb][r] *= a;
      float s = 0.f;
#pragma unroll
      for (int j = 0; j < 16; ++j) {
        const float e = __expf(acc[j][r] - mN);
        acc[j][r] = e;
        s += e;
      }
      s += __shfl_xor(s, 1);
      s += __shfl_xor(s, 2);
      s += __shfl_xor(s, 4);
      s += __shfl_xor(s, 8);
      l[r] += s;
    }
#pragma unroll
    for (int j = 0; j < 16; ++j) {
      const int kcol = j * 16 + c;
      const int kb8 = kcol >> 5;
      const int la_base = 16 * ((kcol >> 3) & 3);
      const int j8 = kcol & 7;
#pragma unroll
      for (int r = 0; r < 4; ++r) {
        const int rl = qd * 4 + r;
        Pw[(kb8 * 64 + la_base + rl) * 8 + j8] = (short)f2bf_(acc[j][r]);
      }
    }
#pragma unroll
    for (int kbk = 0; kbk < 8; ++kbk) {
      bf8 ap = *(const bf8*)&Pw[(kbk * 64 + lane) * 8];
#pragma unroll
      for (int nb = 0; nb < 4; ++nb) {
        bf8 bv = *(const bf8*)&vp[(size_t)(nb * 16 + c) * 4096 + kb0 + kbk * 32 + qd * 8];
        accO[nb] = __builtin_amdgcn_mfma_f32_16x16x32_bf16(ap, bv, accO[nb], 0, 0, 0);
      }
    }
  }
  const size_t ob = ((size_t)kc * 32 + bh) * 256 + rt * 64;
#pragma unroll
  for (int nb = 0; nb < 4; ++nb)
#pragma unroll
    for (int r = 0; r < 4; ++r)
      opart[(ob + w * 16 + qd * 4 + r) * 64 + nb * 16 + c] = accO[nb][r];
  if (c == 0) {
#pragma unroll
    for (int r = 0; r < 4; ++r) {
      mpart[ob + w * 16 + qd * 4 + r] = m[r];
      lpart[ob + w * 16 + qd * 4 + r] = l[r];
    }
  }
}

// ------- merge the 4 key-chunk partials -> avT hi/lo bf16 [bh][d][row] ------
__global__ __launch_bounds__(256) void attn3_merge(const float* __restrict__ opart,
                                                   const float* __restrict__ mpart,
                                                   const float* __restrict__ lpart,
                                                   short* __restrict__ avth,
                                                   short* __restrict__ avtl) {
  const int g = blockIdx.x * 256 + threadIdx.x;   // 524288 = 32*256*64
  const int d = g & 63;
  const int idx = g >> 6;                          // bh*256+row
  const int bh = idx >> 8, row = idx & 255;
  const float m0 = mpart[idx], m1 = mpart[8192 + idx],
              m2 = mpart[16384 + idx], m3 = mpart[24576 + idx];
  const float mx = fmaxf(fmaxf(m0, m1), fmaxf(m2, m3));
  const float w0 = __expf(m0 - mx), w1 = __expf(m1 - mx),
              w2 = __expf(m2 - mx), w3 = __expf(m3 - mx);
  const float l = lpart[idx] * w0 + lpart[8192 + idx] * w1 +
                  lpart[16384 + idx] * w2 + lpart[24576 + idx] * w3;
  const float o = opart[(size_t)idx * 64 + d] * w0 +
                  opart[524288 + (size_t)idx * 64 + d] * w1 +
                  opart[1048576 + (size_t)idx * 64 + d] * w2 +
                  opart[1572864 + (size_t)idx * 64 + d] * w3;
  const float val = o / l;
  const unsigned short h = f2bf_(val);
  const size_t o2 = ((size_t)bh * 64 + d) * 256 + row;
  avth[o2] = (short)h;
  avtl[o2] = (short)f2bf_(val - bf2f_(h));
}

// ------- w2^T = (z_final @ av)^T via split-bf16 MFMA ------------------------
__global__ __launch_bounds__(256) void zav_mfma(const short* __restrict__ zAhi,
                                                const short* __restrict__ zAlo,
                                                const short* __restrict__ avth,
                                                const short* __restrict__ avtl,
                                                short* __restrict__ w2tb16) {
  __shared__ short Tb[64 * 68];
  const int rt = blockIdx.x;      // 0..3
  const int bh = blockIdx.y;      // 0..31
  const int tid = threadIdx.x, lane = tid & 63, w = tid >> 6;
  const int qd = lane >> 4, c = lane & 15;
  const size_t zoff = (size_t)bh * MM_STRIDE + (size_t)(rt * 64 + w * 16 + c) * 256;
  const short* zh = zAhi + zoff;
  const short* zl = zAlo + zoff;
  const short* ahp = avth + (size_t)bh * LM_STRIDE;
  const short* alp = avtl + (size_t)bh * LM_STRIDE;
  f32x4 acc[4];
#pragma unroll
  for (int j = 0; j < 4; ++j) acc[j] = (f32x4){0.f, 0.f, 0.f, 0.f};
  for (int kt = 0; kt < 8; ++kt) {
    const int k0 = kt * 32 + qd * 8;
    bf8 ah = *(const bf8*)&zh[k0];
    bf8 al = *(const bf8*)&zl[k0];
#pragma unroll
    for (int j = 0; j < 4; ++j) {
      bf8 bhj = *(const bf8*)&ahp[(size_t)(j * 16 + c) * 256 + k0];
      bf8 blj = *(const bf8*)&alp[(size_t)(j * 16 + c) * 256 + k0];
      acc[j] = __builtin_amdgcn_mfma_f32_16x16x32_bf16(ah, bhj, acc[j], 0, 0, 0);
      acc[j] = __builtin_amdgcn_mfma_f32_16x16x32_bf16(ah, blj, acc[j], 0, 0, 0);
      acc[j] = __builtin_amdgcn_mfma_f32_16x16x32_bf16(al, bhj, acc[j], 0, 0, 0);
    }
  }
#pragma unroll
  for (int j = 0; j < 4; ++j)
#pragma unroll
    for (int r = 0; r < 4; ++r)
      Tb[(j * 16 + c) * 68 + w * 16 + qd * 4 + r] = (short)f2bf_(acc[j][r]);
  __syncthreads();
  const int col = tid >> 2, rs = (tid & 3) * 16;
  short* dst = &w2tb16[(size_t)bh * LM_STRIDE + (size_t)col * 256 + rt * 64 + rs];
  const short* srcp = &Tb[col * 68 + rs];
#pragma unroll
  for (int u = 0; u < 4; ++u) *(s4v*)&dst[u * 4] = *(const s4v*)&srcp[u * 4];
}

// -- attn1+conv: oh = softmax(q@kl^T)@w2 + conv(v) [conv via banded MFMA] ----
// 32-row blocks (R8-verified best: grid 4096, Pa 16KB -> ~8 blocks/CU).
// Wave w: QK cols w*64..+63; PV/conv rows (w&1)*16, cols (w>>1)*32. XCD remap.
__global__ __launch_bounds__(256) void attn1_conv_mfma(const short* __restrict__ qb16,
                                                       const short* __restrict__ klb16,
                                                       const short* __restrict__ w2tb16,
                                                       const short* __restrict__ vT16,
                                                       const float* __restrict__ cw,
                                                       short* __restrict__ ohb16) {
  __shared__ short Pa[8192];                // 32x256 bf16 in A-frag order (16KB)
  __shared__ float redM[4][32], redS[4][32];
  __shared__ float rowM[32], rowI[32];
  __shared__ float cwS[33];
  const int tid = threadIdx.x;
  const int lane = tid & 63, w = tid >> 6;
  const int qd = lane >> 4, c = lane & 15;
  const int lin = blockIdx.y * 128 + blockIdx.x;   // grid (128,32) -> 0..4095
  const int xcd = lin & 7;
  const int idx = lin >> 3;                        // 0..511
  const int bh = xcd * 4 + (idx >> 7);             // 4 bh per XCD
  const int r0 = (idx & 127) * 32;                 // 32-row tile
  const short* qp = qb16 + (size_t)bh * QKV_STRIDE;
  const short* klp = klb16 + (size_t)bh * LM_STRIDE;
  const short* w2p = w2tb16 + (size_t)bh * LM_STRIDE;
  const short* vp = vT16 + (size_t)bh * QKV_STRIDE;

  if (tid < 33) cwS[tid] = cw[(bh & 7) * 33 + tid];

  // ---- QK^T: S[32][256], wave w owns cols w*64..+63 ----
  f32x4 acc[2][4];
#pragma unroll
  for (int i = 0; i < 2; ++i)
#pragma unroll
    for (int j = 0; j < 4; ++j) acc[i][j] = (f32x4){0.f, 0.f, 0.f, 0.f};
#pragma unroll
  for (int st = 0; st < 2; ++st) {
    const int k0 = st * 32 + qd * 8;
    bf8 af[2], bf[4];
#pragma unroll
    for (int i = 0; i < 2; ++i)
      af[i] = *(const bf8*)&qp[(size_t)(r0 + i * 16 + c) * 64 + k0];
#pragma unroll
    for (int j = 0; j < 4; ++j)
      bf[j] = *(const bf8*)&klp[(size_t)(w * 64 + j * 16 + c) * 64 + k0];
#pragma unroll
    for (int i = 0; i < 2; ++i)
#pragma unroll
      for (int j = 0; j < 4; ++j)
        acc[i][j] = __builtin_amdgcn_mfma_f32_16x16x32_bf16(af[i], bf[j], acc[i][j], 0, 0, 0);
  }
  // ---- row max (over 4 waves x 64 cols each) ----
#pragma unroll
  for (int i = 0; i < 2; ++i)
#pragma unroll
    for (int r = 0; r < 4; ++r) {
      float m0 = fmaxf(fmaxf(acc[i][0][r], acc[i][1][r]),
                       fmaxf(acc[i][2][r], acc[i][3][r]));
      m0 = fmaxf(m0, __shfl_xor(m0, 1));
      m0 = fmaxf(m0, __shfl_xor(m0, 2));
      m0 = fmaxf(m0, __shfl_xor(m0, 4));
      m0 = fmaxf(m0, __shfl_xor(m0, 8));
      if (c == 0) redM[w][i * 16 + qd * 4 + r] = m0;
    }
  __syncthreads();
  if (tid < 32)
    rowM[tid] = fmaxf(fmaxf(redM[0][tid], redM[1][tid]),
                      fmaxf(redM[2][tid], redM[3][tid]));
  __syncthreads();
  // ---- exp + row sum ----
#pragma unroll
  for (int i = 0; i < 2; ++i)
#pragma unroll
    for (int r = 0; r < 4; ++r) {
      const float mrow = rowM[i * 16 + qd * 4 + r];
      float s = 0.f;
#pragma unroll
      for (int j = 0; j < 4; ++j) {
        const float e = __expf(acc[i][j][r] - mrow);
        acc[i][j][r] = e;
        s += e;
      }
      s += __shfl_xor(s, 1);
      s += __shfl_xor(s, 2);
      s += __shfl_xor(s, 4);
      s += __shfl_xor(s, 8);
      if (c == 0) redS[w][i * 16 + qd * 4 + r] = s;
    }
  __syncthreads();
  if (tid < 32)
    rowI[tid] = 1.0f / (redS[0][tid] + redS[1][tid] + redS[2][tid] + redS[3][tid]);
  __syncthreads();
  // ---- P -> Pa (A-frag order: tile (kb,i), lane2, elem) ----
#pragma unroll
  for (int i = 0; i < 2; ++i)
#pragma unroll
    for (int r = 0; r < 4; ++r) {
      const int row = i * 16 + qd * 4 + r;
      const float inv = rowI[row];
#pragma unroll
      for (int j = 0; j < 4; ++j) {
        const int col = w * 64 + j * 16 + c;
        const short val = (short)f2bf_(acc[i][j][r] * inv);
        const int kb = col >> 5;
        const int lane2 = (row & 15) + 16 * ((col >> 3) & 3);
        Pa[((kb * 2 + i) * 64 + lane2) * 8 + (col & 7)] = val;
      }
    }
  __syncthreads();
  // ---- PV: wave w -> rows (w&1)*16, cols (w>>1)*32 ----
  const int iw = w & 1, ch = w >> 1;
  f32x4 accO[2];
#pragma unroll
  for (int nb = 0; nb < 2; ++nb) accO[nb] = (f32x4){0.f, 0.f, 0.f, 0.f};
  for (int kb = 0; kb < 8; ++kb) {
    bf8 ap = *(const bf8*)&Pa[((kb * 2 + iw) * 64 + lane) * 8];
#pragma unroll
    for (int nb = 0; nb < 2; ++nb) {
      bf8 bfr = *(const bf8*)&w2p[(size_t)(ch * 32 + nb * 16 + c) * 256 + kb * 32 + qd * 8];
      accO[nb] = __builtin_amdgcn_mfma_f32_16x16x32_bf16(ap, bfr, accO[nb], 0, 0, 0);
    }
  }
  // ---- conv residual: Band[16x64] @ Vwin[64x32] per wave ----
  {
    bf8 ba[2];
    const int rl = iw * 16 + (lane & 15);   // row within 32-row block
#pragma unroll
    for (int kb = 0; kb < 2; ++kb) {
#pragma unroll
      for (int e = 0; e < 8; ++e) {
        const int kk = kb * 32 + qd * 8 + e;
        const int t = kk - rl;
        const int s = r0 - 16 + kk;
        const float bv = (t >= 0 && t < 33 && s >= 0 && s < 4096) ? cwS[t] : 0.f;
        ba[kb][e] = (short)f2bf_(bv);
      }
    }
#pragma unroll
    for (int kb = 0; kb < 2; ++kb) {
      int s0 = r0 - 16 + kb * 32 + qd * 8;
      s0 = s0 < 0 ? 0 : (s0 > 4088 ? 4088 : s0);
#pragma unroll
      for (int nb = 0; nb < 2; ++nb) {
        bf8 bv = *(const bf8*)&vp[(size_t)(ch * 32 + nb * 16 + c) * 4096 + s0];
        accO[nb] = __builtin_amdgcn_mfma_f32_16x16x32_bf16(ba[kb], bv, accO[nb], 0, 0, 0);
      }
    }
  }
  short* ohp = (short*)ohb16 + (size_t)bh * QKV_STRIDE;
#pragma unroll
  for (int nb = 0; nb < 2; ++nb)
#pragma unroll
    for (int r = 0; r < 4; ++r) {
      const int row = r0 + iw * 16 + qd * 4 + r;
      ohp[(size_t)row * 64 + ch * 32 + nb * 16 + c] = (short)f2bf_(accO[nb][r]);
    }
}

// ------- out = concat_heads(oh_bf16) @ w_out + b_out (MFMA) -----------------
// BK=64 staged global_load_lds (8 K-steps); XCD-swizzled 1-D grid (512=8*64).
__global__ __launch_bounds__(256) void gemm_out_mfma(const short* __restrict__ ohb16,
                                                     const short* __restrict__ wT,
                                                     const float* __restrict__ bias,
                                                     float* __restrict__ out) {
  __shared__ short As[8192];      // [2][4096] halves
  __shared__ short Bs[8192];
  const int tid = threadIdx.x;
  const int lane = tid & 63, w = tid >> 6;
  const int wr = w >> 1, wc = w & 1;
  const int bid = (blockIdx.x & 7) * 64 + (blockIdx.x >> 3);   // 512 = 8*64
  const int bn = bid & 3, bm = bid >> 2;
  const int gm0 = bm * 128, gn0 = bn * 128;
  const int mA0 = (tid >> 6) * 16 + (tid & 15), kA0 = ((tid >> 4) & 3) * 8;
  const int s1 = tid + 256;
  const int mA1 = (s1 >> 6) * 16 + (s1 & 15), kA1 = ((s1 >> 4) & 3) * 8;
  const int b0r = (gm0 + mA0) >> 12, seq0 = (gm0 + mA0) & 4095;
  const int b1r = (gm0 + mA1) >> 12, seq1 = (gm0 + mA1) & 4095;
  f32x4 acc[4][4];
#pragma unroll
  for (int i = 0; i < 4; ++i)
#pragma unroll
    for (int j = 0; j < 4; ++j) acc[i][j] = (f32x4){0.f, 0.f, 0.f, 0.f};
  for (int kt = 0; kt < 8; ++kt) {
    __syncthreads();
#pragma unroll
    for (int hf = 0; hf < 2; ++hf) {
      const int ka = kt * 64 + hf * 32 + kA0, kb = kt * 64 + hf * 32 + kA1;
      gl16(&ohb16[(size_t)(b0r * 8 + (ka >> 6)) * QKV_STRIDE + (size_t)seq0 * 64 + (ka & 63)],
           &As[hf * 4096 + w * 512]);
      gl16(&ohb16[(size_t)(b1r * 8 + (kb >> 6)) * QKV_STRIDE + (size_t)seq1 * 64 + (kb & 63)],
           &As[hf * 4096 + 2048 + w * 512]);
      gl16(&wT[(size_t)(gn0 + mA0) * 512 + ka], &Bs[hf * 4096 + w * 512]);
      gl16(&wT[(size_t)(gn0 + mA1) * 512 + kb], &Bs[hf * 4096 + 2048 + w * 512]);
    }
    __syncthreads();
#pragma unroll
    for (int st = 0; st < 2; ++st) {
      bf8 af[4], bfr[4];
#pragma unroll
      for (int i = 0; i < 4; ++i) {
        af[i] = *(const bf8*)&As[st * 4096 + ((wr * 4 + i) * 64 + lane) * 8];
        bfr[i] = *(const bf8*)&Bs[st * 4096 + ((wc * 4 + i) * 64 + lane) * 8];
      }
#pragma unroll
      for (int i = 0; i < 4; ++i)
#pragma unroll
        for (int j = 0; j < 4; ++j)
          acc[i][j] = __builtin_amdgcn_mfma_f32_16x16x32_bf16(af[i], bfr[j], acc[i][j], 0, 0, 0);
    }
  }
  const int qd = lane >> 4, c = lane & 15;
#pragma unroll
  for (int i = 0; i < 4; ++i)
#pragma unroll
    for (int j = 0; j < 4; ++j) {
      const int col = gn0 + wc * 64 + j * 16 + c;
      const float bval = bias[col];
#pragma unroll
      for (int r = 0; r < 4; ++r) {
        const int row = gm0 + wr * 64 + i * 16 + qd * 4 + r;
        out[(size_t)row * 512 + col] = acc[i][j][r] + bval;
      }
    }
}

// ---------------------------------------------------------------------------
extern "C" void kernel_launch(void* const* d_in, const int* in_sizes, int n_in,
                              void* d_out, int out_size, void* d_ws, size_t ws_size,
                              hipStream_t stream) {
  const float* x    = (const float*)d_in[0];
  const float* wqkv = (const float*)d_in[1];
  const float* wout = (const float*)d_in[2];
  const float* bout = (const float*)d_in[3];
  const float* cw   = (const float*)d_in[4];
  float* out = (float*)d_out;

  float* w = (float*)d_ws;
  // ---- compact layout: 37,486,656 floats total (~150 MB) ----
  short* qb16   = (short*)(w);              // [32,4096,64] bf16   (4194304 fl)
  short* kb16   = (short*)(w + 4194304);
  short* vT16   = (short*)(w + 8388608);    // [32,64,4096] bf16
  // region 12582912..16777216 (4194304 fl), time-multiplexed:
  short* xb16   = (short*)(w + 12582912);   // phase 1: x bf16 (dead after qkv)
  float* z0f    = w + 12582912;             // phase 2: fp32 z ping (2097152)
  float* z1f    = w + 14680064;             // phase 2: fp32 z pong (2097152)
  float* opart  = w + 12582912;             // phase 3: [4,32,256,64] (2097152)
  short* ohb16  = (short*)(w + 12582912);   // phase 4: oh bf16 (4194304 fl)
  float* ql     = w + 16777216;             // [32,256,64] fp32 (524288)
  float* kl     = w + 17301504;
  short* klb16  = (short*)(w + 17825792);   // (262144 fl)
  short* x2hi   = (short*)(w + 18087936);   // hi/lo pairs: 1048576 fl each
  short* x2lo   = (short*)(w + 19136512);
  float* xzf    = w + 20185088;             // fp32 xz (E steps 2,3) (2097152)
  short* xzAhi  = (short*)(w + 22282240);
  short* xzAlo  = (short*)(w + 23330816);
  short* xzBhi  = (short*)(w + 24379392);   // also u2B (xzB dead after step 2)
  short* xzBlo  = (short*)(w + 25427968);
  short* u1Bhi  = (short*)(w + 26476544);
  short* u1Blo  = (short*)(w + 27525120);
  short* z0Ahi  = (short*)(w + 28573696);
  short* z0Alo  = (short*)(w + 29622272);
  short* z0Bhi  = (short*)(w + 30670848);
  short* z0Blo  = (short*)(w + 31719424);
  short* z1Ahi  = (short*)(w + 32768000);
  short* z1Alo  = (short*)(w + 33816576);
  short* z1Bhi  = (short*)(w + 34865152);
  short* z1Blo  = (short*)(w + 35913728);
  float* scal   = w + 36962304;             // [2]
  short* wqkvT  = (short*)(w + 36962368);   // [1536,512] bf16 (393216 fl)
  short* woutT  = (short*)(w + 37355584);   // [512,512] bf16 (131072 fl)
  // end: 37486656 floats (~150 MB)
  // post-pinv aliases (xzf/xzA/u1B dead after the loop):
  short* avth   = (short*)(w + 20185088);   // [32,64,256] bf16 (262144 fl)
  short* avtl   = (short*)(w + 20447232);
  short* w2tb16 = (short*)(w + 20709376);   // [32,256,64] bf16 (262144 fl)
  float* mpart  = w + 26476544;             // [4,32,256] (32768 fl, in u1Bhi)
  float* lpart  = w + 26509312;

  zero_scal<<<1, 64, 0, stream>>>(scal);
  transpose_bf16<<<dim3(48, 16), 256, 0, stream>>>(wqkv, wqkvT, 512, 1536);
  transpose_bf16<<<dim3(16, 16), 256, 0, stream>>>(wout, woutT, 512, 512);
  x_to_bf16<<<2048, 256, 0, stream>>>(x, xb16);
  gemm_qkv_mfma<<<1536, 256, 0, stream>>>(xb16, wqkvT, qb16, kb16, vT16);
  lmk_mean<<<2048, 256, 0, stream>>>(qb16, kb16, ql, kl, klb16);
  sim2_softmax<<<512, 256, 0, stream>>>(ql, kl, x2hi, x2lo);
  colrow_max<<<32, 256, 0, stream>>>(x2hi, x2lo, scal);
  // overwrites xb16 region with z0f -- xb16 dead after gemm_qkv.
  tscale2<<<8192, 256, 0, stream>>>(x2hi, x2lo, scal, z0Bhi, z0Blo, z0Ahi, z0Alo, z0f);

  float *zcf = z0f, *znf = z1f;
  short *zAh = z0Ahi, *zAl = z0Alo, *zBh = z0Bhi, *zBl = z0Blo;
  short *nAh = z1Ahi, *nAl = z1Alo, *nBh = z1Bhi, *nBl = z1Blo;
  for (int it = 0; it < 6; ++it) {
    const int pr = (it >= 4) ? 1 : 0;  // iters 0-3 hi-only (NS self-corrects)
    const int nl = (it < 5) ? 1 : 0;   // final iter: fp32 zn + B-form unused
    const int lo123 = pr;              // steps 1-3 lo consumed iff this iter precise
    const int lo4 = (it >= 3) ? 1 : 0; // step-4 lo consumed iff NEXT consumer precise
    // xz = x2 @ z
    pinv_mfma<<<512, 256, 0, stream>>>(x2hi, x2lo, zBh, zBl, xzf,
                                       xzf, xzAhi, xzAlo, xzBhi, xzBlo,
                                       0.f, 1.f, 1, 1, 1, lo123, pr);
    // u1 = 7*xz - xz@xz   (only u1^T needed)
    pinv_mfma<<<512, 256, 0, stream>>>(xzAhi, xzAlo, xzBhi, xzBlo, xzf,
                                       znf, u1Bhi, u1Blo, u1Bhi, u1Blo,
                                       7.f, -1.f, 0, 0, 1, lo123, pr);
    // u2 = 15*xz - xz@u1  (only u2^T needed; overwrites xzB slots)
    pinv_mfma<<<512, 256, 0, stream>>>(xzAhi, xzAlo, u1Bhi, u1Blo, xzf,
                                       znf, xzBhi, xzBlo, xzBhi, xzBlo,
                                       15.f, -1.f, 0, 0, 1, lo123, pr);
    // zn = 3.25*z - 0.25*z@u2  (trimmed on it=5)
    pinv_mfma<<<512, 256, 0, stream>>>(zAh, zAl, xzBhi, xzBlo, zcf,
                                       znf, nAh, nAl, nBh, nBl,
                                       3.25f, -0.25f, nl, 1, nl, lo4, pr);
    float* tf = zcf; zcf = znf; znf = tf;
    short* t;
    t = zAh; zAh = nAh; nAh = t;  t = zAl; zAl = nAl; nAl = t;
    t = zBh; zBh = nBh; nBh = t;  t = zBl; zBl = nBl; nBl = t;
  }
  // zAh/zAl == z0A here (6 swaps). z0f/z1f/xzf/xzA/u1B dead -> aliases live.
  // opart overwrites z0f region (dead); read by merge before ohb16 is written.

  attn3_flash<<<dim3(4, 4, 32), 256, 0, stream>>>(ql, kb16, vT16, opart, mpart, lpart);
  attn3_merge<<<2048, 256, 0, stream>>>(opart, mpart, lpart, avth, avtl);
  zav_mfma<<<dim3(4, 32), 256, 0, stream>>>(zAh, zAl, avth, avtl, w2tb16);
  // attn1_conv writes ohb16 over the opart/z0f/z1f region (all dead now).
  attn1_conv_mfma<<<dim3(128, 32), 256, 0, stream>>>(qb16, klb16, w2tb16, vT16, cw, ohb16);
  gemm_out_mfma<<<512, 256, 0, stream>>>(ohb16, woutT, bout, out);
}

// Round 12
// 687.567 us; speedup vs baseline: 1.1464x; 1.0376x over previous
//
#include <hip/hip_runtime.h>
#include <math.h>

// ---------------------------------------------------------------------------
// NystromAttention round 19: R11 (713us) + (a) single-precise-iteration NS:
// the 13/15/7 polynomial is ORDER-3 (f'(1)=f''(1)=0), and NS-for-inverse is
// fully self-correcting, so 5 hi-only iterations + 1 split-bf16 iteration
// contract bf16-grade error to ~5e-7 relative; (b) zero_scal folded into
// x_to_bf16 (-1 launch). Dead-lo gating updated (lo123=pr, lo4=it>=4; final
// zA hi+lo still written for zav's split MFMA).
// b=4 n=4096 dim=512 h=8 d=64 m=256, l=16, iters=6, conv k=33.
// MFMA 16x16x32_bf16 layouts (HW-verified per guide):
//   A: m=lane&15, k=(lane>>4)*8+j    B: n=lane&15, k=(lane>>4)*8+j
//   C/D: col=lane&15, row=(lane>>4)*4+reg
// ---------------------------------------------------------------------------

#define QKV_STRIDE 262144   // 4096*64 per (b,h)
#define LM_STRIDE 16384     // 256*64
#define MM_STRIDE 65536     // 256*256

typedef float f32x4 __attribute__((ext_vector_type(4)));
typedef short bf8 __attribute__((ext_vector_type(8)));   // 8 bf16 in 4 VGPRs
typedef short s4v __attribute__((ext_vector_type(4)));

__device__ __forceinline__ unsigned short f2bf_(float f) {
  unsigned u = __float_as_uint(f);
  u += 0x7FFFu + ((u >> 16) & 1u);   // RNE
  return (unsigned short)(u >> 16);
}
__device__ __forceinline__ float bf2f_(unsigned short h) {
  return __uint_as_float(((unsigned)h) << 16);
}

// async global->LDS, 16B per lane; LDS dest must be wave-uniform base.
__device__ __forceinline__ void gl16(const short* g, short* l) {
  __builtin_amdgcn_global_load_lds(
      (const __attribute__((address_space(1))) unsigned int*)g,
      (__attribute__((address_space(3))) unsigned int*)l, 16, 0, 0);
}

// ---------------- x (fp32) -> xb16 (bf16 row-major) + scal zero -------------
__global__ __launch_bounds__(256) void x_to_bf16(const float* __restrict__ x,
                                                 short* __restrict__ xb,
                                                 float* __restrict__ scal) {
  const int g = blockIdx.x * 256 + threadIdx.x;   // 524288 threads
  if (g < 2) scal[g] = 0.0f;
  const float4* xp = (const float4*)x;
#pragma unroll
  for (int u = 0; u < 4; ++u) {
    const size_t i4 = (size_t)u * 524288 + g;
    float4 v = xp[i4];
    s4v o;
    o[0] = (short)f2bf_(v.x); o[1] = (short)f2bf_(v.y);
    o[2] = (short)f2bf_(v.z); o[3] = (short)f2bf_(v.w);
    *(s4v*)&xb[i4 * 4] = o;
  }
}

// ------------- transpose + fp32->bf16: dst[C][R] = bf16(src[R][C]) ----------
__global__ __launch_bounds__(256) void transpose_bf16(const float* __restrict__ src,
                                                      short* __restrict__ dst,
                                                      int R, int C) {
  __shared__ float T[32][33];
  const int t = threadIdx.x;
  const int c0 = blockIdx.x * 32, r0 = blockIdx.y * 32;
  const int tr = t >> 3, tc = (t & 7) << 2;
  float4 vsrc = *(const float4*)&src[(size_t)(r0 + tr) * C + c0 + tc];
  T[tr][tc + 0] = vsrc.x; T[tr][tc + 1] = vsrc.y;
  T[tr][tc + 2] = vsrc.z; T[tr][tc + 3] = vsrc.w;
  __syncthreads();
  s4v o;
  o[0] = (short)f2bf_(T[tc + 0][tr]);
  o[1] = (short)f2bf_(T[tc + 1][tr]);
  o[2] = (short)f2bf_(T[tc + 2][tr]);
  o[3] = (short)f2bf_(T[tc + 3][tr]);
  *(s4v*)&dst[(size_t)(c0 + tr) * R + r0 + tc] = o;
}

// ---- qkv = xb16 @ w_qkv via MFMA -> qb16/kb16 row-major, vT16 transposed ---
// BK=64 staged global_load_lds (8 K-steps, 2 barriers each);
// XCD-swizzled 1-D grid (bijective, 1536 = 8*192).
__global__ __launch_bounds__(256) void gemm_qkv_mfma(const short* __restrict__ xb,
                                                     const short* __restrict__ wT,
                                                     short* __restrict__ qb16,
                                                     short* __restrict__ kb16,
                                                     short* __restrict__ vT16) {
  __shared__ short SMEM[17408];   // staging: As[2][4096] Bs[2][4096]; V: 128x136
  short* As = SMEM;               // halves at 0 / 4096
  short* Bs = SMEM + 8192;        // halves at 0 / 4096
  const int tid = threadIdx.x;
  const int lane = tid & 63, w = tid >> 6;
  const int wr = w >> 1, wc = w & 1;
  const int bid = (blockIdx.x & 7) * 192 + (blockIdx.x >> 3);  // 1536 = 8*192
  const int bn = bid % 12, bm = bid / 12;
  const int gm0 = bm * 128, gn0 = bn * 128;
  const int mA0 = (tid >> 6) * 16 + (tid & 15), kA0 = ((tid >> 4) & 3) * 8;
  const int s1 = tid + 256;
  const int mA1 = (s1 >> 6) * 16 + (s1 & 15), kA1 = ((s1 >> 4) & 3) * 8;
  const short* srcA0 = &xb[(size_t)(gm0 + mA0) * 512 + kA0];
  const short* srcA1 = &xb[(size_t)(gm0 + mA1) * 512 + kA1];
  const short* srcB0 = &wT[(size_t)(gn0 + mA0) * 512 + kA0];
  const short* srcB1 = &wT[(size_t)(gn0 + mA1) * 512 + kA1];
  f32x4 acc[4][4];
#pragma unroll
  for (int i = 0; i < 4; ++i)
#pragma unroll
    for (int j = 0; j < 4; ++j) acc[i][j] = (f32x4){0.f, 0.f, 0.f, 0.f};
  for (int kt = 0; kt < 8; ++kt) {
    const int k0 = kt * 64;
    __syncthreads();                 // prev-step LDS reads done before overwrite
    gl16(srcA0 + k0, &As[w * 512]);
    gl16(srcA1 + k0, &As[2048 + w * 512]);
    gl16(srcA0 + k0 + 32, &As[4096 + w * 512]);
    gl16(srcA1 + k0 + 32, &As[4096 + 2048 + w * 512]);
    gl16(srcB0 + k0, &Bs[w * 512]);
    gl16(srcB1 + k0, &Bs[2048 + w * 512]);
    gl16(srcB0 + k0 + 32, &Bs[4096 + w * 512]);
    gl16(srcB1 + k0 + 32, &Bs[4096 + 2048 + w * 512]);
    __syncthreads();                 // drains vmcnt -> tile resident
#pragma unroll
    for (int st = 0; st < 2; ++st) {
      bf8 af[4], bf[4];
#pragma unroll
      for (int i = 0; i < 4; ++i) {
        af[i] = *(const bf8*)&As[st * 4096 + ((wr * 4 + i) * 64 + lane) * 8];
        bf[i] = *(const bf8*)&Bs[st * 4096 + ((wc * 4 + i) * 64 + lane) * 8];
      }
#pragma unroll
      for (int i = 0; i < 4; ++i)
#pragma unroll
        for (int j = 0; j < 4; ++j)
          acc[i][j] = __builtin_amdgcn_mfma_f32_16x16x32_bf16(af[i], bf[j], acc[i][j], 0, 0, 0);
    }
  }
  const int which = bn >> 2;  // 0:q 1:k 2:v
  const int qd = lane >> 4, c = lane & 15;
  if (which < 2) {
    short* dst = which == 0 ? qb16 : kb16;
    const float scale = which == 0 ? 0.125f : 1.0f;
#pragma unroll
    for (int i = 0; i < 4; ++i)
#pragma unroll
      for (int j = 0; j < 4; ++j) {
        const int col = gn0 + wc * 64 + j * 16 + c;
        const int head = (col >> 6) & 7, dd = col & 63;
#pragma unroll
        for (int r = 0; r < 4; ++r) {
          const int row = gm0 + wr * 64 + i * 16 + qd * 4 + r;
          const int b = row >> 12, seq = row & 4095;
          dst[(size_t)(b * 8 + head) * QKV_STRIDE + seq * 64 + dd] =
              (short)f2bf_(acc[i][j][r] * scale);
        }
      }
  } else {
    __syncthreads();
#pragma unroll
    for (int i = 0; i < 4; ++i)
#pragma unroll
      for (int j = 0; j < 4; ++j) {
        const int colL = wc * 64 + j * 16 + c;
#pragma unroll
        for (int r = 0; r < 4; ++r) {
          const int rowL = wr * 64 + i * 16 + qd * 4 + r;
          SMEM[colL * 136 + rowL] = (short)f2bf_(acc[i][j][r]);
        }
      }
    __syncthreads();
    const int b = gm0 >> 12, seq0 = gm0 & 4095;
    const int dcol = tid >> 1, half = tid & 1;
    const int col = gn0 + dcol;
    const int head = (col >> 6) & 7, d = col & 63;
    const short* src = &SMEM[dcol * 136 + half * 64];
    short* dstp = &vT16[(size_t)(b * 8 + head) * QKV_STRIDE + (size_t)d * 4096 +
                        seq0 + half * 64];
#pragma unroll
    for (int u = 0; u < 16; ++u) *(s4v*)&dstp[u * 4] = *(const s4v*)&src[u * 4];
  }
}

// ---------------- landmark means (bf16 in, fp32 + bf16-kl out) --------------
__global__ __launch_bounds__(256) void lmk_mean(const short* __restrict__ qb16,
                                                const short* __restrict__ kb16,
                                                float* __restrict__ ql,
                                                float* __restrict__ kl,
                                                short* __restrict__ klb16) {
  const int g = blockIdx.x * 256 + threadIdx.x;
  const int dd = g & 63, mi = (g >> 6) & 255, bh = g >> 14;
  const size_t base = (size_t)bh * QKV_STRIDE + mi * 1024 + dd;
  float sq = 0.f, sk = 0.f;
#pragma unroll
  for (int jj = 0; jj < 16; ++jj) {
    sq += bf2f_((unsigned short)qb16[base + jj * 64]);
    sk += bf2f_((unsigned short)kb16[base + jj * 64]);
  }
  const float qv = sq * 0.0625f, kv = sk * 0.0625f;
  ql[g] = qv;
  kl[g] = kv;
  klb16[g] = (short)f2bf_(kv);
}

// ---------------- sim2 = ql @ kl^T, softmax -> x2 hi/lo ---------------------
__global__ __launch_bounds__(256) void sim2_softmax(const float* __restrict__ ql,
                                                    const float* __restrict__ kl,
                                                    short* __restrict__ x2hi,
                                                    short* __restrict__ x2lo) {
  const int blk = blockIdx.x;
  const int bh = blk >> 4, rg = blk & 15;
  __shared__ float Qs[16][64];
  __shared__ float Ks[64][68];
  __shared__ float S[16][257];
  __shared__ float red[16][17];
  __shared__ float rowinv[16];
  const int tid = threadIdx.x;
  const int r = tid >> 4, jc = tid & 15;
#pragma unroll
  for (int u = 0; u < 4; ++u) {
    int t2 = tid + u * 256;
    Qs[t2 >> 6][t2 & 63] =
        ql[(size_t)bh * LM_STRIDE + (rg * 16 + (t2 >> 6)) * 64 + (t2 & 63)];
  }
  for (int c = 0; c < 4; ++c) {
    __syncthreads();
#pragma unroll
    for (int u = 0; u < 4; ++u) {
      int t4 = tid + u * 256;
      int row = t4 >> 4, c4 = (t4 & 15) << 2;
      *(float4*)&Ks[row][c4] =
          *(const float4*)&kl[(size_t)bh * LM_STRIDE + (c * 64 + row) * 64 + c4];
    }
    __syncthreads();
#pragma unroll
    for (int s = 0; s < 4; ++s) {
      const int jj = jc + (s << 4);
      float acc = 0.f;
#pragma unroll
      for (int k4 = 0; k4 < 16; ++k4) {
        const float4 a = *(const float4*)&Qs[r][k4 << 2];
        const float4 bb = *(const float4*)&Ks[jj][k4 << 2];
        acc += a.x * bb.x + a.y * bb.y + a.z * bb.z + a.w * bb.w;
      }
      S[r][(c << 6) + jj] = acc;
    }
  }
  __syncthreads();
  float pm = -3.0e38f;
#pragma unroll
  for (int u = 0; u < 16; ++u) pm = fmaxf(pm, S[r][jc + (u << 4)]);
  red[r][jc] = pm;
  __syncthreads();
  float m = red[r][0];
#pragma unroll
  for (int u = 1; u < 16; ++u) m = fmaxf(m, red[r][u]);
  __syncthreads();
  float ps = 0.f;
#pragma unroll
  for (int u = 0; u < 16; ++u) {
    const int j = jc + (u << 4);
    const float e = __expf(S[r][j] - m);
    S[r][j] = e;
    ps += e;
  }
  red[r][jc] = ps;
  __syncthreads();
  if (jc == 0) {
    float sum = 0.f;
#pragma unroll
    for (int u = 0; u < 16; ++u) sum += red[r][u];
    rowinv[r] = 1.0f / sum;
  }
  __syncthreads();
  for (int idx = tid; idx < 4096; idx += 256) {
    const int rr = idx >> 8, j = idx & 255;
    const float v = S[rr][j] * rowinv[rr];
    const unsigned short h = f2bf_(v);
    const size_t off = (size_t)bh * MM_STRIDE + (rg * 16 + rr) * 256 + j;
    x2hi[off] = (short)h;
    x2lo[off] = (short)f2bf_(v - bf2f_(h));
  }
}

// ---------------- global max of col/row abs-sums (hi/lo input) --------------
__global__ __launch_bounds__(256) void colrow_max(const short* __restrict__ x2hi,
                                                  const short* __restrict__ x2lo,
                                                  float* __restrict__ scal) {
  const int bh = blockIdx.x;
  const int tid = threadIdx.x;
  const size_t b0 = (size_t)bh * MM_STRIDE;
  float cs = 0.f, rs = 0.f;
  for (int j = 0; j < 256; ++j) {
    const size_t o = b0 + (size_t)tid * 256 + j;
    cs += fabsf(bf2f_((unsigned short)x2hi[o]) + bf2f_((unsigned short)x2lo[o]));
  }
  for (int i = 0; i < 256; ++i) {
    const size_t o = b0 + (size_t)i * 256 + tid;
    rs += fabsf(bf2f_((unsigned short)x2hi[o]) + bf2f_((unsigned short)x2lo[o]));
  }
  __shared__ float rc[256], rr[256];
  rc[tid] = cs; rr[tid] = rs;
  __syncthreads();
  for (int st = 128; st > 0; st >>= 1) {
    if (tid < st) {
      rc[tid] = fmaxf(rc[tid], rc[tid + st]);
      rr[tid] = fmaxf(rr[tid], rr[tid + st]);
    }
    __syncthreads();
  }
  if (tid == 0) {
    atomicMax((int*)&scal[0], __float_as_int(rc[0]));
    atomicMax((int*)&scal[1], __float_as_int(rr[0]));
  }
}

// --- z0 = x2^T/(cmax*rmax): A-form hi/lo + fp32, B-form (=x2/s) hi/lo -------
__global__ __launch_bounds__(256) void tscale2(const short* __restrict__ x2hi,
                                               const short* __restrict__ x2lo,
                                               const float* __restrict__ scal,
                                               short* __restrict__ zBhi,
                                               short* __restrict__ zBlo,
                                               short* __restrict__ zAhi,
                                               short* __restrict__ zAlo,
                                               float* __restrict__ zf) {
  const int g = blockIdx.x * 256 + threadIdx.x;
  const int j = g & 255, i = (g >> 8) & 255, bh = g >> 16;
  const float inv = 1.0f / (scal[0] * scal[1]);
  const float val = (bf2f_((unsigned short)x2hi[g]) +
                     bf2f_((unsigned short)x2lo[g])) * inv;
  const unsigned short h = f2bf_(val);
  const unsigned short lo = f2bf_(val - bf2f_(h));
  zBhi[g] = (short)h;
  zBlo[g] = (short)lo;
  const size_t tg = (size_t)bh * MM_STRIDE + (size_t)j * 256 + i;
  zAhi[tg] = (short)h;
  zAlo[tg] = (short)lo;
  zf[tg] = val;                     // fp32 A-form (exact E for step 4)
}

// --------- split-bf16 batched 256^3: C = alpha*Ef + beta*(A@B) --------------
// R4 tile structure (16x64, 512 blocks), BK=64 staging (4 K-steps). prec=1:
// 3-MFMA split path; prec=0: hi-only. wantLo gates dead lo stores. E fp32.
__global__ __launch_bounds__(256) void pinv_mfma(const short* __restrict__ Ahi_g,
                                                 const short* __restrict__ Alo_g,
                                                 const short* __restrict__ Bhi_g,
                                                 const short* __restrict__ Blo_g,
                                                 const float* __restrict__ Ef,
                                                 float* __restrict__ Cf,
                                                 short* __restrict__ Chi,
                                                 short* __restrict__ Clo,
                                                 short* __restrict__ CThi,
                                                 short* __restrict__ CTlo,
                                                 float alpha, float beta,
                                                 int wantCf, int wantChl,
                                                 int wantT, int wantLo,
                                                 int prec) {
  __shared__ short Ah[4096], Al[4096], Bh[4096], Bl[4096];   // [2][2048] halves
  __shared__ float Tbuf[64 * 68];
  const int tid = threadIdx.x;
  const int lane = tid & 63, w = tid >> 6;
  const int bid = blockIdx.x;
  const int xcd = bid & 7, y = bid >> 3;
  const int t16 = y & 15, bgrp = y >> 4;
  const int batch = bgrp * 8 + xcd;
  const int tm = t16 >> 2, tn = t16 & 3;
  const size_t bb = (size_t)batch * MM_STRIDE;
  const int ml = (tid >> 6) * 16 + (tid & 15), koff = ((tid >> 4) & 3) * 8;
  const short* sAh = Ahi_g + bb + (size_t)(tm * 64 + ml) * 256 + koff;
  const short* sAl = Alo_g + bb + (size_t)(tm * 64 + ml) * 256 + koff;
  const short* sBh = Bhi_g + bb + (size_t)(tn * 64 + ml) * 256 + koff;
  const short* sBl = Blo_g + bb + (size_t)(tn * 64 + ml) * 256 + koff;
  f32x4 acc[4];
#pragma unroll
  for (int j = 0; j < 4; ++j) acc[j] = (f32x4){0.f, 0.f, 0.f, 0.f};
  for (int kt = 0; kt < 4; ++kt) {
    const int k0 = kt * 64;
    __syncthreads();
    gl16(sAh + k0, &Ah[w * 512]);
    gl16(sAh + k0 + 32, &Ah[2048 + w * 512]);
    gl16(sBh + k0, &Bh[w * 512]);
    gl16(sBh + k0 + 32, &Bh[2048 + w * 512]);
    if (prec) {
      gl16(sAl + k0, &Al[w * 512]);
      gl16(sAl + k0 + 32, &Al[2048 + w * 512]);
      gl16(sBl + k0, &Bl[w * 512]);
      gl16(sBl + k0 + 32, &Bl[2048 + w * 512]);
    }
    __syncthreads();
#pragma unroll
    for (int st = 0; st < 2; ++st) {
      bf8 ah = *(const bf8*)&Ah[st * 2048 + (w * 64 + lane) * 8];
      if (prec) {
        bf8 al = *(const bf8*)&Al[st * 2048 + (w * 64 + lane) * 8];
#pragma unroll
        for (int j = 0; j < 4; ++j) {
          bf8 bh = *(const bf8*)&Bh[st * 2048 + (j * 64 + lane) * 8];
          bf8 bl = *(const bf8*)&Bl[st * 2048 + (j * 64 + lane) * 8];
          acc[j] = __builtin_amdgcn_mfma_f32_16x16x32_bf16(ah, bh, acc[j], 0, 0, 0);
          acc[j] = __builtin_amdgcn_mfma_f32_16x16x32_bf16(ah, bl, acc[j], 0, 0, 0);
          acc[j] = __builtin_amdgcn_mfma_f32_16x16x32_bf16(al, bh, acc[j], 0, 0, 0);
        }
      } else {
#pragma unroll
        for (int j = 0; j < 4; ++j) {
          bf8 bh = *(const bf8*)&Bh[st * 2048 + (j * 64 + lane) * 8];
          acc[j] = __builtin_amdgcn_mfma_f32_16x16x32_bf16(ah, bh, acc[j], 0, 0, 0);
        }
      }
    }
  }
  const int qd = lane >> 4, c = lane & 15;
  float vals[4][4];
#pragma unroll
  for (int j = 0; j < 4; ++j) {
    const int col = tn * 64 + j * 16 + c;
#pragma unroll
    for (int r = 0; r < 4; ++r) {
      const int row = tm * 64 + w * 16 + qd * 4 + r;
      const size_t off = bb + (size_t)row * 256 + col;
      float e = 0.f;
      if (alpha != 0.0f) e = alpha * Ef[off];
      const float vv = e + beta * acc[j][r];
      vals[j][r] = vv;
      if (wantCf) Cf[off] = vv;
      if (wantChl) {
        const unsigned short h = f2bf_(vv);
        Chi[off] = (short)h;
        if (wantLo) Clo[off] = (short)f2bf_(vv - bf2f_(h));
      }
    }
  }
  if (wantT) {
    __syncthreads();
#pragma unroll
    for (int j = 0; j < 4; ++j)
#pragma unroll
      for (int r = 0; r < 4; ++r)
        Tbuf[(j * 16 + c) * 68 + w * 16 + qd * 4 + r] = vals[j][r];
    __syncthreads();
    const int ctr = tid >> 2, seg = (tid & 3) * 16;
#pragma unroll
    for (int u = 0; u < 4; ++u) {
      float4 o = *(const float4*)&Tbuf[ctr * 68 + seg + u * 4];
      s4v hi, lo;
      unsigned short h;
      h = f2bf_(o.x); hi[0] = (short)h; lo[0] = (short)f2bf_(o.x - bf2f_(h));
      h = f2bf_(o.y); hi[1] = (short)h; lo[1] = (short)f2bf_(o.y - bf2f_(h));
      h = f2bf_(o.z); hi[2] = (short)h; lo[2] = (short)f2bf_(o.z - bf2f_(h));
      h = f2bf_(o.w); hi[3] = (short)h; lo[3] = (short)f2bf_(o.w - bf2f_(h));
      const size_t off = bb + (size_t)(tn * 64 + ctr) * 256 + tm * 64 + seg + u * 4;
      *(s4v*)&CThi[off] = hi;
      if (wantLo) *(s4v*)&CTlo[off] = lo;
    }
  }
}

// ---- attn3 flash, per-wave (barrier-free): each wave owns 16 ql rows -------
__global__ __launch_bounds__(256) void attn3_flash(const float* __restrict__ ql,
                                                   const short* __restrict__ kb16,
                                                   const short* __restrict__ vT16,
                                                   float* __restrict__ opart,
                                                   float* __restrict__ mpart,
                                                   float* __restrict__ lpart) {
  const int kc = blockIdx.x;   // key chunk 0..3 (1024 keys each)
  const int rt = blockIdx.y;   // row tile 0..3 (64 rows each)
  const int bh = blockIdx.z;   // 0..31
  __shared__ short Pa[4][4096];  // per-wave 16 rows x 256 keys, A-frag order
  const int tid = threadIdx.x, lane = tid & 63, w = tid >> 6;
  const int qd = lane >> 4, c = lane & 15;
  const int rw = rt * 64 + w * 16;               // wave's first global row
  const float* qlp = ql + (size_t)bh * LM_STRIDE;
  const short* kp = kb16 + (size_t)bh * QKV_STRIDE;
  const short* vp = vT16 + (size_t)bh * QKV_STRIDE;
  short* Pw = &Pa[w][0];
  bf8 af[2];
#pragma unroll
  for (int st = 0; st < 2; ++st) {
    float4 x0 = *(const float4*)&qlp[(size_t)(rw + c) * 64 + st * 32 + qd * 8];
    float4 x1 = *(const float4*)&qlp[(size_t)(rw + c) * 64 + st * 32 + qd * 8 + 4];
    bf8 r;
    r[0] = (short)f2bf_(x0.x); r[1] = (short)f2bf_(x0.y);
    r[2] = (short)f2bf_(x0.z); r[3] = (short)f2bf_(x0.w);
    r[4] = (short)f2bf_(x1.x); r[5] = (short)f2bf_(x1.y);
    r[6] = (short)f2bf_(x1.z); r[7] = (short)f2bf_(x1.w);
    af[st] = r;
  }
  float m[4], l[4];
#pragma unroll
  for (int r = 0; r < 4; ++r) { m[r] = -3.0e38f; l[r] = 0.f; }
  f32x4 accO[4];
#pragma unroll
  for (int nb = 0; nb < 4; ++nb) accO[nb] = (f32x4){0.f, 0.f, 0.f, 0.f};
  for (int it = 0; it < 4; ++it) {
    const int kb0 = kc * 1024 + it * 256;
    f32x4 acc[16];
#pragma unroll
    for (int j = 0; j < 16; ++j) acc[j] = (f32x4){0.f, 0.f, 0.f, 0.f};
#pragma unroll
    for (int st = 0; st < 2; ++st)
#pragma unroll
      for (int j = 0; j < 16; ++j) {
        bf8 bfk = *(const bf8*)&kp[(size_t)(kb0 + j * 16 + c) * 64 + st * 32 + qd * 8];
        acc[j] = __builtin_amdgcn_mfma_f32_16x16x32_bf16(af[st], bfk, acc[j], 0, 0, 0);
      }
#pragma unroll
    for (int r = 0; r < 4; ++r) {
      float mx = acc[0][r];
#pragma unroll
      for (int j = 1; j < 16; ++j) mx = fmaxf(mx, acc[j][r]);
      mx = fmaxf(mx, __shfl_xor(mx, 1));
      mx = fmaxf(mx, __shfl_xor(mx, 2));
      mx = fmaxf(mx, __shfl_xor(mx, 4));
      mx = fmaxf(mx, __shfl_xor(mx, 8));
      const float mN = fmaxf(m[r], mx);
      const float a = __expf(m[r] - mN);
      m[r] = mN;
      l[r] *= a;
#pragma unroll
      for (int nb = 0; nb < 4; ++nb) accO[nb][r] *= a;
      float s = 0.f;
#pragma unroll
      for (int j = 0; j < 16; ++j) {
        const float e = __expf(acc[j][r] - mN);
        acc[j][r] = e;
        s += e;
      }
      s += __shfl_xor(s, 1);
      s += __shfl_xor(s, 2);
      s += __shfl_xor(s, 4);
      s += __shfl_xor(s, 8);
      l[r] += s;
    }
#pragma unroll
    for (int j = 0; j < 16; ++j) {
      const int kcol = j * 16 + c;
      const int kb8 = kcol >> 5;
      const int la_base = 16 * ((kcol >> 3) & 3);
      const int j8 = kcol & 7;
#pragma unroll
      for (int r = 0; r < 4; ++r) {
        const int rl = qd * 4 + r;
        Pw[(kb8 * 64 + la_base + rl) * 8 + j8] = (short)f2bf_(acc[j][r]);
      }
    }
#pragma unroll
    for (int kbk = 0; kbk < 8; ++kbk) {
      bf8 ap = *(const bf8*)&Pw[(kbk * 64 + lane) * 8];
#pragma unroll
      for (int nb = 0; nb < 4; ++nb) {
        bf8 bv = *(const bf8*)&vp[(size_t)(nb * 16 + c) * 4096 + kb0 + kbk * 32 + qd * 8];
        accO[nb] = __builtin_amdgcn_mfma_f32_16x16x32_bf16(ap, bv, accO[nb], 0, 0, 0);
      }
    }
  }
  const size_t ob = ((size_t)kc * 32 + bh) * 256 + rt * 64;
#pragma unroll
  for (int nb = 0; nb < 4; ++nb)
#pragma unroll
    for (int r = 0; r < 4; ++r)
      opart[(ob + w * 16 + qd * 4 + r) * 64 + nb * 16 + c] = accO[nb][r];
  if (c == 0) {
#pragma unroll
    for (int r = 0; r < 4; ++r) {
      mpart[ob + w * 16 + qd * 4 + r] = m[r];
      lpart[ob + w * 16 + qd * 4 + r] = l[r];
    }
  }
}

// ------- merge the 4 key-chunk partials -> avT hi/lo bf16 [bh][d][row] ------
__global__ __launch_bounds__(256) void attn3_merge(const float* __restrict__ opart,
                                                   const float* __restrict__ mpart,
                                                   const float* __restrict__ lpart,
                                                   short* __restrict__ avth,
                                                   short* __restrict__ avtl) {
  const int g = blockIdx.x * 256 + threadIdx.x;   // 524288 = 32*256*64
  const int d = g & 63;
  const int idx = g >> 6;                          // bh*256+row
  const int bh = idx >> 8, row = idx & 255;
  const float m0 = mpart[idx], m1 = mpart[8192 + idx],
              m2 = mpart[16384 + idx], m3 = mpart[24576 + idx];
  const float mx = fmaxf(fmaxf(m0, m1), fmaxf(m2, m3));
  const float w0 = __expf(m0 - mx), w1 = __expf(m1 - mx),
              w2 = __expf(m2 - mx), w3 = __expf(m3 - mx);
  const float l = lpart[idx] * w0 + lpart[8192 + idx] * w1 +
                  lpart[16384 + idx] * w2 + lpart[24576 + idx] * w3;
  const float o = opart[(size_t)idx * 64 + d] * w0 +
                  opart[524288 + (size_t)idx * 64 + d] * w1 +
                  opart[1048576 + (size_t)idx * 64 + d] * w2 +
                  opart[1572864 + (size_t)idx * 64 + d] * w3;
  const float val = o / l;
  const unsigned short h = f2bf_(val);
  const size_t o2 = ((size_t)bh * 64 + d) * 256 + row;
  avth[o2] = (short)h;
  avtl[o2] = (short)f2bf_(val - bf2f_(h));
}

// ------- w2^T = (z_final @ av)^T via split-bf16 MFMA ------------------------
__global__ __launch_bounds__(256) void zav_mfma(const short* __restrict__ zAhi,
                                                const short* __restrict__ zAlo,
                                                const short* __restrict__ avth,
                                                const short* __restrict__ avtl,
                                                short* __restrict__ w2tb16) {
  __shared__ short Tb[64 * 68];
  const int rt = blockIdx.x;      // 0..3
  const int bh = blockIdx.y;      // 0..31
  const int tid = threadIdx.x, lane = tid & 63, w = tid >> 6;
  const int qd = lane >> 4, c = lane & 15;
  const size_t zoff = (size_t)bh * MM_STRIDE + (size_t)(rt * 64 + w * 16 + c) * 256;
  const short* zh = zAhi + zoff;
  const short* zl = zAlo + zoff;
  const short* ahp = avth + (size_t)bh * LM_STRIDE;
  const short* alp = avtl + (size_t)bh * LM_STRIDE;
  f32x4 acc[4];
#pragma unroll
  for (int j = 0; j < 4; ++j) acc[j] = (f32x4){0.f, 0.f, 0.f, 0.f};
  for (int kt = 0; kt < 8; ++kt) {
    const int k0 = kt * 32 + qd * 8;
    bf8 ah = *(const bf8*)&zh[k0];
    bf8 al = *(const bf8*)&zl[k0];
#pragma unroll
    for (int j = 0; j < 4; ++j) {
      bf8 bhj = *(const bf8*)&ahp[(size_t)(j * 16 + c) * 256 + k0];
      bf8 blj = *(const bf8*)&alp[(size_t)(j * 16 + c) * 256 + k0];
      acc[j] = __builtin_amdgcn_mfma_f32_16x16x32_bf16(ah, bhj, acc[j], 0, 0, 0);
      acc[j] = __builtin_amdgcn_mfma_f32_16x16x32_bf16(ah, blj, acc[j], 0, 0, 0);
      acc[j] = __builtin_amdgcn_mfma_f32_16x16x32_bf16(al, bhj, acc[j], 0, 0, 0);
    }
  }
#pragma unroll
  for (int j = 0; j < 4; ++j)
#pragma unroll
    for (int r = 0; r < 4; ++r)
      Tb[(j * 16 + c) * 68 + w * 16 + qd * 4 + r] = (short)f2bf_(acc[j][r]);
  __syncthreads();
  const int col = tid >> 2, rs = (tid & 3) * 16;
  short* dst = &w2tb16[(size_t)bh * LM_STRIDE + (size_t)col * 256 + rt * 64 + rs];
  const short* srcp = &Tb[col * 68 + rs];
#pragma unroll
  for (int u = 0; u < 4; ++u) *(s4v*)&dst[u * 4] = *(const s4v*)&srcp[u * 4];
}

// -- attn1+conv: oh = softmax(q@kl^T)@w2 + conv(v) [conv via banded MFMA] ----
// 32-row blocks (R8-verified best: grid 4096, Pa 16KB -> ~8 blocks/CU).
// Wave w: QK cols w*64..+63; PV/conv rows (w&1)*16, cols (w>>1)*32. XCD remap.
__global__ __launch_bounds__(256) void attn1_conv_mfma(const short* __restrict__ qb16,
                                                       const short* __restrict__ klb16,
                                                       const short* __restrict__ w2tb16,
                                                       const short* __restrict__ vT16,
                                                       const float* __restrict__ cw,
                                                       short* __restrict__ ohb16) {
  __shared__ short Pa[8192];                // 32x256 bf16 in A-frag order (16KB)
  __shared__ float redM[4][32], redS[4][32];
  __shared__ float rowM[32], rowI[32];
  __shared__ float cwS[33];
  const int tid = threadIdx.x;
  const int lane = tid & 63, w = tid >> 6;
  const int qd = lane >> 4, c = lane & 15;
  const int lin = blockIdx.y * 128 + blockIdx.x;   // grid (128,32) -> 0..4095
  const int xcd = lin & 7;
  const int idx = lin >> 3;                        // 0..511
  const int bh = xcd * 4 + (idx >> 7);             // 4 bh per XCD
  const int r0 = (idx & 127) * 32;                 // 32-row tile
  const short* qp = qb16 + (size_t)bh * QKV_STRIDE;
  const short* klp = klb16 + (size_t)bh * LM_STRIDE;
  const short* w2p = w2tb16 + (size_t)bh * LM_STRIDE;
  const short* vp = vT16 + (size_t)bh * QKV_STRIDE;

  if (tid < 33) cwS[tid] = cw[(bh & 7) * 33 + tid];

  // ---- QK^T: S[32][256], wave w owns cols w*64..+63 ----
  f32x4 acc[2][4];
#pragma unroll
  for (int i = 0; i < 2; ++i)
#pragma unroll
    for (int j = 0; j < 4; ++j) acc[i][j] = (f32x4){0.f, 0.f, 0.f, 0.f};
#pragma unroll
  for (int st = 0; st < 2; ++st) {
    const int k0 = st * 32 + qd * 8;
    bf8 af[2], bf[4];
#pragma unroll
    for (int i = 0; i < 2; ++i)
      af[i] = *(const bf8*)&qp[(size_t)(r0 + i * 16 + c) * 64 + k0];
#pragma unroll
    for (int j = 0; j < 4; ++j)
      bf[j] = *(const bf8*)&klp[(size_t)(w * 64 + j * 16 + c) * 64 + k0];
#pragma unroll
    for (int i = 0; i < 2; ++i)
#pragma unroll
      for (int j = 0; j < 4; ++j)
        acc[i][j] = __builtin_amdgcn_mfma_f32_16x16x32_bf16(af[i], bf[j], acc[i][j], 0, 0, 0);
  }
  // ---- row max (over 4 waves x 64 cols each) ----
#pragma unroll
  for (int i = 0; i < 2; ++i)
#pragma unroll
    for (int r = 0; r < 4; ++r) {
      float m0 = fmaxf(fmaxf(acc[i][0][r], acc[i][1][r]),
                       fmaxf(acc[i][2][r], acc[i][3][r]));
      m0 = fmaxf(m0, __shfl_xor(m0, 1));
      m0 = fmaxf(m0, __shfl_xor(m0, 2));
      m0 = fmaxf(m0, __shfl_xor(m0, 4));
      m0 = fmaxf(m0, __shfl_xor(m0, 8));
      if (c == 0) redM[w][i * 16 + qd * 4 + r] = m0;
    }
  __syncthreads();
  if (tid < 32)
    rowM[tid] = fmaxf(fmaxf(redM[0][tid], redM[1][tid]),
                      fmaxf(redM[2][tid], redM[3][tid]));
  __syncthreads();
  // ---- exp + row sum ----
#pragma unroll
  for (int i = 0; i < 2; ++i)
#pragma unroll
    for (int r = 0; r < 4; ++r) {
      const float mrow = rowM[i * 16 + qd * 4 + r];
      float s = 0.f;
#pragma unroll
      for (int j = 0; j < 4; ++j) {
        const float e = __expf(acc[i][j][r] - mrow);
        acc[i][j][r] = e;
        s += e;
      }
      s += __shfl_xor(s, 1);
      s += __shfl_xor(s, 2);
      s += __shfl_xor(s, 4);
      s += __shfl_xor(s, 8);
      if (c == 0) redS[w][i * 16 + qd * 4 + r] = s;
    }
  __syncthreads();
  if (tid < 32)
    rowI[tid] = 1.0f / (redS[0][tid] + redS[1][tid] + redS[2][tid] + redS[3][tid]);
  __syncthreads();
  // ---- P -> Pa (A-frag order: tile (kb,i), lane2, elem) ----
#pragma unroll
  for (int i = 0; i < 2; ++i)
#pragma unroll
    for (int r = 0; r < 4; ++r) {
      const int row = i * 16 + qd * 4 + r;
      const float inv = rowI[row];
#pragma unroll
      for (int j = 0; j < 4; ++j) {
        const int col = w * 64 + j * 16 + c;
        const short val = (short)f2bf_(acc[i][j][r] * inv);
        const int kb = col >> 5;
        const int lane2 = (row & 15) + 16 * ((col >> 3) & 3);
        Pa[((kb * 2 + i) * 64 + lane2) * 8 + (col & 7)] = val;
      }
    }
  __syncthreads();
  // ---- PV: wave w -> rows (w&1)*16, cols (w>>1)*32 ----
  const int iw = w & 1, ch = w >> 1;
  f32x4 accO[2];
#pragma unroll
  for (int nb = 0; nb < 2; ++nb) accO[nb] = (f32x4){0.f, 0.f, 0.f, 0.f};
  for (int kb = 0; kb < 8; ++kb) {
    bf8 ap = *(const bf8*)&Pa[((kb * 2 + iw) * 64 + lane) * 8];
#pragma unroll
    for (int nb = 0; nb < 2; ++nb) {
      bf8 bfr = *(const bf8*)&w2p[(size_t)(ch * 32 + nb * 16 + c) * 256 + kb * 32 + qd * 8];
      accO[nb] = __builtin_amdgcn_mfma_f32_16x16x32_bf16(ap, bfr, accO[nb], 0, 0, 0);
    }
  }
  // ---- conv residual: Band[16x64] @ Vwin[64x32] per wave ----
  {
    bf8 ba[2];
    const int rl = iw * 16 + (lane & 15);   // row within 32-row block
#pragma unroll
    for (int kb = 0; kb < 2; ++kb) {
#pragma unroll
      for (int e = 0; e < 8; ++e) {
        const int kk = kb * 32 + qd * 8 + e;
        const int t = kk - rl;
        const int s = r0 - 16 + kk;
        const float bv = (t >= 0 && t < 33 && s >= 0 && s < 4096) ? cwS[t] : 0.f;
        ba[kb][e] = (short)f2bf_(bv);
      }
    }
#pragma unroll
    for (int kb = 0; kb < 2; ++kb) {
      int s0 = r0 - 16 + kb * 32 + qd * 8;
      s0 = s0 < 0 ? 0 : (s0 > 4088 ? 4088 : s0);
#pragma unroll
      for (int nb = 0; nb < 2; ++nb) {
        bf8 bv = *(const bf8*)&vp[(size_t)(ch * 32 + nb * 16 + c) * 4096 + s0];
        accO[nb] = __builtin_amdgcn_mfma_f32_16x16x32_bf16(ba[kb], bv, accO[nb], 0, 0, 0);
      }
    }
  }
  short* ohp = (short*)ohb16 + (size_t)bh * QKV_STRIDE;
#pragma unroll
  for (int nb = 0; nb < 2; ++nb)
#pragma unroll
    for (int r = 0; r < 4; ++r) {
      const int row = r0 + iw * 16 + qd * 4 + r;
      ohp[(size_t)row * 64 + ch * 32 + nb * 16 + c] = (short)f2bf_(accO[nb][r]);
    }
}

// ------- out = concat_heads(oh_bf16) @ w_out + b_out (MFMA) -----------------
// BK=64 staged global_load_lds (8 K-steps); XCD-swizzled 1-D grid (512=8*64).
__global__ __launch_bounds__(256) void gemm_out_mfma(const short* __restrict__ ohb16,
                                                     const short* __restrict__ wT,
                                                     const float* __restrict__ bias,
                                                     float* __restrict__ out) {
  __shared__ short As[8192];      // [2][4096] halves
  __shared__ short Bs[8192];
  const int tid = threadIdx.x;
  const int lane = tid & 63, w = tid >> 6;
  const int wr = w >> 1, wc = w & 1;
  const int bid = (blockIdx.x & 7) * 64 + (blockIdx.x >> 3);   // 512 = 8*64
  const int bn = bid & 3, bm = bid >> 2;
  const int gm0 = bm * 128, gn0 = bn * 128;
  const int mA0 = (tid >> 6) * 16 + (tid & 15), kA0 = ((tid >> 4) & 3) * 8;
  const int s1 = tid + 256;
  const int mA1 = (s1 >> 6) * 16 + (s1 & 15), kA1 = ((s1 >> 4) & 3) * 8;
  const int b0r = (gm0 + mA0) >> 12, seq0 = (gm0 + mA0) & 4095;
  const int b1r = (gm0 + mA1) >> 12, seq1 = (gm0 + mA1) & 4095;
  f32x4 acc[4][4];
#pragma unroll
  for (int i = 0; i < 4; ++i)
#pragma unroll
    for (int j = 0; j < 4; ++j) acc[i][j] = (f32x4){0.f, 0.f, 0.f, 0.f};
  for (int kt = 0; kt < 8; ++kt) {
    __syncthreads();
#pragma unroll
    for (int hf = 0; hf < 2; ++hf) {
      const int ka = kt * 64 + hf * 32 + kA0, kb = kt * 64 + hf * 32 + kA1;
      gl16(&ohb16[(size_t)(b0r * 8 + (ka >> 6)) * QKV_STRIDE + (size_t)seq0 * 64 + (ka & 63)],
           &As[hf * 4096 + w * 512]);
      gl16(&ohb16[(size_t)(b1r * 8 + (kb >> 6)) * QKV_STRIDE + (size_t)seq1 * 64 + (kb & 63)],
           &As[hf * 4096 + 2048 + w * 512]);
      gl16(&wT[(size_t)(gn0 + mA0) * 512 + ka], &Bs[hf * 4096 + w * 512]);
      gl16(&wT[(size_t)(gn0 + mA1) * 512 + kb], &Bs[hf * 4096 + 2048 + w * 512]);
    }
    __syncthreads();
#pragma unroll
    for (int st = 0; st < 2; ++st) {
      bf8 af[4], bfr[4];
#pragma unroll
      for (int i = 0; i < 4; ++i) {
        af[i] = *(const bf8*)&As[st * 4096 + ((wr * 4 + i) * 64 + lane) * 8];
        bfr[i] = *(const bf8*)&Bs[st * 4096 + ((wc * 4 + i) * 64 + lane) * 8];
      }
#pragma unroll
      for (int i = 0; i < 4; ++i)
#pragma unroll
        for (int j = 0; j < 4; ++j)
          acc[i][j] = __builtin_amdgcn_mfma_f32_16x16x32_bf16(af[i], bfr[j], acc[i][j], 0, 0, 0);
    }
  }
  const int qd = lane >> 4, c = lane & 15;
#pragma unroll
  for (int i = 0; i < 4; ++i)
#pragma unroll
    for (int j = 0; j < 4; ++j) {
      const int col = gn0 + wc * 64 + j * 16 + c;
      const float bval = bias[col];
#pragma unroll
      for (int r = 0; r < 4; ++r) {
        const int row = gm0 + wr * 64 + i * 16 + qd * 4 + r;
        out[(size_t)row * 512 + col] = acc[i][j][r] + bval;
      }
    }
}

// ---------------------------------------------------------------------------
extern "C" void kernel_launch(void* const* d_in, const int* in_sizes, int n_in,
                              void* d_out, int out_size, void* d_ws, size_t ws_size,
                              hipStream_t stream) {
  const float* x    = (const float*)d_in[0];
  const float* wqkv = (const float*)d_in[1];
  const float* wout = (const float*)d_in[2];
  const float* bout = (const float*)d_in[3];
  const float* cw   = (const float*)d_in[4];
  float* out = (float*)d_out;

  float* w = (float*)d_ws;
  // ---- compact layout: 37,486,656 floats total (~150 MB) ----
  short* qb16   = (short*)(w);              // [32,4096,64] bf16   (4194304 fl)
  short* kb16   = (short*)(w + 4194304);
  short* vT16   = (short*)(w + 8388608);    // [32,64,4096] bf16
  // region 12582912..16777216 (4194304 fl), time-multiplexed:
  short* xb16   = (short*)(w + 12582912);   // phase 1: x bf16 (dead after qkv)
  float* z0f    = w + 12582912;             // phase 2: fp32 z ping (2097152)
  float* z1f    = w + 14680064;             // phase 2: fp32 z pong (2097152)
  float* opart  = w + 12582912;             // phase 3: [4,32,256,64] (2097152)
  short* ohb16  = (short*)(w + 12582912);   // phase 4: oh bf16 (4194304 fl)
  float* ql     = w + 16777216;             // [32,256,64] fp32 (524288)
  float* kl     = w + 17301504;
  short* klb16  = (short*)(w + 17825792);   // (262144 fl)
  short* x2hi   = (short*)(w + 18087936);   // hi/lo pairs: 1048576 fl each
  short* x2lo   = (short*)(w + 19136512);
  float* xzf    = w + 20185088;             // fp32 xz (E steps 2,3) (2097152)
  short* xzAhi  = (short*)(w + 22282240);
  short* xzAlo  = (short*)(w + 23330816);
  short* xzBhi  = (short*)(w + 24379392);   // also u2B (xzB dead after step 2)
  short* xzBlo  = (short*)(w + 25427968);
  short* u1Bhi  = (short*)(w + 26476544);
  short* u1Blo  = (short*)(w + 27525120);
  short* z0Ahi  = (short*)(w + 28573696);
  short* z0Alo  = (short*)(w + 29622272);
  short* z0Bhi  = (short*)(w + 30670848);
  short* z0Blo  = (short*)(w + 31719424);
  short* z1Ahi  = (short*)(w + 32768000);
  short* z1Alo  = (short*)(w + 33816576);
  short* z1Bhi  = (short*)(w + 34865152);
  short* z1Blo  = (short*)(w + 35913728);
  float* scal   = w + 36962304;             // [2]
  short* wqkvT  = (short*)(w + 36962368);   // [1536,512] bf16 (393216 fl)
  short* woutT  = (short*)(w + 37355584);   // [512,512] bf16 (131072 fl)
  // end: 37486656 floats (~150 MB)
  // post-pinv aliases (xzf/xzA/u1B dead after the loop):
  short* avth   = (short*)(w + 20185088);   // [32,64,256] bf16 (262144 fl)
  short* avtl   = (short*)(w + 20447232);
  short* w2tb16 = (short*)(w + 20709376);   // [32,256,64] bf16 (262144 fl)
  float* mpart  = w + 26476544;             // [4,32,256] (32768 fl, in u1Bhi)
  float* lpart  = w + 26509312;

  transpose_bf16<<<dim3(48, 16), 256, 0, stream>>>(wqkv, wqkvT, 512, 1536);
  transpose_bf16<<<dim3(16, 16), 256, 0, stream>>>(wout, woutT, 512, 512);
  x_to_bf16<<<2048, 256, 0, stream>>>(x, xb16, scal);
  gemm_qkv_mfma<<<1536, 256, 0, stream>>>(xb16, wqkvT, qb16, kb16, vT16);
  lmk_mean<<<2048, 256, 0, stream>>>(qb16, kb16, ql, kl, klb16);
  sim2_softmax<<<512, 256, 0, stream>>>(ql, kl, x2hi, x2lo);
  colrow_max<<<32, 256, 0, stream>>>(x2hi, x2lo, scal);
  // overwrites xb16 region with z0f -- xb16 dead after gemm_qkv.
  tscale2<<<8192, 256, 0, stream>>>(x2hi, x2lo, scal, z0Bhi, z0Blo, z0Ahi, z0Alo, z0f);

  float *zcf = z0f, *znf = z1f;
  short *zAh = z0Ahi, *zAl = z0Alo, *zBh = z0Bhi, *zBl = z0Blo;
  short *nAh = z1Ahi, *nAl = z1Alo, *nBh = z1Bhi, *nBl = z1Blo;
  for (int it = 0; it < 6; ++it) {
    const int pr = (it == 5) ? 1 : 0;  // single precise final iter (order-3 NS)
    const int nl = (it < 5) ? 1 : 0;   // final iter: fp32 zn + B-form unused
    const int lo123 = pr;              // steps 1-3 lo consumed iff this iter precise
    const int lo4 = (it >= 4) ? 1 : 0; // step-4 lo consumed iff NEXT consumer precise
    // xz = x2 @ z
    pinv_mfma<<<512, 256, 0, stream>>>(x2hi, x2lo, zBh, zBl, xzf,
                                       xzf, xzAhi, xzAlo, xzBhi, xzBlo,
                                       0.f, 1.f, 1, 1, 1, lo123, pr);
    // u1 = 7*xz - xz@xz   (only u1^T needed)
    pinv_mfma<<<512, 256, 0, stream>>>(xzAhi, xzAlo, xzBhi, xzBlo, xzf,
                                       znf, u1Bhi, u1Blo, u1Bhi, u1Blo,
                                       7.f, -1.f, 0, 0, 1, lo123, pr);
    // u2 = 15*xz - xz@u1  (only u2^T needed; overwrites xzB slots)
    pinv_mfma<<<512, 256, 0, stream>>>(xzAhi, xzAlo, u1Bhi, u1Blo, xzf,
                                       znf, xzBhi, xzBlo, xzBhi, xzBlo,
                                       15.f, -1.f, 0, 0, 1, lo123, pr);
    // zn = 3.25*z - 0.25*z@u2  (trimmed on it=5; zA hi+lo always for zav)
    pinv_mfma<<<512, 256, 0, stream>>>(zAh, zAl, xzBhi, xzBlo, zcf,
                                       znf, nAh, nAl, nBh, nBl,
                                       3.25f, -0.25f, nl, 1, nl, lo4, pr);
    float* tf = zcf; zcf = znf; znf = tf;
    short* t;
    t = zAh; zAh = nAh; nAh = t;  t = zAl; zAl = nAl; nAl = t;
    t = zBh; zBh = nBh; nBh = t;  t = zBl; zBl = nBl; nBl = t;
  }
  // zAh/zAl == z0A here (6 swaps). z0f/z1f/xzf/xzA/u1B dead -> aliases live.
  // opart overwrites z0f region (dead); read by merge before ohb16 is written.

  attn3_flash<<<dim3(4, 4, 32), 256, 0, stream>>>(ql, kb16, vT16, opart, mpart, lpart);
  attn3_merge<<<2048, 256, 0, stream>>>(opart, mpart, lpart, avth, avtl);
  zav_mfma<<<dim3(4, 32), 256, 0, stream>>>(zAh, zAl, avth, avtl, w2tb16);
  // attn1_conv writes ohb16 over the opart/z0f/z1f region (all dead now).
  attn1_conv_mfma<<<dim3(128, 32), 256, 0, stream>>>(qb16, klb16, w2tb16, vT16, cw, ohb16);
  gemm_out_mfma<<<512, 256, 0, stream>>>(ohb16, woutT, bout, out);
}